// Round 3
// baseline (191.088 us; speedup 1.0000x reference)
//
#include <hip/hip_runtime.h>
#include <hip/hip_bf16.h>
#include <stdint.h>

#define PI_F 3.14159265358979323846f
#define C1_EXP 0.18033688f   // log2(e)/8
#define C2_EXP 23.083120f    // 16*log2(e)

typedef __bf16 bf16x8 __attribute__((ext_vector_type(8)));
typedef float f32x4 __attribute__((ext_vector_type(4)));
typedef unsigned int uint32x4 __attribute__((ext_vector_type(4)));

__device__ __forceinline__ bf16x8 neg8(bf16x8 v) {
  union { bf16x8 b; uint32x4 u; } x;
  x.b = v;
  x.u ^= (uint32x4){0x80008000u, 0x80008000u, 0x80008000u, 0x80008000u};
  return x.b;
}

// 3-term split-accumulate: P*Q with P=Ph+Pl, Q=Qh+Ql (drop Pl*Ql ~2^-18)
#define MFMA3(acc, Ph, Pl, Qh, Ql)                                        \
  acc = __builtin_amdgcn_mfma_f32_16x16x32_bf16(Ph, Qh, acc, 0, 0, 0);    \
  acc = __builtin_amdgcn_mfma_f32_16x16x32_bf16(Ph, Ql, acc, 0, 0, 0);    \
  acc = __builtin_amdgcn_mfma_f32_16x16x32_bf16(Pl, Qh, acc, 0, 0, 0);

// Closed-form base-slot -> original column mapping.
__device__ __forceinline__ int slot2n(int slot) {
  const int pi = slot >> 1, im = slot & 1;
  int k1, k2;
  if (pi < 480)      { k1 = 1 + (pi >> 5); k2 = pi & 31; }
  else if (pi < 495) { k1 = 0;  k2 = pi - 479; }
  else if (pi < 510) { k1 = 16; k2 = pi - 494; }
  else if (pi < 514) { k1 = ((pi - 510) >> 1) * 16; k2 = ((pi - 510) & 1) * 16; }
  else               { k1 = 0; k2 = 0; }
  return 2 * (k1 * 32 + k2) + im;
}

// ---------------------------------------------------------------------------
// Kernel 0: twiddle tables, hi/lo split bf16.
// ---------------------------------------------------------------------------
__global__ __launch_bounds__(256) void k_twid(__bf16* __restrict__ tw) {
  for (int e = threadIdx.x; e < 1024; e += 256) {
    const int j = e >> 5, k = e & 31;
    const int t = (j * k) & 31;
    float sv, cv;
    sincosf(2.0f * PI_F * (float)t / 32.0f, &sv, &cv);
    const __bf16 ch = (__bf16)cv;
    const __bf16 sh = (__bf16)sv;
    tw[e] = ch;
    tw[1024 + e] = (__bf16)(cv - (float)ch);
    tw[2048 + e] = sh;
    tw[3072 + e] = (__bf16)(sv - (float)sh);
  }
}

// ---------------------------------------------------------------------------
// Kernel 1: forward FFT2 via split-bf16 MFMA. One slice per wave (r14
// measured-best barrier-free form; the r15/r16 2-wave split regressed).
// X global loads issued BEFORE table staging to overlap HBM latency.
// ---------------------------------------------------------------------------
__global__ __launch_bounds__(256) void k_fft2(const float* __restrict__ x,
                                              float* __restrict__ xr,
                                              float* __restrict__ stats_raw,
                                              const __bf16* __restrict__ tw) {
  __shared__ __align__(16) char smem[51200];
  const int tid = threadIdx.x, lane = tid & 63, wv = tid >> 6;
  const int quad = lane >> 4, q16 = lane & 15;
  const int slice = blockIdx.x * 4 + wv;
  char* const wr_ = smem + 10240 + wv * 10240;

  // early X global loads (wave-private region; overlap with table staging)
  const float* xs = x + (size_t)slice * 1024;
  float4 xv[4];
#pragma unroll
  for (int u = 0; u < 4; ++u) xv[u] = ((const float4*)xs)[u * 64 + lane];

  for (int i = tid; i < 512; i += 256) {
    const int t = i >> 7, r = (i >> 2) & 31, c8 = (i & 3) * 8;
    *(uint4*)(smem + t * 2560 + r * 80 + c8 * 2) =
        *(const uint4*)(tw + t * 1024 + r * 32 + c8);
  }

  // X split + stage (same-wave ds ordering)
#pragma unroll
  for (int u = 0; u < 4; ++u) {
    const int f = u * 64 + lane;
    const float4 v = xv[u];
    const int row = f >> 3, c4 = (f & 7) * 4;
    union { unsigned long long q; __bf16 b[4]; } ph, pl;
    ph.b[0] = (__bf16)v.x; ph.b[1] = (__bf16)v.y;
    ph.b[2] = (__bf16)v.z; ph.b[3] = (__bf16)v.w;
    pl.b[0] = (__bf16)(v.x - (float)ph.b[0]);
    pl.b[1] = (__bf16)(v.y - (float)ph.b[1]);
    pl.b[2] = (__bf16)(v.z - (float)ph.b[2]);
    pl.b[3] = (__bf16)(v.w - (float)ph.b[3]);
    *(unsigned long long*)(wr_ + row * 80 + c4 * 2) = ph.q;
    *(unsigned long long*)(wr_ + 2560 + row * 80 + c4 * 2) = pl.q;
  }
  __syncthreads();  // tables visible to all waves; X same-wave ordered

  bf16x8 cch[2], ccl[2], ssh[2], ssl[2], xh[2], xl[2];
#pragma unroll
  for (int t2 = 0; t2 < 2; ++t2) {
    const int row = t2 * 16 + q16;
    cch[t2] = *(const bf16x8*)(smem + row * 80 + quad * 16);
    ccl[t2] = *(const bf16x8*)(smem + 2560 + row * 80 + quad * 16);
    ssh[t2] = *(const bf16x8*)(smem + 5120 + row * 80 + quad * 16);
    ssl[t2] = *(const bf16x8*)(smem + 7680 + row * 80 + quad * 16);
    xh[t2] = *(const bf16x8*)(wr_ + row * 80 + quad * 16);
    xl[t2] = *(const bf16x8*)(wr_ + 2560 + row * 80 + quad * 16);
  }

  // pass 1: Yre = X@Cc, Yim = -(X@Ss)
  f32x4 yre[2][2] = {}, yim[2][2] = {};
#pragma unroll
  for (int mt = 0; mt < 2; ++mt)
#pragma unroll
    for (int nt = 0; nt < 2; ++nt) {
      MFMA3(yre[mt][nt], xh[mt], xl[mt], cch[nt], ccl[nt]);
      MFMA3(yim[mt][nt], xh[mt], xl[mt], ssh[nt], ssl[nt]);
    }

  // write Yt transposed + split (wave-private; same-wave ordering)
#pragma unroll
  for (int mt = 0; mt < 2; ++mt)
#pragma unroll
    for (int nt = 0; nt < 2; ++nt) {
      char* base = wr_ + (nt * 16 + q16) * 80 + (mt * 16 + quad * 4) * 2;
      union { unsigned long long q; __bf16 b[4]; } h, l;
#pragma unroll
      for (int r = 0; r < 4; ++r) {
        const float v = yre[mt][nt][r];
        h.b[r] = (__bf16)v; l.b[r] = (__bf16)(v - (float)h.b[r]);
      }
      *(unsigned long long*)(base) = h.q;
      *(unsigned long long*)(base + 2560) = l.q;
#pragma unroll
      for (int r = 0; r < 4; ++r) {
        const float v = -yim[mt][nt][r];
        h.b[r] = (__bf16)v; l.b[r] = (__bf16)(v - (float)h.b[r]);
      }
      *(unsigned long long*)(base + 5120) = h.q;
      *(unsigned long long*)(base + 7680) = l.q;
    }
  asm volatile("" ::: "memory");

  bf16x8 yreh[2], yrel[2], yimh[2], yiml[2];
#pragma unroll
  for (int nt = 0; nt < 2; ++nt) {
    const int row = nt * 16 + q16;
    yreh[nt] = *(const bf16x8*)(wr_ + row * 80 + quad * 16);
    yrel[nt] = *(const bf16x8*)(wr_ + 2560 + row * 80 + quad * 16);
    yimh[nt] = *(const bf16x8*)(wr_ + 5120 + row * 80 + quad * 16);
    yiml[nt] = *(const bf16x8*)(wr_ + 7680 + row * 80 + quad * 16);
  }

  // pass 2: Zre = Cc@Yre + Ss@Yim ; Zim = Cc@Yim - Ss@Yre
  f32x4 zre[2][2] = {}, zim[2][2] = {};
  bf16x8 ssnh[2], ssnl[2];
  ssnh[0] = neg8(ssh[0]); ssnh[1] = neg8(ssh[1]);
  ssnl[0] = neg8(ssl[0]); ssnl[1] = neg8(ssl[1]);
#pragma unroll
  for (int mt = 0; mt < 2; ++mt)
#pragma unroll
    for (int nt = 0; nt < 2; ++nt) {
      MFMA3(zre[mt][nt], cch[mt], ccl[mt], yreh[nt], yrel[nt]);
      MFMA3(zre[mt][nt], ssh[mt], ssl[mt], yimh[nt], yiml[nt]);
      MFMA3(zim[mt][nt], cch[mt], ccl[mt], yimh[nt], yiml[nt]);
      MFMA3(zim[mt][nt], ssnh[mt], ssnl[mt], yreh[nt], yrel[nt]);
    }

  // stats + store
  float* op = xr + (size_t)slice * 2048;
  float s1 = 0.f, s2 = 0.f;
#pragma unroll
  for (int mt = 0; mt < 2; ++mt)
#pragma unroll
    for (int nt = 0; nt < 2; ++nt)
#pragma unroll
      for (int r = 0; r < 4; ++r) {
        const int k1 = mt * 16 + quad * 4 + r;
        const int k2 = nt * 16 + q16;
        const float a = zre[mt][nt][r], bimg = zim[mt][nt][r];
        s1 += a + bimg;
        s2 += a * a + bimg * bimg;
        float2 st; st.x = a; st.y = bimg;
        *(float2*)(op + 2 * (k1 * 32 + k2)) = st;
      }
#pragma unroll
  for (int off = 1; off <= 32; off <<= 1) {
    s1 += __shfl_xor(s1, off);
    s2 += __shfl_xor(s2, off);
  }
  if (lane == 0) {
    const int bg = (slice >> 8) * 32 + ((slice & 255) >> 3);
    atomicAdd(&stats_raw[bg * 2], s1);
    atomicAdd(&stats_raw[bg * 2 + 1], s2);
  }
}

// ---------------------------------------------------------------------------
// Kernel 2: mirror-correction vectors (coalesced); unchanged.
// ---------------------------------------------------------------------------
__global__ __launch_bounds__(256) void k_uvec(const float* __restrict__ stats_raw,
                                              const float* __restrict__ gn_w,
                                              const float* __restrict__ gn_b,
                                              const float* __restrict__ qkv_w,
                                              const float* __restrict__ qkv_b,
                                              float* __restrict__ uk,
                                              float* __restrict__ uv) {
  const int blk = blockIdx.x;
  const int tid = threadIdx.x;
  const int b = blk >> 3, h = (blk >> 1) & 3, role = blk & 1;
  __shared__ float Bsh[256];
  {
    const int g = tid >> 3;
    const float S = stats_raw[(b * 32 + g) * 2];
    const float S2 = stats_raw[(b * 32 + g) * 2 + 1];
    const float mean = S * (1.0f / 16384.0f);
    const float var = S2 * (1.0f / 16384.0f) - mean * mean;
    const float rstd = rsqrtf(var + 1e-5f);
    Bsh[tid] = gn_b[tid] - mean * rstd * gn_w[tid];
  }
  __syncthreads();
  const int cp = tid >> 2, seg = tid & 3;
  const int row = h * 192 + 64 + role * 64 + cp;
  const float* wr_ = qkv_w + (size_t)row * 256 + seg * 64;
  const float* bs = Bsh + seg * 64;
  float s = 0.f;
#pragma unroll
  for (int i = 0; i < 16; ++i) {
    const float4 w4 = *(const float4*)(wr_ + i * 4);
    const float4 b4 = *(const float4*)(bs + i * 4);
    s += w4.x * b4.x + w4.y * b4.y + w4.z * b4.z + w4.w * b4.w;
  }
  s += __shfl_xor(s, 1);
  s += __shfl_xor(s, 2);
  if (seg == 0) {
    float* dst = (role == 0) ? uk : uv;
    dst[(size_t)(b * 4 + h) * 64 + cp] = s + qkv_b[row];
  }
}

// ---------------------------------------------------------------------------
// Kernel 3: GroupNorm apply + transpose to bf16 X^T [b][n][c]; unchanged.
// ---------------------------------------------------------------------------
__global__ __launch_bounds__(256) void k_gntrans(const float* __restrict__ xr,
                                                 const float* __restrict__ stats_raw,
                                                 const float* __restrict__ w,
                                                 const float* __restrict__ bias,
                                                 __bf16* __restrict__ xt) {
  const int n0 = blockIdx.x * 64;
  const int c0 = blockIdx.y * 64;
  const int b = blockIdx.z;
  __shared__ __bf16 Lt[64][72];
  const int tid = threadIdx.x;
  for (int i = tid; i < 1024; i += 256) {
    const int cl = i >> 4, c = c0 + cl, nl = (i & 15) * 4;
    const float S = stats_raw[(b * 32 + (c >> 3)) * 2];
    const float S2 = stats_raw[(b * 32 + (c >> 3)) * 2 + 1];
    const float mean = S * (1.0f / 16384.0f);
    const float var = S2 * (1.0f / 16384.0f) - mean * mean;
    const float rstd = rsqrtf(var + 1e-5f);
    const float sc = rstd * w[c];
    const float sh = bias[c] - mean * sc;
    const float4 v = *(const float4*)(xr + ((size_t)b * 256 + c) * 2048 + n0 + nl);
    Lt[nl][cl] = (__bf16)(v.x * sc + sh);
    Lt[nl + 1][cl] = (__bf16)(v.y * sc + sh);
    Lt[nl + 2][cl] = (__bf16)(v.z * sc + sh);
    Lt[nl + 3][cl] = (__bf16)(v.w * sc + sh);
  }
  __syncthreads();
  __bf16* dst = xt + (size_t)b * 524288 + (size_t)n0 * 256 + c0;
  for (int i = tid; i < 512; i += 256) {
    const int nl = i >> 3, cch = (i & 7) * 8;
    *(uint4*)(dst + (size_t)nl * 256 + cch) = *(const uint4*)&Lt[nl][cch];
  }
}

// ---------------------------------------------------------------------------
// Kernel 4: QKV GEMM (bf16 MFMA), double-buffered LDS; unchanged.
// ---------------------------------------------------------------------------
__global__ __launch_bounds__(256) void k_gemm_qkv(const float* __restrict__ W,
                                                  const __bf16* __restrict__ X,
                                                  const float* __restrict__ bias,
                                                  const float* __restrict__ uk,
                                                  float* __restrict__ dq,
                                                  __bf16* __restrict__ Qt,
                                                  __bf16* __restrict__ Kt,
                                                  __bf16* __restrict__ Vt) {
  const int tx = blockIdx.x;
  const int b = blockIdx.y;
  int role, hd, nt;
  if (tx < 64) { role = 0; hd = tx >> 4; nt = tx & 15; }
  else if (tx < 100) { role = 1; const int i = tx - 64; hd = i / 9; nt = i - hd * 9; }
  else { role = 2; const int i = tx - 100; hd = i / 9; nt = i - hd * 9; }
  const int n0 = nt * 128;
  const int bo = hd * 192 + role * 64;
  const __bf16* Xb = X + (size_t)b * 524288;

  __shared__ __align__(16) char smem[30720];
  __bf16 (*Ot)[72] = (__bf16(*)[72])smem;
  __bf16 (*Ot2)[136] = (__bf16(*)[136])smem;

  const int tid = threadIdx.x, lane = tid & 63, wv = tid >> 6;
  const int quad = lane >> 4, q16 = lane & 15, wn = wv * 32;

  const int rowA = tid >> 2, chA = (tid & 3) * 8;
  const int browB0 = tid >> 2, bchB = (tid & 3) * 8;
  const float* wA = W + (size_t)(bo + rowA) * 256 + chA;

  const int s0r = n0 + browB0, s1r = n0 + browB0 + 64;
  const int pn0 = (role == 0) ? s0r : slot2n(s0r);
  const int pn1 = (role == 0) ? s1r : slot2n(s1r);

  float4 aP0 = *(const float4*)(wA);
  float4 aP1 = *(const float4*)(wA + 4);
  uint4 bP0 = *(const uint4*)(Xb + (size_t)pn0 * 256 + bchB);
  uint4 bP1 = *(const uint4*)(Xb + (size_t)pn1 * 256 + bchB);

  f32x4 acc[4][2] = {};
  int bsel = 0;
  for (int k0 = 0; k0 < 256; k0 += 32) {
    char* const Ab = smem + bsel;
    char* const Bb = smem + bsel + 5120;
    {
      union { uint4 u; __bf16 h[8]; } pa;
      pa.h[0] = (__bf16)aP0.x; pa.h[1] = (__bf16)aP0.y;
      pa.h[2] = (__bf16)aP0.z; pa.h[3] = (__bf16)aP0.w;
      pa.h[4] = (__bf16)aP1.x; pa.h[5] = (__bf16)aP1.y;
      pa.h[6] = (__bf16)aP1.z; pa.h[7] = (__bf16)aP1.w;
      *(uint4*)(Ab + rowA * 80 + chA * 2) = pa.u;
      *(uint4*)(Bb + browB0 * 80 + bchB * 2) = bP0;
      *(uint4*)(Bb + (browB0 + 64) * 80 + bchB * 2) = bP1;
    }
    __syncthreads();
    if (k0 + 32 < 256) {
      const int kn = k0 + 32;
      aP0 = *(const float4*)(wA + kn);
      aP1 = *(const float4*)(wA + kn + 4);
      bP0 = *(const uint4*)(Xb + (size_t)pn0 * 256 + kn + bchB);
      bP1 = *(const uint4*)(Xb + (size_t)pn1 * 256 + kn + bchB);
    }
    bf16x8 af[4], bfr[2];
#pragma unroll
    for (int mt = 0; mt < 4; ++mt)
      af[mt] = *(const bf16x8*)(Ab + (mt * 16 + q16) * 80 + quad * 16);
#pragma unroll
    for (int jn = 0; jn < 2; ++jn)
      bfr[jn] = *(const bf16x8*)(Bb + (wn + jn * 16 + q16) * 80 + quad * 16);
#pragma unroll
    for (int mt = 0; mt < 4; ++mt)
#pragma unroll
      for (int jn = 0; jn < 2; ++jn)
        acc[mt][jn] = __builtin_amdgcn_mfma_f32_16x16x32_bf16(af[mt], bfr[jn], acc[mt][jn], 0, 0, 0);
    bsel ^= 15360;
  }
  __syncthreads();

  const int bh = b * 4 + hd;
  if (role == 2) {
#pragma unroll
    for (int mt = 0; mt < 4; ++mt)
#pragma unroll
      for (int r = 0; r < 4; ++r) {
        const int c = mt * 16 + quad * 4 + r;
        const float bv = bias[bo + c];
#pragma unroll
        for (int jn = 0; jn < 2; ++jn)
          Ot2[c][wn + jn * 16 + q16] = (__bf16)(acc[mt][jn][r] + bv);
      }
    __syncthreads();
    __bf16* dst = Vt + (size_t)bh * 73728;  // [c][1152]
    for (int i = tid; i < 1024; i += 256) {
      const int c = i >> 4, sg = (i & 15) * 8;
      *(uint4*)(dst + (size_t)c * 1152 + n0 + sg) = *(const uint4*)&Ot2[c][sg];
    }
  } else {
    __bf16* dst = (role == 0 ? Qt + (size_t)bh * 131072
                             : Kt + (size_t)bh * 73728);  // [n][64]
#pragma unroll
    for (int mt = 0; mt < 4; ++mt)
#pragma unroll
      for (int r = 0; r < 4; ++r) {
        const int c = mt * 16 + quad * 4 + r;
        const float bv = bias[bo + c];
#pragma unroll
        for (int jn = 0; jn < 2; ++jn)
          Ot[wn + jn * 16 + q16][c] = (__bf16)(acc[mt][jn][r] + bv);
      }
    __syncthreads();
    for (int i = tid; i < 1024; i += 256) {
      const int nl = i >> 3, cch = (i & 7) * 8;
      *(uint4*)(dst + (size_t)(n0 + nl) * 64 + cch) = *(const uint4*)&Ot[nl][cch];
    }
    if (role == 0 && tid < 128) {
      const float* ukp = uk + (size_t)bh * 64;
      float dv = 0.f;
#pragma unroll
      for (int g8 = 0; g8 < 8; ++g8) {
        const bf16x8 qv = *(const bf16x8*)&Ot[tid][g8 * 8];
#pragma unroll
        for (int k = 0; k < 8; ++k) dv += (float)qv[k] * ukp[g8 * 8 + k];
      }
      dq[(size_t)bh * 2048 + n0 + tid] = dv * (2.0f * C1_EXP);
    }
  }
}

// ---------------------------------------------------------------------------
// Kernel 5: MFMA flash attention. r19: r18's double-buffer schedule
// (1 barrier/iter) with COMPILE-TIME buffer selection. r18 mutated the
// swizzled LDS pointer arrays every iteration -> scratch spills (rule #20;
// evidence: WRITE_SIZE 25->35MB, VGPR 64, dur +10us). Here all pointer
// arrays are const; RSEL in {0,4096} is a template arg added at the use
// site (folds into the ds offset immediate). Main loop = even/odd pairs.
// LDS: K0@0 K1@4096 V0@8192 V1@12288 P@16384 => 24576 B (4 blocks/CU).
// ---------------------------------------------------------------------------
template <bool EDGE, int RSEL>
__device__ __forceinline__ void attn_iter(
    const int s0, const int send, const int quad,
    const __bf16* __restrict__ kg, const __bf16* __restrict__ vg,
    char* const kw, char* const vw,
    const char* const (&krp)[2][2], const char* const (&vrp)[4],
    char* const (&pwp)[2][2], const char* const (&prp)[2],
    const bf16x8 (&bq)[2][2], const float (&Dm)[2],
    uint4& kA, uint4& vA, f32x4 (&oacc)[2][4],
    float (&lsum)[2], float (&spsum)[2]) {
  constexpr int WSEL = RSEL ^ 4096;  // idle buffer

  // QK^T from current (RSEL) buffers
  f32x4 sacc[2][2] = {};
  __builtin_amdgcn_s_setprio(1);
#pragma unroll
  for (int j = 0; j < 2; ++j)
#pragma unroll
    for (int kk = 0; kk < 2; ++kk) {
      const bf16x8 ak = *(const bf16x8*)(krp[j][kk] + RSEL);
      sacc[0][j] = __builtin_amdgcn_mfma_f32_16x16x32_bf16(ak, bq[0][kk], sacc[0][j], 0, 0, 0);
      sacc[1][j] = __builtin_amdgcn_mfma_f32_16x16x32_bf16(ak, bq[1][kk], sacc[1][j], 0, 0, 0);
    }
  __builtin_amdgcn_s_setprio(0);

  // stage tile t+1 into the idle buffer (disjoint from readers; no barrier)
  if (s0 + 32 < send) {
    *(uint4*)(kw + WSEL) = kA;
    *(uint4*)(vw + WSEL) = vA;
  }
  // prefetch tile t+2 into regs (HBM latency hides under softmax+PV)
  if (s0 + 64 < send) {
    kA = *(const uint4*)(kg + (size_t)(s0 + 64) * 64);
    vA = *(const uint4*)(vg + s0 + 64);
  }

#pragma unroll
  for (int b = 0; b < 2; ++b) {
    float lacc = 0.f, spacc = 0.f;
#pragma unroll
    for (int j = 0; j < 2; ++j) {
      float B0, B2, Bv1, Bv3, Bm1, Bm3;
      if (EDGE) {
        const int sg = s0 + j * 16 + quad * 4;
        B0 = (sg < 1020) ? (1.0f - C2_EXP) : ((sg < 1028) ? -C2_EXP : -1e30f);
        B2 = (sg + 2 < 1020) ? (1.0f - C2_EXP)
                             : ((sg + 2 < 1028) ? -C2_EXP : -1e30f);
        Bv1 = (sg + 1 < 1028) ? -C2_EXP : -1e30f;
        Bv3 = (sg + 3 < 1028) ? -C2_EXP : -1e30f;
        Bm1 = (sg + 1 < 1020) ? Dm[b] : -1e30f;
        Bm3 = (sg + 3 < 1020) ? Dm[b] : -1e30f;
      } else {
        B0 = 1.0f - C2_EXP;
        B2 = 1.0f - C2_EXP;
        Bv1 = -C2_EXP;
        Bv3 = -C2_EXP;
        Bm1 = Dm[b];
        Bm3 = Dm[b];
      }
      const float P0  = __builtin_amdgcn_exp2f(fmaf(sacc[b][j][0],  C1_EXP, B0));
      const float Pv1 = __builtin_amdgcn_exp2f(fmaf(sacc[b][j][1],  C1_EXP, Bv1));
      const float P2  = __builtin_amdgcn_exp2f(fmaf(sacc[b][j][2],  C1_EXP, B2));
      const float Pv3 = __builtin_amdgcn_exp2f(fmaf(sacc[b][j][3],  C1_EXP, Bv3));
      const float pm1 = __builtin_amdgcn_exp2f(fmaf(sacc[b][j][1], -C1_EXP, Bm1));
      const float pm3 = __builtin_amdgcn_exp2f(fmaf(sacc[b][j][3], -C1_EXP, Bm3));
      const float mm = pm1 + pm3;
      lacc += (P0 + P2) + (Pv1 + Pv3) + mm;
      spacc += mm;
      union { uint2 u; __bf16 h[4]; } pk;
      pk.h[0] = (__bf16)P0;
      pk.h[1] = (__bf16)(Pv1 - pm1);
      pk.h[2] = (__bf16)P2;
      pk.h[3] = (__bf16)(Pv3 - pm3);
      *(uint2*)pwp[b][j] = pk.u;
    }
    lsum[b] += lacc;
    spsum[b] += spacc;
  }
  asm volatile("" ::: "memory");

  bf16x8 bp[2];
  bp[0] = *(const bf16x8*)prp[0];
  bp[1] = *(const bf16x8*)prp[1];
  __builtin_amdgcn_s_setprio(1);
#pragma unroll
  for (int jc = 0; jc < 4; ++jc) {
    const bf16x8 av = *(const bf16x8*)(vrp[jc] + RSEL);
    oacc[0][jc] = __builtin_amdgcn_mfma_f32_16x16x32_bf16(av, bp[0], oacc[0][jc], 0, 0, 0);
    oacc[1][jc] = __builtin_amdgcn_mfma_f32_16x16x32_bf16(av, bp[1], oacc[1][jc], 0, 0, 0);
  }
  __builtin_amdgcn_s_setprio(0);
  __syncthreads();
}

__global__ __launch_bounds__(256, 4) void k_attn_mfma(const __bf16* __restrict__ Qt,
                                                      const __bf16* __restrict__ Kt,
                                                      const __bf16* __restrict__ Vt,
                                                      const float* __restrict__ dq,
                                                      const float* __restrict__ uv,
                                                      __bf16* __restrict__ opart,
                                                      float* __restrict__ lpart) {
  const int t0 = blockIdx.x * 128;
  const int part = blockIdx.y;  // 0..2
  const int bh = blockIdx.z;
  const __bf16* kt = Kt + (size_t)bh * 73728;
  const __bf16* vt = Vt + (size_t)bh * 73728;

  __shared__ __align__(16) char smem[24576];

  const int tid = threadIdx.x, lane = tid & 63, wv = tid >> 6;
  const int quad = lane >> 4, q16 = lane & 15;
  const int wband = wv * 32;

  const int rK = tid >> 3, gK = tid & 7;
  char* const kw = smem + rK * 128 + ((gK ^ (rK & 7)) * 16);
  const int cV = tid >> 2, gV = tid & 3;
  char* const vw = smem + 8192 + (cV >> 1) * 128 +
                   ((((cV & 1) * 4 + gV) ^ ((cV >> 1) & 7)) * 16);
  const __bf16* const kg = kt + (size_t)rK * 64 + gK * 8;
  const __bf16* const vg = vt + (size_t)cV * 1152 + gV * 8;

  const char* krp[2][2];
#pragma unroll
  for (int j = 0; j < 2; ++j)
#pragma unroll
    for (int kk = 0; kk < 2; ++kk)
      krp[j][kk] = smem + (j * 16 + q16) * 128 + (((kk * 4 + quad) ^ (q16 & 7)) * 16);
  const int a7 = (q16 >> 1) & 7, p1 = q16 & 1;
  const char* vrp[4];
#pragma unroll
  for (int jc = 0; jc < 4; ++jc)
    vrp[jc] = smem + 8192 + (jc * 8 + (q16 >> 1)) * 128 +
              (((p1 * 4 + quad) ^ a7) * 16);
  char* pwp[2][2];
  const char* prp[2];
#pragma unroll
  for (int b = 0; b < 2; ++b) {
    const int mrow = ((wband + b * 16) >> 1) + (q16 >> 1);
    prp[b] = smem + 16384 + mrow * 128 + (((p1 * 4 + quad) ^ a7) * 16);
#pragma unroll
    for (int j = 0; j < 2; ++j)
      pwp[b][j] = smem + 16384 + mrow * 128 +
                  (((p1 * 4 + j * 2 + (quad >> 1)) ^ a7) * 16) + (quad & 1) * 8;
  }

  const __bf16* qbase = Qt + (size_t)bh * 131072;
  bf16x8 bq[2][2];
  float Dm[2];
#pragma unroll
  for (int b = 0; b < 2; ++b) {
    const int t = t0 + wband + b * 16 + q16;
    const __bf16* qp = qbase + (size_t)t * 64 + quad * 8;
    bq[b][0] = *(const bf16x8*)qp;
    bq[b][1] = *(const bf16x8*)(qp + 32);
    Dm[b] = dq[(size_t)bh * 2048 + t] - C2_EXP;
  }

  f32x4 oacc[2][4] = {};
  float lsum[2] = {0.f, 0.f};
  float spsum[2] = {0.f, 0.f};

  const int sbase = part * 352, send = sbase + 352;

  // prologue: tile 0 -> buf0; prefetch tile 1 into regs; one barrier.
  uint4 kA = *(const uint4*)(kg + (size_t)sbase * 64);
  uint4 vA = *(const uint4*)(vg + sbase);
  *(uint4*)kw = kA;
  *(uint4*)vw = vA;
  kA = *(const uint4*)(kg + (size_t)(sbase + 32) * 64);
  vA = *(const uint4*)(vg + sbase + 32);
  __syncthreads();

  // 11 iterations per part. part 0/1: all interior (5 pairs + 1 tail).
  // part 2: 9 interior (4 pairs + 1 tail) + 2 edge (guards live from
  // slot 1020; s0=960 still interior since 960+31 < 1020... (991<1020)).
  int s0 = sbase;
  if (part != 2) {
#pragma unroll 1
    for (int p = 0; p < 5; ++p) {
      attn_iter<false, 0>(s0, send, quad, kg, vg, kw, vw, krp, vrp, pwp, prp,
                          bq, Dm, kA, vA, oacc, lsum, spsum);
      attn_iter<false, 4096>(s0 + 32, send, quad, kg, vg, kw, vw, krp, vrp,
                             pwp, prp, bq, Dm, kA, vA, oacc, lsum, spsum);
      s0 += 64;
    }
    attn_iter<false, 0>(s0, send, quad, kg, vg, kw, vw, krp, vrp, pwp, prp,
                        bq, Dm, kA, vA, oacc, lsum, spsum);
  } else {
#pragma unroll 1
    for (int p = 0; p < 4; ++p) {
      attn_iter<false, 0>(s0, send, quad, kg, vg, kw, vw, krp, vrp, pwp, prp,
                          bq, Dm, kA, vA, oacc, lsum, spsum);
      attn_iter<false, 4096>(s0 + 32, send, quad, kg, vg, kw, vw, krp, vrp,
                             pwp, prp, bq, Dm, kA, vA, oacc, lsum, spsum);
      s0 += 64;
    }
    attn_iter<false, 0>(s0, send, quad, kg, vg, kw, vw, krp, vrp, pwp, prp,
                        bq, Dm, kA, vA, oacc, lsum, spsum);
    attn_iter<true, 4096>(s0 + 32, send, quad, kg, vg, kw, vw, krp, vrp,
                          pwp, prp, bq, Dm, kA, vA, oacc, lsum, spsum);
    attn_iter<true, 0>(s0 + 64, send, quad, kg, vg, kw, vw, krp, vrp,
                       pwp, prp, bq, Dm, kA, vA, oacc, lsum, spsum);
  }

  // epilogue-only uv load (kept out of the loop-live register set)
  float4 uv4[4];
  {
    const float* uvp = uv + (size_t)bh * 64;
#pragma unroll
    for (int jc = 0; jc < 4; ++jc)
      uv4[jc] = *(const float4*)(uvp + jc * 16 + quad * 4);
  }

#pragma unroll
  for (int b = 0; b < 2; ++b) {
    float l = lsum[b], sp = spsum[b];
    l += __shfl_xor(l, 16);
    l += __shfl_xor(l, 32);
    sp += __shfl_xor(sp, 16);
    sp += __shfl_xor(sp, 32);
    const float sp2 = 2.0f * sp;
    const int t = t0 + wband + b * 16 + q16;
    const size_t row = (size_t)(bh * 3 + part) * 2048 + t;
    if (quad == 0) lpart[row] = l;
    __bf16* opp = opart + row * 64;
#pragma unroll
    for (int jc = 0; jc < 4; ++jc) {
      union { uint2 u; __bf16 h[4]; } pk;
      pk.h[0] = (__bf16)(oacc[b][jc][0] + sp2 * uv4[jc].x);
      pk.h[1] = (__bf16)(oacc[b][jc][1] + sp2 * uv4[jc].y);
      pk.h[2] = (__bf16)(oacc[b][jc][2] + sp2 * uv4[jc].z);
      pk.h[3] = (__bf16)(oacc[b][jc][3] + sp2 * uv4[jc].w);
      *(uint2*)(opp + jc * 16 + quad * 4) = pk.u;
    }
  }
}

// ---------------------------------------------------------------------------
// Kernel 6: proj GEMM (bf16 MFMA), double-buffered, fused 3-way combine;
// unchanged.
// ---------------------------------------------------------------------------
__global__ __launch_bounds__(256) void k_gemm_proj(const float* __restrict__ W,
                                                   const __bf16* __restrict__ opart,
                                                   const float* __restrict__ lpart,
                                                   const float* __restrict__ bias,
                                                   float* __restrict__ C) {
  const int n0 = blockIdx.x * 128;
  const int bo = blockIdx.y * 64;
  const int b = blockIdx.z;
  float* Cb = C + (size_t)b * 524288;

  __shared__ __align__(16) char smem[30720];

  const int tid = threadIdx.x, lane = tid & 63, wv = tid >> 6;
  const int quad = lane >> 4, q16 = lane & 15, wn = wv * 32;

  const int rowA = tid >> 2, chA = (tid & 3) * 8;
  const int browB0 = tid >> 2, bchB = (tid & 3) * 8;
  const float* wA = W + (size_t)(bo + rowA) * 256 + chA;

  float linv[2][4];
#pragma unroll
  for (int g = 0; g < 2; ++g) {
    const int t = n0 + browB0 + g * 64;
#pragma unroll
    for (int hd = 0; hd < 4; ++hd) {
      const size_t rr = (size_t)((b * 4 + hd) * 3) * 2048 + t;
      linv[g][hd] = 1.0f / (lpart[rr] + lpart[rr + 2048] + lpart[rr + 4096]);
    }
  }

  float4 aP0 = *(const float4*)(wA);
  float4 aP1 = *(const float4*)(wA + 4);
  bf16x8 oP[2][3];
#pragma unroll
  for (int g = 0; g < 2; ++g) {
    const int t = n0 + browB0 + g * 64;
    const size_t rr = (size_t)(b * 4 * 3) * 2048 + t;
#pragma unroll
    for (int p = 0; p < 3; ++p)
      oP[g][p] = *(const bf16x8*)(opart + (rr + p * 2048) * 64 + bchB);
  }

  f32x4 acc[4][2] = {};
  int bsel = 0;
  for (int k0 = 0; k0 < 256; k0 += 32) {
    char* const Ab = smem + bsel;
    char* const Bb = smem + bsel + 5120;
    {
      union { uint4 u; __bf16 h[8]; } pa;
      pa.h[0] = (__bf16)aP0.x; pa.h[1] = (__bf16)aP0.y;
      pa.h[2] = (__bf16)aP0.z; pa.h[3] = (__bf16)aP0.w;
      pa.h[4] = (__bf16)aP1.x; pa.h[5] = (__bf16)aP1.y;
      pa.h[6] = (__bf16)aP1.z; pa.h[7] = (__bf16)aP1.w;
      *(uint4*)(Ab + rowA * 80 + chA * 2) = pa.u;
      const int hd = (k0 + bchB) >> 6;
#pragma unroll
      for (int g = 0; g < 2; ++g) {
        const float inv = linv[g][hd];
        bf16x8 res;
#pragma unroll
        for (int k = 0; k < 8; ++k)
          res[k] = (__bf16)((((float)oP[g][0][k] + (float)oP[g][1][k]) +
                             (float)oP[g][2][k]) * inv);
        *(bf16x8*)(Bb + (browB0 + g * 64) * 80 + bchB * 2) = res;
      }
    }
    __syncthreads();
    if (k0 + 32 < 256) {
      const int kn = k0 + 32;
      aP0 = *(const float4*)(wA + kn);
      aP1 = *(const float4*)(wA + kn + 4);
      const int c = kn + bchB;
      const int hd = c >> 6, cu = c & 63;
#pragma unroll
      for (int g = 0; g < 2; ++g) {
        const int t = n0 + browB0 + g * 64;
        const size_t rr = (size_t)((b * 4 + hd) * 3) * 2048 + t;
#pragma unroll
        for (int p = 0; p < 3; ++p)
          oP[g][p] = *(const bf16x8*)(opart + (rr + p * 2048) * 64 + cu);
      }
    }
    bf16x8 af[4], bfr[2];
#pragma unroll
    for (int mt = 0; mt < 4; ++mt)
      af[mt] = *(const bf16x8*)(Ab + (mt * 16 + q16) * 80 + quad * 16);
#pragma unroll
    for (int jn = 0; jn < 2; ++jn)
      bfr[jn] = *(const bf16x8*)(Bb + (wn + jn * 16 + q16) * 80 + quad * 16);
#pragma unroll
    for (int mt = 0; mt < 4; ++mt)
#pragma unroll
      for (int jn = 0; jn < 2; ++jn)
        acc[mt][jn] = __builtin_amdgcn_mfma_f32_16x16x32_bf16(af[mt], bfr[jn], acc[mt][jn], 0, 0, 0);
    bsel ^= 15360;
  }

#pragma unroll
  for (int mt = 0; mt < 4; ++mt)
#pragma unroll
    for (int r = 0; r < 4; ++r) {
      const int o = bo + mt * 16 + quad * 4 + r;
      const float bv = bias[o];
#pragma unroll
      for (int jn = 0; jn < 2; ++jn)
        Cb[(size_t)o * 2048 + n0 + wn + jn * 16 + q16] = acc[mt][jn][r] + bv;
    }
}

// ---------------------------------------------------------------------------
// Kernel 7: inverse FFT2 via split-bf16 MFMA. One slice per wave (r14 form),
// spec global loads issued before table staging.
// ---------------------------------------------------------------------------
__global__ __launch_bounds__(256) void k_ifft2(const float* __restrict__ spec,
                                               float* __restrict__ out,
                                               const __bf16* __restrict__ tw) {
  __shared__ __align__(16) char smem[51200];
  const int tid = threadIdx.x, lane = tid & 63, wv = tid >> 6;
  const int quad = lane >> 4, q16 = lane & 15;
  const int slice = blockIdx.x * 4 + wv;
  char* const wr_ = smem + 10240 + wv * 10240;

  // early spec global loads
  const float* sp = spec + (size_t)slice * 2048;
  float4 sv8[8];
#pragma unroll
  for (int u = 0; u < 8; ++u) sv8[u] = ((const float4*)sp)[u * 64 + lane];

  for (int i = tid; i < 512; i += 256) {
    const int t = i >> 7, r = (i >> 2) & 31, c8 = (i & 3) * 8;
    *(uint4*)(smem + t * 2560 + r * 80 + c8 * 2) =
        *(const uint4*)(tw + t * 1024 + r * 32 + c8);
  }

#pragma unroll
  for (int u = 0; u < 8; ++u) {
    const int f = u * 64 + lane;  // 0..511 float4 (2 complex each)
    const float4 v = sv8[u];
    const int k1 = f >> 4, k2 = (f & 15) * 2;
    char* base = wr_ + k1 * 80 + k2 * 2;
    union { unsigned int w; __bf16 b[2]; } p;
    const __bf16 rh0 = (__bf16)v.x, rh1 = (__bf16)v.z;
    const __bf16 ih0 = (__bf16)v.y, ih1 = (__bf16)v.w;
    p.b[0] = rh0; p.b[1] = rh1; *(unsigned int*)(base) = p.w;
    p.b[0] = (__bf16)(v.x - (float)rh0);
    p.b[1] = (__bf16)(v.z - (float)rh1); *(unsigned int*)(base + 2560) = p.w;
    p.b[0] = ih0; p.b[1] = ih1; *(unsigned int*)(base + 5120) = p.w;
    p.b[0] = (__bf16)(v.y - (float)ih0);
    p.b[1] = (__bf16)(v.w - (float)ih1); *(unsigned int*)(base + 7680) = p.w;
  }
  __syncthreads();  // tables visible; X same-wave ordered

  bf16x8 cch[2], ccl[2], ssh[2], ssl[2], ssnh[2], ssnl[2];
  bf16x8 xreh[2], xrel[2], ximh[2], ximl[2];
#pragma unroll
  for (int t2 = 0; t2 < 2; ++t2) {
    const int row = t2 * 16 + q16;
    cch[t2] = *(const bf16x8*)(smem + row * 80 + quad * 16);
    ccl[t2] = *(const bf16x8*)(smem + 2560 + row * 80 + quad * 16);
    ssh[t2] = *(const bf16x8*)(smem + 5120 + row * 80 + quad * 16);
    ssl[t2] = *(const bf16x8*)(smem + 7680 + row * 80 + quad * 16);
    xreh[t2] = *(const bf16x8*)(wr_ + row * 80 + quad * 16);
    xrel[t2] = *(const bf16x8*)(wr_ + 2560 + row * 80 + quad * 16);
    ximh[t2] = *(const bf16x8*)(wr_ + 5120 + row * 80 + quad * 16);
    ximl[t2] = *(const bf16x8*)(wr_ + 7680 + row * 80 + quad * 16);
  }
  ssnh[0] = neg8(ssh[0]); ssnh[1] = neg8(ssh[1]);
  ssnl[0] = neg8(ssl[0]); ssnl[1] = neg8(ssl[1]);

  // pass 1
  f32x4 yre[2][2] = {}, yim[2][2] = {};
#pragma unroll
  for (int mt = 0; mt < 2; ++mt)
#pragma unroll
    for (int nt = 0; nt < 2; ++nt) {
      MFMA3(yre[mt][nt], xreh[mt], xrel[mt], cch[nt], ccl[nt]);
      MFMA3(yre[mt][nt], ximh[mt], ximl[mt], ssnh[nt], ssnl[nt]);
      MFMA3(yim[mt][nt], xreh[mt], xrel[mt], ssh[nt], ssl[nt]);
      MFMA3(yim[mt][nt], ximh[mt], ximl[mt], cch[nt], ccl[nt]);
    }

  // write Yt transposed + split over the X regions (wave-private)
#pragma unroll
  for (int mt = 0; mt < 2; ++mt)
#pragma unroll
    for (int nt = 0; nt < 2; ++nt) {
      char* base = wr_ + (nt * 16 + q16) * 80 + (mt * 16 + quad * 4) * 2;
      union { unsigned long long q; __bf16 b[4]; } h, l;
#pragma unroll
      for (int r = 0; r < 4; ++r) {
        const float v = yre[mt][nt][r];
        h.b[r] = (__bf16)v; l.b[r] = (__bf16)(v - (float)h.b[r]);
      }
      *(unsigned long long*)(base) = h.q;
      *(unsigned long long*)(base + 2560) = l.q;
#pragma unroll
      for (int r = 0; r < 4; ++r) {
        const float v = yim[mt][nt][r];
        h.b[r] = (__bf16)v; l.b[r] = (__bf16)(v - (float)h.b[r]);
      }
      *(unsigned long long*)(base + 5120) = h.q;
      *(unsigned long long*)(base + 7680) = l.q;
    }
  asm volatile("" ::: "memory");

  bf16x8 yreh[2], yrel[2], yimh[2], yiml[2];
#pragma unroll
  for (int nt = 0; nt < 2; ++nt) {
    const int row = nt * 16 + q16;
    yreh[nt] = *(const bf16x8*)(wr_ + row * 80 + quad * 16);
    yrel[nt] = *(const bf16x8*)(wr_ + 2560 + row * 80 + quad * 16);
    yimh[nt] = *(const bf16x8*)(wr_ + 5120 + row * 80 + quad * 16);
    yiml[nt] = *(const bf16x8*)(wr_ + 7680 + row * 80 + quad * 16);
  }

  // pass 2
  f32x4 zre[2][2] = {}, zim[2][2] = {};
#pragma unroll
  for (int mt = 0; mt < 2; ++mt)
#pragma unroll
    for (int nt = 0; nt < 2; ++nt) {
      MFMA3(zre[mt][nt], cch[mt], ccl[mt], yreh[nt], yrel[nt]);
      MFMA3(zre[mt][nt], ssnh[mt], ssnl[mt], yimh[nt], yiml[nt]);
      MFMA3(zim[mt][nt], cch[mt], ccl[mt], yimh[nt], yiml[nt]);
      MFMA3(zim[mt][nt], ssh[mt], ssl[mt], yreh[nt], yrel[nt]);
    }

  float* op = out + (size_t)slice * 2048;
#pragma unroll
  for (int mt = 0; mt < 2; ++mt)
#pragma unroll
    for (int nt = 0; nt < 2; ++nt)
#pragma unroll
      for (int r = 0; r < 4; ++r) {
        const int n1 = mt * 16 + quad * 4 + r;
        const int n2 = nt * 16 + q16;
        float2 st;
        st.x = zre[mt][nt][r] * (1.0f / 1024.0f);
        st.y = zim[mt][nt][r] * (1.0f / 1024.0f);
        *(float2*)(op + 2 * (n1 * 32 + n2)) = st;
      }
}

// ---------------------------------------------------------------------------
extern "C" void kernel_launch(void* const* d_in, const int* in_sizes, int n_in,
                              void* d_out, int out_size, void* d_ws, size_t ws_size,
                              hipStream_t stream) {
  (void)in_sizes; (void)n_in; (void)out_size; (void)ws_size;
  const float* x      = (const float*)d_in[0];
  const float* gn_w   = (const float*)d_in[1];
  const float* gn_b   = (const float*)d_in[2];
  const float* qkv_w  = (const float*)d_in[3];
  const float* qkv_b  = (const float*)d_in[4];
  const float* proj_w = (const float*)d_in[5];
  const float* proj_b = (const float*)d_in[6];
  float* out = (float*)d_out;

  float* spec  = (float*)d_ws;
  __bf16* Qt   = (__bf16*)(spec + 4194304);   // 4194304 elems
  __bf16* Kt   = Qt + 4194304;                // 2359296 elems (32*1152*64)
  __bf16* Vt   = Kt + 2359296;                // 2359296 elems
  float* stats = (float*)(Vt + 2359296);      // 512
  float* xr    = stats + 512;                 // 4194304 floats
  __bf16* xt   = (__bf16*)(xr + 4194304);     // 4194304 bf16
  __bf16* opart = (__bf16*)xr;                // 12582912 bf16 (clobbers xr+xt)
  float*  lpart = (float*)(opart + 12582912); // 196608
  float*  dq    = lpart + 196608;             // 65536
  float*  uk    = dq + 65536;                 // 2048
  float*  uv    = uk + 2048;                  // 2048
  __bf16* tw    = (__bf16*)(uv + 2048);       // 4096 bf16 twiddle tables

  hipMemsetAsync(stats, 0, 512 * sizeof(float), stream);
  k_twid<<<1, 256, 0, stream>>>(tw);
  k_fft2<<<512, 256, 0, stream>>>(x, xr, stats, tw);
  k_uvec<<<64, 256, 0, stream>>>(stats, gn_w, gn_b, qkv_w, qkv_b, uk, uv);
  k_gntrans<<<dim3(32, 4, 8), 256, 0, stream>>>(xr, stats, gn_w, gn_b, xt);
  k_gemm_qkv<<<dim3(136, 8), 256, 0, stream>>>(qkv_w, xt, qkv_b, uk, dq,
                                               Qt, Kt, Vt);
  k_attn_mfma<<<dim3(16, 3, 32), 256, 0, stream>>>(Qt, Kt, Vt, dq, uv,
                                                   opart, lpart);
  k_gemm_proj<<<dim3(16, 4, 8), 256, 0, stream>>>(proj_w, opart, lpart,
                                                  proj_b, spec);
  k_ifft2<<<512, 256, 0, stream>>>(spec, out, tw);
}

// Round 4
// 166.847 us; speedup vs baseline: 1.1453x; 1.1453x over previous
//
#include <hip/hip_runtime.h>
#include <hip/hip_bf16.h>
#include <stdint.h>

#define PI_F 3.14159265358979323846f
#define C1_EXP 0.18033688f   // log2(e)/8
#define C2_EXP 23.083120f    // 16*log2(e)

typedef __bf16 bf16x8 __attribute__((ext_vector_type(8)));
typedef float f32x4 __attribute__((ext_vector_type(4)));
typedef unsigned int uint32x4 __attribute__((ext_vector_type(4)));

// LDS-only barrier: s_barrier with lgkmcnt drain but NO vmcnt drain, so
// in-flight global prefetch loads survive across the barrier (T4-minimal).
// Correctness: all cross-wave data here is LDS (K/V tiles); ds ops are
// tracked by lgkmcnt. The "memory" clobber stops compiler reordering of
// memory ops across the barrier; in-register global load results keep
// their normal data-dependency vmcnt waits at the consumer.
#define BAR_LDS() asm volatile("s_waitcnt lgkmcnt(0)\n\ts_barrier" ::: "memory")

__device__ __forceinline__ bf16x8 neg8(bf16x8 v) {
  union { bf16x8 b; uint32x4 u; } x;
  x.b = v;
  x.u ^= (uint32x4){0x80008000u, 0x80008000u, 0x80008000u, 0x80008000u};
  return x.b;
}

// 3-term split-accumulate: P*Q with P=Ph+Pl, Q=Qh+Ql (drop Pl*Ql ~2^-18)
#define MFMA3(acc, Ph, Pl, Qh, Ql)                                        \
  acc = __builtin_amdgcn_mfma_f32_16x16x32_bf16(Ph, Qh, acc, 0, 0, 0);    \
  acc = __builtin_amdgcn_mfma_f32_16x16x32_bf16(Ph, Ql, acc, 0, 0, 0);    \
  acc = __builtin_amdgcn_mfma_f32_16x16x32_bf16(Pl, Qh, acc, 0, 0, 0);

// Closed-form base-slot -> original column mapping.
__device__ __forceinline__ int slot2n(int slot) {
  const int pi = slot >> 1, im = slot & 1;
  int k1, k2;
  if (pi < 480)      { k1 = 1 + (pi >> 5); k2 = pi & 31; }
  else if (pi < 495) { k1 = 0;  k2 = pi - 479; }
  else if (pi < 510) { k1 = 16; k2 = pi - 494; }
  else if (pi < 514) { k1 = ((pi - 510) >> 1) * 16; k2 = ((pi - 510) & 1) * 16; }
  else               { k1 = 0; k2 = 0; }
  return 2 * (k1 * 32 + k2) + im;
}

// ---------------------------------------------------------------------------
// Kernel 0: twiddle tables, hi/lo split bf16.
// ---------------------------------------------------------------------------
__global__ __launch_bounds__(256) void k_twid(__bf16* __restrict__ tw) {
  for (int e = threadIdx.x; e < 1024; e += 256) {
    const int j = e >> 5, k = e & 31;
    const int t = (j * k) & 31;
    float sv, cv;
    sincosf(2.0f * PI_F * (float)t / 32.0f, &sv, &cv);
    const __bf16 ch = (__bf16)cv;
    const __bf16 sh = (__bf16)sv;
    tw[e] = ch;
    tw[1024 + e] = (__bf16)(cv - (float)ch);
    tw[2048 + e] = sh;
    tw[3072 + e] = (__bf16)(sv - (float)sh);
  }
}

// ---------------------------------------------------------------------------
// Kernel 1: forward FFT2 via split-bf16 MFMA. One slice per wave (r14
// measured-best barrier-free form; the r15/r16 2-wave split regressed).
// X global loads issued BEFORE table staging to overlap HBM latency.
// ---------------------------------------------------------------------------
__global__ __launch_bounds__(256) void k_fft2(const float* __restrict__ x,
                                              float* __restrict__ xr,
                                              float* __restrict__ stats_raw,
                                              const __bf16* __restrict__ tw) {
  __shared__ __align__(16) char smem[51200];
  const int tid = threadIdx.x, lane = tid & 63, wv = tid >> 6;
  const int quad = lane >> 4, q16 = lane & 15;
  const int slice = blockIdx.x * 4 + wv;
  char* const wr_ = smem + 10240 + wv * 10240;

  // early X global loads (wave-private region; overlap with table staging)
  const float* xs = x + (size_t)slice * 1024;
  float4 xv[4];
#pragma unroll
  for (int u = 0; u < 4; ++u) xv[u] = ((const float4*)xs)[u * 64 + lane];

  for (int i = tid; i < 512; i += 256) {
    const int t = i >> 7, r = (i >> 2) & 31, c8 = (i & 3) * 8;
    *(uint4*)(smem + t * 2560 + r * 80 + c8 * 2) =
        *(const uint4*)(tw + t * 1024 + r * 32 + c8);
  }

  // X split + stage (same-wave ds ordering)
#pragma unroll
  for (int u = 0; u < 4; ++u) {
    const int f = u * 64 + lane;
    const float4 v = xv[u];
    const int row = f >> 3, c4 = (f & 7) * 4;
    union { unsigned long long q; __bf16 b[4]; } ph, pl;
    ph.b[0] = (__bf16)v.x; ph.b[1] = (__bf16)v.y;
    ph.b[2] = (__bf16)v.z; ph.b[3] = (__bf16)v.w;
    pl.b[0] = (__bf16)(v.x - (float)ph.b[0]);
    pl.b[1] = (__bf16)(v.y - (float)ph.b[1]);
    pl.b[2] = (__bf16)(v.z - (float)ph.b[2]);
    pl.b[3] = (__bf16)(v.w - (float)ph.b[3]);
    *(unsigned long long*)(wr_ + row * 80 + c4 * 2) = ph.q;
    *(unsigned long long*)(wr_ + 2560 + row * 80 + c4 * 2) = pl.q;
  }
  __syncthreads();  // tables visible to all waves; X same-wave ordered

  bf16x8 cch[2], ccl[2], ssh[2], ssl[2], xh[2], xl[2];
#pragma unroll
  for (int t2 = 0; t2 < 2; ++t2) {
    const int row = t2 * 16 + q16;
    cch[t2] = *(const bf16x8*)(smem + row * 80 + quad * 16);
    ccl[t2] = *(const bf16x8*)(smem + 2560 + row * 80 + quad * 16);
    ssh[t2] = *(const bf16x8*)(smem + 5120 + row * 80 + quad * 16);
    ssl[t2] = *(const bf16x8*)(smem + 7680 + row * 80 + quad * 16);
    xh[t2] = *(const bf16x8*)(wr_ + row * 80 + quad * 16);
    xl[t2] = *(const bf16x8*)(wr_ + 2560 + row * 80 + quad * 16);
  }

  // pass 1: Yre = X@Cc, Yim = -(X@Ss)
  f32x4 yre[2][2] = {}, yim[2][2] = {};
#pragma unroll
  for (int mt = 0; mt < 2; ++mt)
#pragma unroll
    for (int nt = 0; nt < 2; ++nt) {
      MFMA3(yre[mt][nt], xh[mt], xl[mt], cch[nt], ccl[nt]);
      MFMA3(yim[mt][nt], xh[mt], xl[mt], ssh[nt], ssl[nt]);
    }

  // write Yt transposed + split (wave-private; same-wave ordering)
#pragma unroll
  for (int mt = 0; mt < 2; ++mt)
#pragma unroll
    for (int nt = 0; nt < 2; ++nt) {
      char* base = wr_ + (nt * 16 + q16) * 80 + (mt * 16 + quad * 4) * 2;
      union { unsigned long long q; __bf16 b[4]; } h, l;
#pragma unroll
      for (int r = 0; r < 4; ++r) {
        const float v = yre[mt][nt][r];
        h.b[r] = (__bf16)v; l.b[r] = (__bf16)(v - (float)h.b[r]);
      }
      *(unsigned long long*)(base) = h.q;
      *(unsigned long long*)(base + 2560) = l.q;
#pragma unroll
      for (int r = 0; r < 4; ++r) {
        const float v = -yim[mt][nt][r];
        h.b[r] = (__bf16)v; l.b[r] = (__bf16)(v - (float)h.b[r]);
      }
      *(unsigned long long*)(base + 5120) = h.q;
      *(unsigned long long*)(base + 7680) = l.q;
    }
  asm volatile("" ::: "memory");

  bf16x8 yreh[2], yrel[2], yimh[2], yiml[2];
#pragma unroll
  for (int nt = 0; nt < 2; ++nt) {
    const int row = nt * 16 + q16;
    yreh[nt] = *(const bf16x8*)(wr_ + row * 80 + quad * 16);
    yrel[nt] = *(const bf16x8*)(wr_ + 2560 + row * 80 + quad * 16);
    yimh[nt] = *(const bf16x8*)(wr_ + 5120 + row * 80 + quad * 16);
    yiml[nt] = *(const bf16x8*)(wr_ + 7680 + row * 80 + quad * 16);
  }

  // pass 2: Zre = Cc@Yre + Ss@Yim ; Zim = Cc@Yim - Ss@Yre
  f32x4 zre[2][2] = {}, zim[2][2] = {};
  bf16x8 ssnh[2], ssnl[2];
  ssnh[0] = neg8(ssh[0]); ssnh[1] = neg8(ssh[1]);
  ssnl[0] = neg8(ssl[0]); ssnl[1] = neg8(ssl[1]);
#pragma unroll
  for (int mt = 0; mt < 2; ++mt)
#pragma unroll
    for (int nt = 0; nt < 2; ++nt) {
      MFMA3(zre[mt][nt], cch[mt], ccl[mt], yreh[nt], yrel[nt]);
      MFMA3(zre[mt][nt], ssh[mt], ssl[mt], yimh[nt], yiml[nt]);
      MFMA3(zim[mt][nt], cch[mt], ccl[mt], yimh[nt], yiml[nt]);
      MFMA3(zim[mt][nt], ssnh[mt], ssnl[mt], yreh[nt], yrel[nt]);
    }

  // stats + store
  float* op = xr + (size_t)slice * 2048;
  float s1 = 0.f, s2 = 0.f;
#pragma unroll
  for (int mt = 0; mt < 2; ++mt)
#pragma unroll
    for (int nt = 0; nt < 2; ++nt)
#pragma unroll
      for (int r = 0; r < 4; ++r) {
        const int k1 = mt * 16 + quad * 4 + r;
        const int k2 = nt * 16 + q16;
        const float a = zre[mt][nt][r], bimg = zim[mt][nt][r];
        s1 += a + bimg;
        s2 += a * a + bimg * bimg;
        float2 st; st.x = a; st.y = bimg;
        *(float2*)(op + 2 * (k1 * 32 + k2)) = st;
      }
#pragma unroll
  for (int off = 1; off <= 32; off <<= 1) {
    s1 += __shfl_xor(s1, off);
    s2 += __shfl_xor(s2, off);
  }
  if (lane == 0) {
    const int bg = (slice >> 8) * 32 + ((slice & 255) >> 3);
    atomicAdd(&stats_raw[bg * 2], s1);
    atomicAdd(&stats_raw[bg * 2 + 1], s2);
  }
}

// ---------------------------------------------------------------------------
// Kernel 2: mirror-correction vectors (coalesced); unchanged.
// ---------------------------------------------------------------------------
__global__ __launch_bounds__(256) void k_uvec(const float* __restrict__ stats_raw,
                                              const float* __restrict__ gn_w,
                                              const float* __restrict__ gn_b,
                                              const float* __restrict__ qkv_w,
                                              const float* __restrict__ qkv_b,
                                              float* __restrict__ uk,
                                              float* __restrict__ uv) {
  const int blk = blockIdx.x;
  const int tid = threadIdx.x;
  const int b = blk >> 3, h = (blk >> 1) & 3, role = blk & 1;
  __shared__ float Bsh[256];
  {
    const int g = tid >> 3;
    const float S = stats_raw[(b * 32 + g) * 2];
    const float S2 = stats_raw[(b * 32 + g) * 2 + 1];
    const float mean = S * (1.0f / 16384.0f);
    const float var = S2 * (1.0f / 16384.0f) - mean * mean;
    const float rstd = rsqrtf(var + 1e-5f);
    Bsh[tid] = gn_b[tid] - mean * rstd * gn_w[tid];
  }
  __syncthreads();
  const int cp = tid >> 2, seg = tid & 3;
  const int row = h * 192 + 64 + role * 64 + cp;
  const float* wr_ = qkv_w + (size_t)row * 256 + seg * 64;
  const float* bs = Bsh + seg * 64;
  float s = 0.f;
#pragma unroll
  for (int i = 0; i < 16; ++i) {
    const float4 w4 = *(const float4*)(wr_ + i * 4);
    const float4 b4 = *(const float4*)(bs + i * 4);
    s += w4.x * b4.x + w4.y * b4.y + w4.z * b4.z + w4.w * b4.w;
  }
  s += __shfl_xor(s, 1);
  s += __shfl_xor(s, 2);
  if (seg == 0) {
    float* dst = (role == 0) ? uk : uv;
    dst[(size_t)(b * 4 + h) * 64 + cp] = s + qkv_b[row];
  }
}

// ---------------------------------------------------------------------------
// Kernel 3: GroupNorm apply + transpose to bf16 X^T [b][n][c]; unchanged.
// ---------------------------------------------------------------------------
__global__ __launch_bounds__(256) void k_gntrans(const float* __restrict__ xr,
                                                 const float* __restrict__ stats_raw,
                                                 const float* __restrict__ w,
                                                 const float* __restrict__ bias,
                                                 __bf16* __restrict__ xt) {
  const int n0 = blockIdx.x * 64;
  const int c0 = blockIdx.y * 64;
  const int b = blockIdx.z;
  __shared__ __bf16 Lt[64][72];
  const int tid = threadIdx.x;
  for (int i = tid; i < 1024; i += 256) {
    const int cl = i >> 4, c = c0 + cl, nl = (i & 15) * 4;
    const float S = stats_raw[(b * 32 + (c >> 3)) * 2];
    const float S2 = stats_raw[(b * 32 + (c >> 3)) * 2 + 1];
    const float mean = S * (1.0f / 16384.0f);
    const float var = S2 * (1.0f / 16384.0f) - mean * mean;
    const float rstd = rsqrtf(var + 1e-5f);
    const float sc = rstd * w[c];
    const float sh = bias[c] - mean * sc;
    const float4 v = *(const float4*)(xr + ((size_t)b * 256 + c) * 2048 + n0 + nl);
    Lt[nl][cl] = (__bf16)(v.x * sc + sh);
    Lt[nl + 1][cl] = (__bf16)(v.y * sc + sh);
    Lt[nl + 2][cl] = (__bf16)(v.z * sc + sh);
    Lt[nl + 3][cl] = (__bf16)(v.w * sc + sh);
  }
  __syncthreads();
  __bf16* dst = xt + (size_t)b * 524288 + (size_t)n0 * 256 + c0;
  for (int i = tid; i < 512; i += 256) {
    const int nl = i >> 3, cch = (i & 7) * 8;
    *(uint4*)(dst + (size_t)nl * 256 + cch) = *(const uint4*)&Lt[nl][cch];
  }
}

// ---------------------------------------------------------------------------
// Kernel 4: QKV GEMM (bf16 MFMA), double-buffered LDS; unchanged.
// ---------------------------------------------------------------------------
__global__ __launch_bounds__(256) void k_gemm_qkv(const float* __restrict__ W,
                                                  const __bf16* __restrict__ X,
                                                  const float* __restrict__ bias,
                                                  const float* __restrict__ uk,
                                                  float* __restrict__ dq,
                                                  __bf16* __restrict__ Qt,
                                                  __bf16* __restrict__ Kt,
                                                  __bf16* __restrict__ Vt) {
  const int tx = blockIdx.x;
  const int b = blockIdx.y;
  int role, hd, nt;
  if (tx < 64) { role = 0; hd = tx >> 4; nt = tx & 15; }
  else if (tx < 100) { role = 1; const int i = tx - 64; hd = i / 9; nt = i - hd * 9; }
  else { role = 2; const int i = tx - 100; hd = i / 9; nt = i - hd * 9; }
  const int n0 = nt * 128;
  const int bo = hd * 192 + role * 64;
  const __bf16* Xb = X + (size_t)b * 524288;

  __shared__ __align__(16) char smem[30720];
  __bf16 (*Ot)[72] = (__bf16(*)[72])smem;
  __bf16 (*Ot2)[136] = (__bf16(*)[136])smem;

  const int tid = threadIdx.x, lane = tid & 63, wv = tid >> 6;
  const int quad = lane >> 4, q16 = lane & 15, wn = wv * 32;

  const int rowA = tid >> 2, chA = (tid & 3) * 8;
  const int browB0 = tid >> 2, bchB = (tid & 3) * 8;
  const float* wA = W + (size_t)(bo + rowA) * 256 + chA;

  const int s0r = n0 + browB0, s1r = n0 + browB0 + 64;
  const int pn0 = (role == 0) ? s0r : slot2n(s0r);
  const int pn1 = (role == 0) ? s1r : slot2n(s1r);

  float4 aP0 = *(const float4*)(wA);
  float4 aP1 = *(const float4*)(wA + 4);
  uint4 bP0 = *(const uint4*)(Xb + (size_t)pn0 * 256 + bchB);
  uint4 bP1 = *(const uint4*)(Xb + (size_t)pn1 * 256 + bchB);

  f32x4 acc[4][2] = {};
  int bsel = 0;
  for (int k0 = 0; k0 < 256; k0 += 32) {
    char* const Ab = smem + bsel;
    char* const Bb = smem + bsel + 5120;
    {
      union { uint4 u; __bf16 h[8]; } pa;
      pa.h[0] = (__bf16)aP0.x; pa.h[1] = (__bf16)aP0.y;
      pa.h[2] = (__bf16)aP0.z; pa.h[3] = (__bf16)aP0.w;
      pa.h[4] = (__bf16)aP1.x; pa.h[5] = (__bf16)aP1.y;
      pa.h[6] = (__bf16)aP1.z; pa.h[7] = (__bf16)aP1.w;
      *(uint4*)(Ab + rowA * 80 + chA * 2) = pa.u;
      *(uint4*)(Bb + browB0 * 80 + bchB * 2) = bP0;
      *(uint4*)(Bb + (browB0 + 64) * 80 + bchB * 2) = bP1;
    }
    __syncthreads();
    if (k0 + 32 < 256) {
      const int kn = k0 + 32;
      aP0 = *(const float4*)(wA + kn);
      aP1 = *(const float4*)(wA + kn + 4);
      bP0 = *(const uint4*)(Xb + (size_t)pn0 * 256 + kn + bchB);
      bP1 = *(const uint4*)(Xb + (size_t)pn1 * 256 + kn + bchB);
    }
    bf16x8 af[4], bfr[2];
#pragma unroll
    for (int mt = 0; mt < 4; ++mt)
      af[mt] = *(const bf16x8*)(Ab + (mt * 16 + q16) * 80 + quad * 16);
#pragma unroll
    for (int jn = 0; jn < 2; ++jn)
      bfr[jn] = *(const bf16x8*)(Bb + (wn + jn * 16 + q16) * 80 + quad * 16);
#pragma unroll
    for (int mt = 0; mt < 4; ++mt)
#pragma unroll
      for (int jn = 0; jn < 2; ++jn)
        acc[mt][jn] = __builtin_amdgcn_mfma_f32_16x16x32_bf16(af[mt], bfr[jn], acc[mt][jn], 0, 0, 0);
    bsel ^= 15360;
  }
  __syncthreads();

  const int bh = b * 4 + hd;
  if (role == 2) {
#pragma unroll
    for (int mt = 0; mt < 4; ++mt)
#pragma unroll
      for (int r = 0; r < 4; ++r) {
        const int c = mt * 16 + quad * 4 + r;
        const float bv = bias[bo + c];
#pragma unroll
        for (int jn = 0; jn < 2; ++jn)
          Ot2[c][wn + jn * 16 + q16] = (__bf16)(acc[mt][jn][r] + bv);
      }
    __syncthreads();
    __bf16* dst = Vt + (size_t)bh * 73728;  // [c][1152]
    for (int i = tid; i < 1024; i += 256) {
      const int c = i >> 4, sg = (i & 15) * 8;
      *(uint4*)(dst + (size_t)c * 1152 + n0 + sg) = *(const uint4*)&Ot2[c][sg];
    }
  } else {
    __bf16* dst = (role == 0 ? Qt + (size_t)bh * 131072
                             : Kt + (size_t)bh * 73728);  // [n][64]
#pragma unroll
    for (int mt = 0; mt < 4; ++mt)
#pragma unroll
      for (int r = 0; r < 4; ++r) {
        const int c = mt * 16 + quad * 4 + r;
        const float bv = bias[bo + c];
#pragma unroll
        for (int jn = 0; jn < 2; ++jn)
          Ot[wn + jn * 16 + q16][c] = (__bf16)(acc[mt][jn][r] + bv);
      }
    __syncthreads();
    for (int i = tid; i < 1024; i += 256) {
      const int nl = i >> 3, cch = (i & 7) * 8;
      *(uint4*)(dst + (size_t)(n0 + nl) * 64 + cch) = *(const uint4*)&Ot[nl][cch];
    }
    if (role == 0 && tid < 128) {
      const float* ukp = uk + (size_t)bh * 64;
      float dv = 0.f;
#pragma unroll
      for (int g8 = 0; g8 < 8; ++g8) {
        const bf16x8 qv = *(const bf16x8*)&Ot[tid][g8 * 8];
#pragma unroll
        for (int k = 0; k < 8; ++k) dv += (float)qv[k] * ukp[g8 * 8 + k];
      }
      dq[(size_t)bh * 2048 + n0 + tid] = dv * (2.0f * C1_EXP);
    }
  }
}

// ---------------------------------------------------------------------------
// Kernel 5: MFMA flash attention. r20 = EXACT r17 structure (proven 76 VGPR,
// no spill, attn ~41 us) with ONE change: both per-iteration __syncthreads()
// replaced by BAR_LDS() (lgkmcnt-only drain + s_barrier). This preserves the
// global K/V prefetch in flight across the barrier instead of the compiler's
// vmcnt(0) drain (T4-minimal). r18/r19's dbuf restructures both spilled
// (WRITE_SIZE 25->35->72MB) -- schedule shape defeats regalloc; abandoned.
// ---------------------------------------------------------------------------
template <bool EDGE>
__device__ __forceinline__ void attn_iter(
    const int s0, const int send, const int quad,
    const __bf16* __restrict__ kg, const __bf16* __restrict__ vg,
    char* const kw, char* const vw,
    const char* const (&krp)[2][2], const char* const (&vrp)[4],
    char* const (&pwp)[2][2], const char* const (&prp)[2],
    const bf16x8 (&bq)[2][2], const float (&Dm)[2],
    uint4& kA, uint4& vA, f32x4 (&oacc)[2][4],
    float (&lsum)[2], float (&spsum)[2]) {
  *(uint4*)kw = kA;
  *(uint4*)vw = vA;
  BAR_LDS();
  if (s0 + 32 < send) {
    kA = *(const uint4*)(kg + (size_t)(s0 + 32) * 64);
    vA = *(const uint4*)(vg + s0 + 32);
  }

  f32x4 sacc[2][2] = {};
#pragma unroll
  for (int j = 0; j < 2; ++j)
#pragma unroll
    for (int kk = 0; kk < 2; ++kk) {
      const bf16x8 ak = *(const bf16x8*)krp[j][kk];
      sacc[0][j] = __builtin_amdgcn_mfma_f32_16x16x32_bf16(ak, bq[0][kk], sacc[0][j], 0, 0, 0);
      sacc[1][j] = __builtin_amdgcn_mfma_f32_16x16x32_bf16(ak, bq[1][kk], sacc[1][j], 0, 0, 0);
    }

#pragma unroll
  for (int b = 0; b < 2; ++b) {
    float lacc = 0.f, spacc = 0.f;
#pragma unroll
    for (int j = 0; j < 2; ++j) {
      float B0, B2, Bv1, Bv3, Bm1, Bm3;
      if (EDGE) {
        const int sg = s0 + j * 16 + quad * 4;
        B0 = (sg < 1020) ? (1.0f - C2_EXP) : ((sg < 1028) ? -C2_EXP : -1e30f);
        B2 = (sg + 2 < 1020) ? (1.0f - C2_EXP)
                             : ((sg + 2 < 1028) ? -C2_EXP : -1e30f);
        Bv1 = (sg + 1 < 1028) ? -C2_EXP : -1e30f;
        Bv3 = (sg + 3 < 1028) ? -C2_EXP : -1e30f;
        Bm1 = (sg + 1 < 1020) ? Dm[b] : -1e30f;
        Bm3 = (sg + 3 < 1020) ? Dm[b] : -1e30f;
      } else {
        B0 = 1.0f - C2_EXP;
        B2 = 1.0f - C2_EXP;
        Bv1 = -C2_EXP;
        Bv3 = -C2_EXP;
        Bm1 = Dm[b];
        Bm3 = Dm[b];
      }
      const float P0  = __builtin_amdgcn_exp2f(fmaf(sacc[b][j][0],  C1_EXP, B0));
      const float Pv1 = __builtin_amdgcn_exp2f(fmaf(sacc[b][j][1],  C1_EXP, Bv1));
      const float P2  = __builtin_amdgcn_exp2f(fmaf(sacc[b][j][2],  C1_EXP, B2));
      const float Pv3 = __builtin_amdgcn_exp2f(fmaf(sacc[b][j][3],  C1_EXP, Bv3));
      const float pm1 = __builtin_amdgcn_exp2f(fmaf(sacc[b][j][1], -C1_EXP, Bm1));
      const float pm3 = __builtin_amdgcn_exp2f(fmaf(sacc[b][j][3], -C1_EXP, Bm3));
      const float mm = pm1 + pm3;
      lacc += (P0 + P2) + (Pv1 + Pv3) + mm;
      spacc += mm;
      union { uint2 u; __bf16 h[4]; } pk;
      pk.h[0] = (__bf16)P0;
      pk.h[1] = (__bf16)(Pv1 - pm1);
      pk.h[2] = (__bf16)P2;
      pk.h[3] = (__bf16)(Pv3 - pm3);
      *(uint2*)pwp[b][j] = pk.u;
    }
    lsum[b] += lacc;
    spsum[b] += spacc;
  }
  asm volatile("" ::: "memory");

  bf16x8 bp[2];
  bp[0] = *(const bf16x8*)prp[0];
  bp[1] = *(const bf16x8*)prp[1];
#pragma unroll
  for (int jc = 0; jc < 4; ++jc) {
    const bf16x8 av = *(const bf16x8*)vrp[jc];
    oacc[0][jc] = __builtin_amdgcn_mfma_f32_16x16x32_bf16(av, bp[0], oacc[0][jc], 0, 0, 0);
    oacc[1][jc] = __builtin_amdgcn_mfma_f32_16x16x32_bf16(av, bp[1], oacc[1][jc], 0, 0, 0);
  }
  BAR_LDS();
}

__global__ __launch_bounds__(256, 4) void k_attn_mfma(const __bf16* __restrict__ Qt,
                                                      const __bf16* __restrict__ Kt,
                                                      const __bf16* __restrict__ Vt,
                                                      const float* __restrict__ dq,
                                                      const float* __restrict__ uv,
                                                      __bf16* __restrict__ opart,
                                                      float* __restrict__ lpart) {
  const int t0 = blockIdx.x * 128;
  const int part = blockIdx.y;  // 0..2
  const int bh = blockIdx.z;
  const __bf16* kt = Kt + (size_t)bh * 73728;
  const __bf16* vt = Vt + (size_t)bh * 73728;

  __shared__ __align__(16) char smem[16384];

  const int tid = threadIdx.x, lane = tid & 63, wv = tid >> 6;
  const int quad = lane >> 4, q16 = lane & 15;
  const int wband = wv * 32;

  const int rK = tid >> 3, gK = tid & 7;
  char* const kw = smem + rK * 128 + ((gK ^ (rK & 7)) * 16);
  const int cV = tid >> 2, gV = tid & 3;
  char* const vw = smem + 4096 + (cV >> 1) * 128 +
                   ((((cV & 1) * 4 + gV) ^ ((cV >> 1) & 7)) * 16);
  const __bf16* const kg = kt + (size_t)rK * 64 + gK * 8;
  const __bf16* const vg = vt + (size_t)cV * 1152 + gV * 8;

  const char* krp[2][2];
#pragma unroll
  for (int j = 0; j < 2; ++j)
#pragma unroll
    for (int kk = 0; kk < 2; ++kk)
      krp[j][kk] = smem + (j * 16 + q16) * 128 + (((kk * 4 + quad) ^ (q16 & 7)) * 16);
  const int a7 = (q16 >> 1) & 7, p1 = q16 & 1;
  const char* vrp[4];
#pragma unroll
  for (int jc = 0; jc < 4; ++jc)
    vrp[jc] = smem + 4096 + (jc * 8 + (q16 >> 1)) * 128 +
              (((p1 * 4 + quad) ^ a7) * 16);
  char* pwp[2][2];
  const char* prp[2];
#pragma unroll
  for (int b = 0; b < 2; ++b) {
    const int mrow = ((wband + b * 16) >> 1) + (q16 >> 1);
    prp[b] = smem + 8192 + mrow * 128 + (((p1 * 4 + quad) ^ a7) * 16);
#pragma unroll
    for (int j = 0; j < 2; ++j)
      pwp[b][j] = smem + 8192 + mrow * 128 +
                  (((p1 * 4 + j * 2 + (quad >> 1)) ^ a7) * 16) + (quad & 1) * 8;
  }

  const __bf16* qbase = Qt + (size_t)bh * 131072;
  bf16x8 bq[2][2];
  float Dm[2];
#pragma unroll
  for (int b = 0; b < 2; ++b) {
    const int t = t0 + wband + b * 16 + q16;
    const __bf16* qp = qbase + (size_t)t * 64 + quad * 8;
    bq[b][0] = *(const bf16x8*)qp;
    bq[b][1] = *(const bf16x8*)(qp + 32);
    Dm[b] = dq[(size_t)bh * 2048 + t] - C2_EXP;
  }

  f32x4 oacc[2][4] = {};
  float lsum[2] = {0.f, 0.f};
  float spsum[2] = {0.f, 0.f};

  const int sbase = part * 352, send = sbase + 352;
  // interior iterations have all boundary guards inactive:
  // max sg+3 = s0+31; guards start at slot 1020 -> interior while s0 < 992.
  const int sInt = (part == 2) ? 992 : send;
  uint4 kA = *(const uint4*)(kg + (size_t)sbase * 64);
  uint4 vA = *(const uint4*)(vg + sbase);

  for (int s0 = sbase; s0 < sInt; s0 += 32)
    attn_iter<false>(s0, send, quad, kg, vg, kw, vw, krp, vrp, pwp, prp,
                     bq, Dm, kA, vA, oacc, lsum, spsum);
  for (int s0 = sInt; s0 < send; s0 += 32)
    attn_iter<true>(s0, send, quad, kg, vg, kw, vw, krp, vrp, pwp, prp,
                    bq, Dm, kA, vA, oacc, lsum, spsum);

  // epilogue-only uv load (kept out of the loop-live register set)
  float4 uv4[4];
  {
    const float* uvp = uv + (size_t)bh * 64;
#pragma unroll
    for (int jc = 0; jc < 4; ++jc)
      uv4[jc] = *(const float4*)(uvp + jc * 16 + quad * 4);
  }

#pragma unroll
  for (int b = 0; b < 2; ++b) {
    float l = lsum[b], sp = spsum[b];
    l += __shfl_xor(l, 16);
    l += __shfl_xor(l, 32);
    sp += __shfl_xor(sp, 16);
    sp += __shfl_xor(sp, 32);
    const float sp2 = 2.0f * sp;
    const int t = t0 + wband + b * 16 + q16;
    const size_t row = (size_t)(bh * 3 + part) * 2048 + t;
    if (quad == 0) lpart[row] = l;
    __bf16* opp = opart + row * 64;
#pragma unroll
    for (int jc = 0; jc < 4; ++jc) {
      union { uint2 u; __bf16 h[4]; } pk;
      pk.h[0] = (__bf16)(oacc[b][jc][0] + sp2 * uv4[jc].x);
      pk.h[1] = (__bf16)(oacc[b][jc][1] + sp2 * uv4[jc].y);
      pk.h[2] = (__bf16)(oacc[b][jc][2] + sp2 * uv4[jc].z);
      pk.h[3] = (__bf16)(oacc[b][jc][3] + sp2 * uv4[jc].w);
      *(uint2*)(opp + jc * 16 + quad * 4) = pk.u;
    }
  }
}

// ---------------------------------------------------------------------------
// Kernel 6: proj GEMM (bf16 MFMA), double-buffered, fused 3-way combine;
// unchanged.
// ---------------------------------------------------------------------------
__global__ __launch_bounds__(256) void k_gemm_proj(const float* __restrict__ W,
                                                   const __bf16* __restrict__ opart,
                                                   const float* __restrict__ lpart,
                                                   const float* __restrict__ bias,
                                                   float* __restrict__ C) {
  const int n0 = blockIdx.x * 128;
  const int bo = blockIdx.y * 64;
  const int b = blockIdx.z;
  float* Cb = C + (size_t)b * 524288;

  __shared__ __align__(16) char smem[30720];

  const int tid = threadIdx.x, lane = tid & 63, wv = tid >> 6;
  const int quad = lane >> 4, q16 = lane & 15, wn = wv * 32;

  const int rowA = tid >> 2, chA = (tid & 3) * 8;
  const int browB0 = tid >> 2, bchB = (tid & 3) * 8;
  const float* wA = W + (size_t)(bo + rowA) * 256 + chA;

  float linv[2][4];
#pragma unroll
  for (int g = 0; g < 2; ++g) {
    const int t = n0 + browB0 + g * 64;
#pragma unroll
    for (int hd = 0; hd < 4; ++hd) {
      const size_t rr = (size_t)((b * 4 + hd) * 3) * 2048 + t;
      linv[g][hd] = 1.0f / (lpart[rr] + lpart[rr + 2048] + lpart[rr + 4096]);
    }
  }

  float4 aP0 = *(const float4*)(wA);
  float4 aP1 = *(const float4*)(wA + 4);
  bf16x8 oP[2][3];
#pragma unroll
  for (int g = 0; g < 2; ++g) {
    const int t = n0 + browB0 + g * 64;
    const size_t rr = (size_t)(b * 4 * 3) * 2048 + t;
#pragma unroll
    for (int p = 0; p < 3; ++p)
      oP[g][p] = *(const bf16x8*)(opart + (rr + p * 2048) * 64 + bchB);
  }

  f32x4 acc[4][2] = {};
  int bsel = 0;
  for (int k0 = 0; k0 < 256; k0 += 32) {
    char* const Ab = smem + bsel;
    char* const Bb = smem + bsel + 5120;
    {
      union { uint4 u; __bf16 h[8]; } pa;
      pa.h[0] = (__bf16)aP0.x; pa.h[1] = (__bf16)aP0.y;
      pa.h[2] = (__bf16)aP0.z; pa.h[3] = (__bf16)aP0.w;
      pa.h[4] = (__bf16)aP1.x; pa.h[5] = (__bf16)aP1.y;
      pa.h[6] = (__bf16)aP1.z; pa.h[7] = (__bf16)aP1.w;
      *(uint4*)(Ab + rowA * 80 + chA * 2) = pa.u;
      const int hd = (k0 + bchB) >> 6;
#pragma unroll
      for (int g = 0; g < 2; ++g) {
        const float inv = linv[g][hd];
        bf16x8 res;
#pragma unroll
        for (int k = 0; k < 8; ++k)
          res[k] = (__bf16)((((float)oP[g][0][k] + (float)oP[g][1][k]) +
                             (float)oP[g][2][k]) * inv);
        *(bf16x8*)(Bb + (browB0 + g * 64) * 80 + bchB * 2) = res;
      }
    }
    __syncthreads();
    if (k0 + 32 < 256) {
      const int kn = k0 + 32;
      aP0 = *(const float4*)(wA + kn);
      aP1 = *(const float4*)(wA + kn + 4);
      const int c = kn + bchB;
      const int hd = c >> 6, cu = c & 63;
#pragma unroll
      for (int g = 0; g < 2; ++g) {
        const int t = n0 + browB0 + g * 64;
        const size_t rr = (size_t)((b * 4 + hd) * 3) * 2048 + t;
#pragma unroll
        for (int p = 0; p < 3; ++p)
          oP[g][p] = *(const bf16x8*)(opart + (rr + p * 2048) * 64 + cu);
      }
    }
    bf16x8 af[4], bfr[2];
#pragma unroll
    for (int mt = 0; mt < 4; ++mt)
      af[mt] = *(const bf16x8*)(Ab + (mt * 16 + q16) * 80 + quad * 16);
#pragma unroll
    for (int jn = 0; jn < 2; ++jn)
      bfr[jn] = *(const bf16x8*)(Bb + (wn + jn * 16 + q16) * 80 + quad * 16);
#pragma unroll
    for (int mt = 0; mt < 4; ++mt)
#pragma unroll
      for (int jn = 0; jn < 2; ++jn)
        acc[mt][jn] = __builtin_amdgcn_mfma_f32_16x16x32_bf16(af[mt], bfr[jn], acc[mt][jn], 0, 0, 0);
    bsel ^= 15360;
  }

#pragma unroll
  for (int mt = 0; mt < 4; ++mt)
#pragma unroll
    for (int r = 0; r < 4; ++r) {
      const int o = bo + mt * 16 + quad * 4 + r;
      const float bv = bias[o];
#pragma unroll
      for (int jn = 0; jn < 2; ++jn)
        Cb[(size_t)o * 2048 + n0 + wn + jn * 16 + q16] = acc[mt][jn][r] + bv;
    }
}

// ---------------------------------------------------------------------------
// Kernel 7: inverse FFT2 via split-bf16 MFMA. One slice per wave (r14 form),
// spec global loads issued before table staging.
// ---------------------------------------------------------------------------
__global__ __launch_bounds__(256) void k_ifft2(const float* __restrict__ spec,
                                               float* __restrict__ out,
                                               const __bf16* __restrict__ tw) {
  __shared__ __align__(16) char smem[51200];
  const int tid = threadIdx.x, lane = tid & 63, wv = tid >> 6;
  const int quad = lane >> 4, q16 = lane & 15;
  const int slice = blockIdx.x * 4 + wv;
  char* const wr_ = smem + 10240 + wv * 10240;

  // early spec global loads
  const float* sp = spec + (size_t)slice * 2048;
  float4 sv8[8];
#pragma unroll
  for (int u = 0; u < 8; ++u) sv8[u] = ((const float4*)sp)[u * 64 + lane];

  for (int i = tid; i < 512; i += 256) {
    const int t = i >> 7, r = (i >> 2) & 31, c8 = (i & 3) * 8;
    *(uint4*)(smem + t * 2560 + r * 80 + c8 * 2) =
        *(const uint4*)(tw + t * 1024 + r * 32 + c8);
  }

#pragma unroll
  for (int u = 0; u < 8; ++u) {
    const int f = u * 64 + lane;  // 0..511 float4 (2 complex each)
    const float4 v = sv8[u];
    const int k1 = f >> 4, k2 = (f & 15) * 2;
    char* base = wr_ + k1 * 80 + k2 * 2;
    union { unsigned int w; __bf16 b[2]; } p;
    const __bf16 rh0 = (__bf16)v.x, rh1 = (__bf16)v.z;
    const __bf16 ih0 = (__bf16)v.y, ih1 = (__bf16)v.w;
    p.b[0] = rh0; p.b[1] = rh1; *(unsigned int*)(base) = p.w;
    p.b[0] = (__bf16)(v.x - (float)rh0);
    p.b[1] = (__bf16)(v.z - (float)rh1); *(unsigned int*)(base + 2560) = p.w;
    p.b[0] = ih0; p.b[1] = ih1; *(unsigned int*)(base + 5120) = p.w;
    p.b[0] = (__bf16)(v.y - (float)ih0);
    p.b[1] = (__bf16)(v.w - (float)ih1); *(unsigned int*)(base + 7680) = p.w;
  }
  __syncthreads();  // tables visible; X same-wave ordered

  bf16x8 cch[2], ccl[2], ssh[2], ssl[2], ssnh[2], ssnl[2];
  bf16x8 xreh[2], xrel[2], ximh[2], ximl[2];
#pragma unroll
  for (int t2 = 0; t2 < 2; ++t2) {
    const int row = t2 * 16 + q16;
    cch[t2] = *(const bf16x8*)(smem + row * 80 + quad * 16);
    ccl[t2] = *(const bf16x8*)(smem + 2560 + row * 80 + quad * 16);
    ssh[t2] = *(const bf16x8*)(smem + 5120 + row * 80 + quad * 16);
    ssl[t2] = *(const bf16x8*)(smem + 7680 + row * 80 + quad * 16);
    xreh[t2] = *(const bf16x8*)(wr_ + row * 80 + quad * 16);
    xrel[t2] = *(const bf16x8*)(wr_ + 2560 + row * 80 + quad * 16);
    ximh[t2] = *(const bf16x8*)(wr_ + 5120 + row * 80 + quad * 16);
    ximl[t2] = *(const bf16x8*)(wr_ + 7680 + row * 80 + quad * 16);
  }
  ssnh[0] = neg8(ssh[0]); ssnh[1] = neg8(ssh[1]);
  ssnl[0] = neg8(ssl[0]); ssnl[1] = neg8(ssl[1]);

  // pass 1
  f32x4 yre[2][2] = {}, yim[2][2] = {};
#pragma unroll
  for (int mt = 0; mt < 2; ++mt)
#pragma unroll
    for (int nt = 0; nt < 2; ++nt) {
      MFMA3(yre[mt][nt], xreh[mt], xrel[mt], cch[nt], ccl[nt]);
      MFMA3(yre[mt][nt], ximh[mt], ximl[mt], ssnh[nt], ssnl[nt]);
      MFMA3(yim[mt][nt], xreh[mt], xrel[mt], ssh[nt], ssl[nt]);
      MFMA3(yim[mt][nt], ximh[mt], ximl[mt], cch[nt], ccl[nt]);
    }

  // write Yt transposed + split over the X regions (wave-private)
#pragma unroll
  for (int mt = 0; mt < 2; ++mt)
#pragma unroll
    for (int nt = 0; nt < 2; ++nt) {
      char* base = wr_ + (nt * 16 + q16) * 80 + (mt * 16 + quad * 4) * 2;
      union { unsigned long long q; __bf16 b[4]; } h, l;
#pragma unroll
      for (int r = 0; r < 4; ++r) {
        const float v = yre[mt][nt][r];
        h.b[r] = (__bf16)v; l.b[r] = (__bf16)(v - (float)h.b[r]);
      }
      *(unsigned long long*)(base) = h.q;
      *(unsigned long long*)(base + 2560) = l.q;
#pragma unroll
      for (int r = 0; r < 4; ++r) {
        const float v = yim[mt][nt][r];
        h.b[r] = (__bf16)v; l.b[r] = (__bf16)(v - (float)h.b[r]);
      }
      *(unsigned long long*)(base + 5120) = h.q;
      *(unsigned long long*)(base + 7680) = l.q;
    }
  asm volatile("" ::: "memory");

  bf16x8 yreh[2], yrel[2], yimh[2], yiml[2];
#pragma unroll
  for (int nt = 0; nt < 2; ++nt) {
    const int row = nt * 16 + q16;
    yreh[nt] = *(const bf16x8*)(wr_ + row * 80 + quad * 16);
    yrel[nt] = *(const bf16x8*)(wr_ + 2560 + row * 80 + quad * 16);
    yimh[nt] = *(const bf16x8*)(wr_ + 5120 + row * 80 + quad * 16);
    yiml[nt] = *(const bf16x8*)(wr_ + 7680 + row * 80 + quad * 16);
  }

  // pass 2
  f32x4 zre[2][2] = {}, zim[2][2] = {};
#pragma unroll
  for (int mt = 0; mt < 2; ++mt)
#pragma unroll
    for (int nt = 0; nt < 2; ++nt) {
      MFMA3(zre[mt][nt], cch[mt], ccl[mt], yreh[nt], yrel[nt]);
      MFMA3(zre[mt][nt], ssnh[mt], ssnl[mt], yimh[nt], yiml[nt]);
      MFMA3(zim[mt][nt], cch[mt], ccl[mt], yimh[nt], yiml[nt]);
      MFMA3(zim[mt][nt], ssh[mt], ssl[mt], yreh[nt], yrel[nt]);
    }

  float* op = out + (size_t)slice * 2048;
#pragma unroll
  for (int mt = 0; mt < 2; ++mt)
#pragma unroll
    for (int nt = 0; nt < 2; ++nt)
#pragma unroll
      for (int r = 0; r < 4; ++r) {
        const int n1 = mt * 16 + quad * 4 + r;
        const int n2 = nt * 16 + q16;
        float2 st;
        st.x = zre[mt][nt][r] * (1.0f / 1024.0f);
        st.y = zim[mt][nt][r] * (1.0f / 1024.0f);
        *(float2*)(op + 2 * (n1 * 32 + n2)) = st;
      }
}

// ---------------------------------------------------------------------------
extern "C" void kernel_launch(void* const* d_in, const int* in_sizes, int n_in,
                              void* d_out, int out_size, void* d_ws, size_t ws_size,
                              hipStream_t stream) {
  (void)in_sizes; (void)n_in; (void)out_size; (void)ws_size;
  const float* x      = (const float*)d_in[0];
  const float* gn_w   = (const float*)d_in[1];
  const float* gn_b   = (const float*)d_in[2];
  const float* qkv_w  = (const float*)d_in[3];
  const float* qkv_b  = (const float*)d_in[4];
  const float* proj_w = (const float*)d_in[5];
  const float* proj_b = (const float*)d_in[6];
  float* out = (float*)d_out;

  float* spec  = (float*)d_ws;
  __bf16* Qt   = (__bf16*)(spec + 4194304);   // 4194304 elems
  __bf16* Kt   = Qt + 4194304;                // 2359296 elems (32*1152*64)
  __bf16* Vt   = Kt + 2359296;                // 2359296 elems
  float* stats = (float*)(Vt + 2359296);      // 512
  float* xr    = stats + 512;                 // 4194304 floats
  __bf16* xt   = (__bf16*)(xr + 4194304);     // 4194304 bf16
  __bf16* opart = (__bf16*)xr;                // 12582912 bf16 (clobbers xr+xt)
  float*  lpart = (float*)(opart + 12582912); // 196608
  float*  dq    = lpart + 196608;             // 65536
  float*  uk    = dq + 65536;                 // 2048
  float*  uv    = uk + 2048;                  // 2048
  __bf16* tw    = (__bf16*)(uv + 2048);       // 4096 bf16 twiddle tables

  hipMemsetAsync(stats, 0, 512 * sizeof(float), stream);
  k_twid<<<1, 256, 0, stream>>>(tw);
  k_fft2<<<512, 256, 0, stream>>>(x, xr, stats, tw);
  k_uvec<<<64, 256, 0, stream>>>(stats, gn_w, gn_b, qkv_w, qkv_b, uk, uv);
  k_gntrans<<<dim3(32, 4, 8), 256, 0, stream>>>(xr, stats, gn_w, gn_b, xt);
  k_gemm_qkv<<<dim3(136, 8), 256, 0, stream>>>(qkv_w, xt, qkv_b, uk, dq,
                                               Qt, Kt, Vt);
  k_attn_mfma<<<dim3(16, 3, 32), 256, 0, stream>>>(Qt, Kt, Vt, dq, uv,
                                                   opart, lpart);
  k_gemm_proj<<<dim3(16, 4, 8), 256, 0, stream>>>(proj_w, opart, lpart,
                                                  proj_b, spec);
  k_ifft2<<<512, 256, 0, stream>>>(spec, out, tw);
}

// Round 6
// 165.244 us; speedup vs baseline: 1.1564x; 1.0097x over previous
//
#include <hip/hip_runtime.h>
#include <hip/hip_bf16.h>
#include <stdint.h>

#define PI_F 3.14159265358979323846f
#define C1_EXP 0.18033688f   // log2(e)/8
#define C2_EXP 23.083120f    // 16*log2(e)

typedef __bf16 bf16x8 __attribute__((ext_vector_type(8)));
typedef float f32x4 __attribute__((ext_vector_type(4)));
typedef unsigned int uint32x4 __attribute__((ext_vector_type(4)));

// LDS-only barrier: s_barrier with lgkmcnt drain but NO vmcnt drain, so
// in-flight global prefetch loads survive across the barrier (T4-minimal).
// Proven +3us on attn in r20.
#define BAR_LDS() asm volatile("s_waitcnt lgkmcnt(0)\n\ts_barrier" ::: "memory")

__device__ __forceinline__ bf16x8 neg8(bf16x8 v) {
  union { bf16x8 b; uint32x4 u; } x;
  x.b = v;
  x.u ^= (uint32x4){0x80008000u, 0x80008000u, 0x80008000u, 0x80008000u};
  return x.b;
}

// 3-term split-accumulate: P*Q with P=Ph+Pl, Q=Qh+Ql (drop Pl*Ql ~2^-18)
#define MFMA3(acc, Ph, Pl, Qh, Ql)                                        \
  acc = __builtin_amdgcn_mfma_f32_16x16x32_bf16(Ph, Qh, acc, 0, 0, 0);    \
  acc = __builtin_amdgcn_mfma_f32_16x16x32_bf16(Ph, Ql, acc, 0, 0, 0);    \
  acc = __builtin_amdgcn_mfma_f32_16x16x32_bf16(Pl, Qh, acc, 0, 0, 0);

// Closed-form base-slot -> original column mapping.
__device__ __forceinline__ int slot2n(int slot) {
  const int pi = slot >> 1, im = slot & 1;
  int k1, k2;
  if (pi < 480)      { k1 = 1 + (pi >> 5); k2 = pi & 31; }
  else if (pi < 495) { k1 = 0;  k2 = pi - 479; }
  else if (pi < 510) { k1 = 16; k2 = pi - 494; }
  else if (pi < 514) { k1 = ((pi - 510) >> 1) * 16; k2 = ((pi - 510) & 1) * 16; }
  else               { k1 = 0; k2 = 0; }
  return 2 * (k1 * 32 + k2) + im;
}

// ---------------------------------------------------------------------------
// Kernel 0: twiddle tables, hi/lo split bf16.
// ---------------------------------------------------------------------------
__global__ __launch_bounds__(256) void k_twid(__bf16* __restrict__ tw) {
  for (int e = threadIdx.x; e < 1024; e += 256) {
    const int j = e >> 5, k = e & 31;
    const int t = (j * k) & 31;
    float sv, cv;
    sincosf(2.0f * PI_F * (float)t / 32.0f, &sv, &cv);
    const __bf16 ch = (__bf16)cv;
    const __bf16 sh = (__bf16)sv;
    tw[e] = ch;
    tw[1024 + e] = (__bf16)(cv - (float)ch);
    tw[2048 + e] = sh;
    tw[3072 + e] = (__bf16)(sv - (float)sh);
  }
}

// ---------------------------------------------------------------------------
// Kernel 1: forward FFT2 via split-bf16 MFMA. One slice per wave (r14
// measured-best barrier-free form).
// ---------------------------------------------------------------------------
__global__ __launch_bounds__(256) void k_fft2(const float* __restrict__ x,
                                              float* __restrict__ xr,
                                              float* __restrict__ stats_raw,
                                              const __bf16* __restrict__ tw) {
  __shared__ __align__(16) char smem[51200];
  const int tid = threadIdx.x, lane = tid & 63, wv = tid >> 6;
  const int quad = lane >> 4, q16 = lane & 15;
  const int slice = blockIdx.x * 4 + wv;
  char* const wr_ = smem + 10240 + wv * 10240;

  // early X global loads (wave-private region; overlap with table staging)
  const float* xs = x + (size_t)slice * 1024;
  float4 xv[4];
#pragma unroll
  for (int u = 0; u < 4; ++u) xv[u] = ((const float4*)xs)[u * 64 + lane];

  for (int i = tid; i < 512; i += 256) {
    const int t = i >> 7, r = (i >> 2) & 31, c8 = (i & 3) * 8;
    *(uint4*)(smem + t * 2560 + r * 80 + c8 * 2) =
        *(const uint4*)(tw + t * 1024 + r * 32 + c8);
  }

  // X split + stage (same-wave ds ordering)
#pragma unroll
  for (int u = 0; u < 4; ++u) {
    const int f = u * 64 + lane;
    const float4 v = xv[u];
    const int row = f >> 3, c4 = (f & 7) * 4;
    union { unsigned long long q; __bf16 b[4]; } ph, pl;
    ph.b[0] = (__bf16)v.x; ph.b[1] = (__bf16)v.y;
    ph.b[2] = (__bf16)v.z; ph.b[3] = (__bf16)v.w;
    pl.b[0] = (__bf16)(v.x - (float)ph.b[0]);
    pl.b[1] = (__bf16)(v.y - (float)ph.b[1]);
    pl.b[2] = (__bf16)(v.z - (float)ph.b[2]);
    pl.b[3] = (__bf16)(v.w - (float)ph.b[3]);
    *(unsigned long long*)(wr_ + row * 80 + c4 * 2) = ph.q;
    *(unsigned long long*)(wr_ + 2560 + row * 80 + c4 * 2) = pl.q;
  }
  __syncthreads();  // tables visible to all waves; X same-wave ordered

  bf16x8 cch[2], ccl[2], ssh[2], ssl[2], xh[2], xl[2];
#pragma unroll
  for (int t2 = 0; t2 < 2; ++t2) {
    const int row = t2 * 16 + q16;
    cch[t2] = *(const bf16x8*)(smem + row * 80 + quad * 16);
    ccl[t2] = *(const bf16x8*)(smem + 2560 + row * 80 + quad * 16);
    ssh[t2] = *(const bf16x8*)(smem + 5120 + row * 80 + quad * 16);
    ssl[t2] = *(const bf16x8*)(smem + 7680 + row * 80 + quad * 16);
    xh[t2] = *(const bf16x8*)(wr_ + row * 80 + quad * 16);
    xl[t2] = *(const bf16x8*)(wr_ + 2560 + row * 80 + quad * 16);
  }

  // pass 1: Yre = X@Cc, Yim = -(X@Ss)
  f32x4 yre[2][2] = {}, yim[2][2] = {};
#pragma unroll
  for (int mt = 0; mt < 2; ++mt)
#pragma unroll
    for (int nt = 0; nt < 2; ++nt) {
      MFMA3(yre[mt][nt], xh[mt], xl[mt], cch[nt], ccl[nt]);
      MFMA3(yim[mt][nt], xh[mt], xl[mt], ssh[nt], ssl[nt]);
    }

  // write Yt transposed + split (wave-private; same-wave ordering)
#pragma unroll
  for (int mt = 0; mt < 2; ++mt)
#pragma unroll
    for (int nt = 0; nt < 2; ++nt) {
      char* base = wr_ + (nt * 16 + q16) * 80 + (mt * 16 + quad * 4) * 2;
      union { unsigned long long q; __bf16 b[4]; } h, l;
#pragma unroll
      for (int r = 0; r < 4; ++r) {
        const float v = yre[mt][nt][r];
        h.b[r] = (__bf16)v; l.b[r] = (__bf16)(v - (float)h.b[r]);
      }
      *(unsigned long long*)(base) = h.q;
      *(unsigned long long*)(base + 2560) = l.q;
#pragma unroll
      for (int r = 0; r < 4; ++r) {
        const float v = -yim[mt][nt][r];
        h.b[r] = (__bf16)v; l.b[r] = (__bf16)(v - (float)h.b[r]);
      }
      *(unsigned long long*)(base + 5120) = h.q;
      *(unsigned long long*)(base + 7680) = l.q;
    }
  asm volatile("" ::: "memory");

  bf16x8 yreh[2], yrel[2], yimh[2], yiml[2];
#pragma unroll
  for (int nt = 0; nt < 2; ++nt) {
    const int row = nt * 16 + q16;
    yreh[nt] = *(const bf16x8*)(wr_ + row * 80 + quad * 16);
    yrel[nt] = *(const bf16x8*)(wr_ + 2560 + row * 80 + quad * 16);
    yimh[nt] = *(const bf16x8*)(wr_ + 5120 + row * 80 + quad * 16);
    yiml[nt] = *(const bf16x8*)(wr_ + 7680 + row * 80 + quad * 16);
  }

  // pass 2: Zre = Cc@Yre + Ss@Yim ; Zim = Cc@Yim - Ss@Yre
  f32x4 zre[2][2] = {}, zim[2][2] = {};
  bf16x8 ssnh[2], ssnl[2];
  ssnh[0] = neg8(ssh[0]); ssnh[1] = neg8(ssh[1]);
  ssnl[0] = neg8(ssl[0]); ssnl[1] = neg8(ssl[1]);
#pragma unroll
  for (int mt = 0; mt < 2; ++mt)
#pragma unroll
    for (int nt = 0; nt < 2; ++nt) {
      MFMA3(zre[mt][nt], cch[mt], ccl[mt], yreh[nt], yrel[nt]);
      MFMA3(zre[mt][nt], ssh[mt], ssl[mt], yimh[nt], yiml[nt]);
      MFMA3(zim[mt][nt], cch[mt], ccl[mt], yimh[nt], yiml[nt]);
      MFMA3(zim[mt][nt], ssnh[mt], ssnl[mt], yreh[nt], yrel[nt]);
    }

  // stats + store
  float* op = xr + (size_t)slice * 2048;
  float s1 = 0.f, s2 = 0.f;
#pragma unroll
  for (int mt = 0; mt < 2; ++mt)
#pragma unroll
    for (int nt = 0; nt < 2; ++nt)
#pragma unroll
      for (int r = 0; r < 4; ++r) {
        const int k1 = mt * 16 + quad * 4 + r;
        const int k2 = nt * 16 + q16;
        const float a = zre[mt][nt][r], bimg = zim[mt][nt][r];
        s1 += a + bimg;
        s2 += a * a + bimg * bimg;
        float2 st; st.x = a; st.y = bimg;
        *(float2*)(op + 2 * (k1 * 32 + k2)) = st;
      }
#pragma unroll
  for (int off = 1; off <= 32; off <<= 1) {
    s1 += __shfl_xor(s1, off);
    s2 += __shfl_xor(s2, off);
  }
  if (lane == 0) {
    const int bg = (slice >> 8) * 32 + ((slice & 255) >> 3);
    atomicAdd(&stats_raw[bg * 2], s1);
    atomicAdd(&stats_raw[bg * 2 + 1], s2);
  }
}

// ---------------------------------------------------------------------------
// Kernel 2: mirror-correction vectors (coalesced); unchanged.
// ---------------------------------------------------------------------------
__global__ __launch_bounds__(256) void k_uvec(const float* __restrict__ stats_raw,
                                              const float* __restrict__ gn_w,
                                              const float* __restrict__ gn_b,
                                              const float* __restrict__ qkv_w,
                                              const float* __restrict__ qkv_b,
                                              float* __restrict__ uk,
                                              float* __restrict__ uv) {
  const int blk = blockIdx.x;
  const int tid = threadIdx.x;
  const int b = blk >> 3, h = (blk >> 1) & 3, role = blk & 1;
  __shared__ float Bsh[256];
  {
    const int g = tid >> 3;
    const float S = stats_raw[(b * 32 + g) * 2];
    const float S2 = stats_raw[(b * 32 + g) * 2 + 1];
    const float mean = S * (1.0f / 16384.0f);
    const float var = S2 * (1.0f / 16384.0f) - mean * mean;
    const float rstd = rsqrtf(var + 1e-5f);
    Bsh[tid] = gn_b[tid] - mean * rstd * gn_w[tid];
  }
  __syncthreads();
  const int cp = tid >> 2, seg = tid & 3;
  const int row = h * 192 + 64 + role * 64 + cp;
  const float* wr_ = qkv_w + (size_t)row * 256 + seg * 64;
  const float* bs = Bsh + seg * 64;
  float s = 0.f;
#pragma unroll
  for (int i = 0; i < 16; ++i) {
    const float4 w4 = *(const float4*)(wr_ + i * 4);
    const float4 b4 = *(const float4*)(bs + i * 4);
    s += w4.x * b4.x + w4.y * b4.y + w4.z * b4.z + w4.w * b4.w;
  }
  s += __shfl_xor(s, 1);
  s += __shfl_xor(s, 2);
  if (seg == 0) {
    float* dst = (role == 0) ? uk : uv;
    dst[(size_t)(b * 4 + h) * 64 + cp] = s + qkv_b[row];
  }
}

// ---------------------------------------------------------------------------
// Kernel 3: GroupNorm apply + transpose to bf16 X^T [b][n][c]; unchanged.
// ---------------------------------------------------------------------------
__global__ __launch_bounds__(256) void k_gntrans(const float* __restrict__ xr,
                                                 const float* __restrict__ stats_raw,
                                                 const float* __restrict__ w,
                                                 const float* __restrict__ bias,
                                                 __bf16* __restrict__ xt) {
  const int n0 = blockIdx.x * 64;
  const int c0 = blockIdx.y * 64;
  const int b = blockIdx.z;
  __shared__ __bf16 Lt[64][72];
  const int tid = threadIdx.x;
  for (int i = tid; i < 1024; i += 256) {
    const int cl = i >> 4, c = c0 + cl, nl = (i & 15) * 4;
    const float S = stats_raw[(b * 32 + (c >> 3)) * 2];
    const float S2 = stats_raw[(b * 32 + (c >> 3)) * 2 + 1];
    const float mean = S * (1.0f / 16384.0f);
    const float var = S2 * (1.0f / 16384.0f) - mean * mean;
    const float rstd = rsqrtf(var + 1e-5f);
    const float sc = rstd * w[c];
    const float sh = bias[c] - mean * sc;
    const float4 v = *(const float4*)(xr + ((size_t)b * 256 + c) * 2048 + n0 + nl);
    Lt[nl][cl] = (__bf16)(v.x * sc + sh);
    Lt[nl + 1][cl] = (__bf16)(v.y * sc + sh);
    Lt[nl + 2][cl] = (__bf16)(v.z * sc + sh);
    Lt[nl + 3][cl] = (__bf16)(v.w * sc + sh);
  }
  __syncthreads();
  __bf16* dst = xt + (size_t)b * 524288 + (size_t)n0 * 256 + c0;
  for (int i = tid; i < 512; i += 256) {
    const int nl = i >> 3, cch = (i & 7) * 8;
    *(uint4*)(dst + (size_t)nl * 256 + cch) = *(const uint4*)&Lt[nl][cch];
  }
}

// ---------------------------------------------------------------------------
// Kernel 4: QKV GEMM (bf16 MFMA), double-buffered LDS; unchanged.
// ---------------------------------------------------------------------------
__global__ __launch_bounds__(256) void k_gemm_qkv(const float* __restrict__ W,
                                                  const __bf16* __restrict__ X,
                                                  const float* __restrict__ bias,
                                                  const float* __restrict__ uk,
                                                  float* __restrict__ dq,
                                                  __bf16* __restrict__ Qt,
                                                  __bf16* __restrict__ Kt,
                                                  __bf16* __restrict__ Vt) {
  const int tx = blockIdx.x;
  const int b = blockIdx.y;
  int role, hd, nt;
  if (tx < 64) { role = 0; hd = tx >> 4; nt = tx & 15; }
  else if (tx < 100) { role = 1; const int i = tx - 64; hd = i / 9; nt = i - hd * 9; }
  else { role = 2; const int i = tx - 100; hd = i / 9; nt = i - hd * 9; }
  const int n0 = nt * 128;
  const int bo = hd * 192 + role * 64;
  const __bf16* Xb = X + (size_t)b * 524288;

  __shared__ __align__(16) char smem[30720];
  __bf16 (*Ot)[72] = (__bf16(*)[72])smem;
  __bf16 (*Ot2)[136] = (__bf16(*)[136])smem;

  const int tid = threadIdx.x, lane = tid & 63, wv = tid >> 6;
  const int quad = lane >> 4, q16 = lane & 15, wn = wv * 32;

  const int rowA = tid >> 2, chA = (tid & 3) * 8;
  const int browB0 = tid >> 2, bchB = (tid & 3) * 8;
  const float* wA = W + (size_t)(bo + rowA) * 256 + chA;

  const int s0r = n0 + browB0, s1r = n0 + browB0 + 64;
  const int pn0 = (role == 0) ? s0r : slot2n(s0r);
  const int pn1 = (role == 0) ? s1r : slot2n(s1r);

  float4 aP0 = *(const float4*)(wA);
  float4 aP1 = *(const float4*)(wA + 4);
  uint4 bP0 = *(const uint4*)(Xb + (size_t)pn0 * 256 + bchB);
  uint4 bP1 = *(const uint4*)(Xb + (size_t)pn1 * 256 + bchB);

  f32x4 acc[4][2] = {};
  int bsel = 0;
  for (int k0 = 0; k0 < 256; k0 += 32) {
    char* const Ab = smem + bsel;
    char* const Bb = smem + bsel + 5120;
    {
      union { uint4 u; __bf16 h[8]; } pa;
      pa.h[0] = (__bf16)aP0.x; pa.h[1] = (__bf16)aP0.y;
      pa.h[2] = (__bf16)aP0.z; pa.h[3] = (__bf16)aP0.w;
      pa.h[4] = (__bf16)aP1.x; pa.h[5] = (__bf16)aP1.y;
      pa.h[6] = (__bf16)aP1.z; pa.h[7] = (__bf16)aP1.w;
      *(uint4*)(Ab + rowA * 80 + chA * 2) = pa.u;
      *(uint4*)(Bb + browB0 * 80 + bchB * 2) = bP0;
      *(uint4*)(Bb + (browB0 + 64) * 80 + bchB * 2) = bP1;
    }
    __syncthreads();
    if (k0 + 32 < 256) {
      const int kn = k0 + 32;
      aP0 = *(const float4*)(wA + kn);
      aP1 = *(const float4*)(wA + kn + 4);
      bP0 = *(const uint4*)(Xb + (size_t)pn0 * 256 + kn + bchB);
      bP1 = *(const uint4*)(Xb + (size_t)pn1 * 256 + kn + bchB);
    }
    bf16x8 af[4], bfr[2];
#pragma unroll
    for (int mt = 0; mt < 4; ++mt)
      af[mt] = *(const bf16x8*)(Ab + (mt * 16 + q16) * 80 + quad * 16);
#pragma unroll
    for (int jn = 0; jn < 2; ++jn)
      bfr[jn] = *(const bf16x8*)(Bb + (wn + jn * 16 + q16) * 80 + quad * 16);
#pragma unroll
    for (int mt = 0; mt < 4; ++mt)
#pragma unroll
      for (int jn = 0; jn < 2; ++jn)
        acc[mt][jn] = __builtin_amdgcn_mfma_f32_16x16x32_bf16(af[mt], bfr[jn], acc[mt][jn], 0, 0, 0);
    bsel ^= 15360;
  }
  __syncthreads();

  const int bh = b * 4 + hd;
  if (role == 2) {
#pragma unroll
    for (int mt = 0; mt < 4; ++mt)
#pragma unroll
      for (int r = 0; r < 4; ++r) {
        const int c = mt * 16 + quad * 4 + r;
        const float bv = bias[bo + c];
#pragma unroll
        for (int jn = 0; jn < 2; ++jn)
          Ot2[c][wn + jn * 16 + q16] = (__bf16)(acc[mt][jn][r] + bv);
      }
    __syncthreads();
    __bf16* dst = Vt + (size_t)bh * 73728;  // [c][1152]
    for (int i = tid; i < 1024; i += 256) {
      const int c = i >> 4, sg = (i & 15) * 8;
      *(uint4*)(dst + (size_t)c * 1152 + n0 + sg) = *(const uint4*)&Ot2[c][sg];
    }
  } else {
    __bf16* dst = (role == 0 ? Qt + (size_t)bh * 131072
                             : Kt + (size_t)bh * 73728);  // [n][64]
#pragma unroll
    for (int mt = 0; mt < 4; ++mt)
#pragma unroll
      for (int r = 0; r < 4; ++r) {
        const int c = mt * 16 + quad * 4 + r;
        const float bv = bias[bo + c];
#pragma unroll
        for (int jn = 0; jn < 2; ++jn)
          Ot[wn + jn * 16 + q16][c] = (__bf16)(acc[mt][jn][r] + bv);
      }
    __syncthreads();
    for (int i = tid; i < 1024; i += 256) {
      const int nl = i >> 3, cch = (i & 7) * 8;
      *(uint4*)(dst + (size_t)(n0 + nl) * 64 + cch) = *(const uint4*)&Ot[nl][cch];
    }
    if (role == 0 && tid < 128) {
      const float* ukp = uk + (size_t)bh * 64;
      float dv = 0.f;
#pragma unroll
      for (int g8 = 0; g8 < 8; ++g8) {
        const bf16x8 qv = *(const bf16x8*)&Ot[tid][g8 * 8];
#pragma unroll
        for (int k = 0; k < 8; ++k) dv += (float)qv[k] * ukp[g8 * 8 + k];
      }
      dq[(size_t)bh * 2048 + n0 + tid] = dv * (2.0f * C1_EXP);
    }
  }
}

// ---------------------------------------------------------------------------
// Kernel 5: MFMA flash attention. r21: SINGLE-PART (was 3-way split).
// Each block runs all 33 K/V tiles; l is complete at epilogue so the output
// is self-normalized bf16 -> lpart eliminated, proj becomes a plain GEMM.
// Saves: opart 25->8.4MB (w+r), Q reads 25->8.4MB, dq reads 3x->1x, proj
// 3-way combine VALU. Inner loop is byte-identical to r20 (BAR_LDS, proven
// 76 VGPR no-spill). Grid 16x32 = 512 blocks = 2 blocks/CU x 4 waves =
// 8 waves/CU, matching the measured occupancy of the 3-part version.
// ---------------------------------------------------------------------------
template <bool EDGE>
__device__ __forceinline__ void attn_iter(
    const int s0, const int send, const int quad,
    const __bf16* __restrict__ kg, const __bf16* __restrict__ vg,
    char* const kw, char* const vw,
    const char* const (&krp)[2][2], const char* const (&vrp)[4],
    char* const (&pwp)[2][2], const char* const (&prp)[2],
    const bf16x8 (&bq)[2][2], const float (&Dm)[2],
    uint4& kA, uint4& vA, f32x4 (&oacc)[2][4],
    float (&lsum)[2], float (&spsum)[2]) {
  *(uint4*)kw = kA;
  *(uint4*)vw = vA;
  BAR_LDS();
  if (s0 + 32 < send) {
    kA = *(const uint4*)(kg + (size_t)(s0 + 32) * 64);
    vA = *(const uint4*)(vg + s0 + 32);
  }

  f32x4 sacc[2][2] = {};
#pragma unroll
  for (int j = 0; j < 2; ++j)
#pragma unroll
    for (int kk = 0; kk < 2; ++kk) {
      const bf16x8 ak = *(const bf16x8*)krp[j][kk];
      sacc[0][j] = __builtin_amdgcn_mfma_f32_16x16x32_bf16(ak, bq[0][kk], sacc[0][j], 0, 0, 0);
      sacc[1][j] = __builtin_amdgcn_mfma_f32_16x16x32_bf16(ak, bq[1][kk], sacc[1][j], 0, 0, 0);
    }

#pragma unroll
  for (int b = 0; b < 2; ++b) {
    float lacc = 0.f, spacc = 0.f;
#pragma unroll
    for (int j = 0; j < 2; ++j) {
      float B0, B2, Bv1, Bv3, Bm1, Bm3;
      if (EDGE) {
        const int sg = s0 + j * 16 + quad * 4;
        B0 = (sg < 1020) ? (1.0f - C2_EXP) : ((sg < 1028) ? -C2_EXP : -1e30f);
        B2 = (sg + 2 < 1020) ? (1.0f - C2_EXP)
                             : ((sg + 2 < 1028) ? -C2_EXP : -1e30f);
        Bv1 = (sg + 1 < 1028) ? -C2_EXP : -1e30f;
        Bv3 = (sg + 3 < 1028) ? -C2_EXP : -1e30f;
        Bm1 = (sg + 1 < 1020) ? Dm[b] : -1e30f;
        Bm3 = (sg + 3 < 1020) ? Dm[b] : -1e30f;
      } else {
        B0 = 1.0f - C2_EXP;
        B2 = 1.0f - C2_EXP;
        Bv1 = -C2_EXP;
        Bv3 = -C2_EXP;
        Bm1 = Dm[b];
        Bm3 = Dm[b];
      }
      const float P0  = __builtin_amdgcn_exp2f(fmaf(sacc[b][j][0],  C1_EXP, B0));
      const float Pv1 = __builtin_amdgcn_exp2f(fmaf(sacc[b][j][1],  C1_EXP, Bv1));
      const float P2  = __builtin_amdgcn_exp2f(fmaf(sacc[b][j][2],  C1_EXP, B2));
      const float Pv3 = __builtin_amdgcn_exp2f(fmaf(sacc[b][j][3],  C1_EXP, Bv3));
      const float pm1 = __builtin_amdgcn_exp2f(fmaf(sacc[b][j][1], -C1_EXP, Bm1));
      const float pm3 = __builtin_amdgcn_exp2f(fmaf(sacc[b][j][3], -C1_EXP, Bm3));
      const float mm = pm1 + pm3;
      lacc += (P0 + P2) + (Pv1 + Pv3) + mm;
      spacc += mm;
      union { uint2 u; __bf16 h[4]; } pk;
      pk.h[0] = (__bf16)P0;
      pk.h[1] = (__bf16)(Pv1 - pm1);
      pk.h[2] = (__bf16)P2;
      pk.h[3] = (__bf16)(Pv3 - pm3);
      *(uint2*)pwp[b][j] = pk.u;
    }
    lsum[b] += lacc;
    spsum[b] += spacc;
  }
  asm volatile("" ::: "memory");

  bf16x8 bp[2];
  bp[0] = *(const bf16x8*)prp[0];
  bp[1] = *(const bf16x8*)prp[1];
#pragma unroll
  for (int jc = 0; jc < 4; ++jc) {
    const bf16x8 av = *(const bf16x8*)vrp[jc];
    oacc[0][jc] = __builtin_amdgcn_mfma_f32_16x16x32_bf16(av, bp[0], oacc[0][jc], 0, 0, 0);
    oacc[1][jc] = __builtin_amdgcn_mfma_f32_16x16x32_bf16(av, bp[1], oacc[1][jc], 0, 0, 0);
  }
  BAR_LDS();
}

__global__ __launch_bounds__(256, 4) void k_attn_mfma(const __bf16* __restrict__ Qt,
                                                      const __bf16* __restrict__ Kt,
                                                      const __bf16* __restrict__ Vt,
                                                      const float* __restrict__ dq,
                                                      const float* __restrict__ uv,
                                                      __bf16* __restrict__ opart) {
  const int t0 = blockIdx.x * 128;
  const int bh = blockIdx.y;
  const __bf16* kt = Kt + (size_t)bh * 73728;
  const __bf16* vt = Vt + (size_t)bh * 73728;

  __shared__ __align__(16) char smem[16384];

  const int tid = threadIdx.x, lane = tid & 63, wv = tid >> 6;
  const int quad = lane >> 4, q16 = lane & 15;
  const int wband = wv * 32;

  const int rK = tid >> 3, gK = tid & 7;
  char* const kw = smem + rK * 128 + ((gK ^ (rK & 7)) * 16);
  const int cV = tid >> 2, gV = tid & 3;
  char* const vw = smem + 4096 + (cV >> 1) * 128 +
                   ((((cV & 1) * 4 + gV) ^ ((cV >> 1) & 7)) * 16);
  const __bf16* const kg = kt + (size_t)rK * 64 + gK * 8;
  const __bf16* const vg = vt + (size_t)cV * 1152 + gV * 8;

  const char* krp[2][2];
#pragma unroll
  for (int j = 0; j < 2; ++j)
#pragma unroll
    for (int kk = 0; kk < 2; ++kk)
      krp[j][kk] = smem + (j * 16 + q16) * 128 + (((kk * 4 + quad) ^ (q16 & 7)) * 16);
  const int a7 = (q16 >> 1) & 7, p1 = q16 & 1;
  const char* vrp[4];
#pragma unroll
  for (int jc = 0; jc < 4; ++jc)
    vrp[jc] = smem + 4096 + (jc * 8 + (q16 >> 1)) * 128 +
              (((p1 * 4 + quad) ^ a7) * 16);
  char* pwp[2][2];
  const char* prp[2];
#pragma unroll
  for (int b = 0; b < 2; ++b) {
    const int mrow = ((wband + b * 16) >> 1) + (q16 >> 1);
    prp[b] = smem + 8192 + mrow * 128 + (((p1 * 4 + quad) ^ a7) * 16);
#pragma unroll
    for (int j = 0; j < 2; ++j)
      pwp[b][j] = smem + 8192 + mrow * 128 +
                  (((p1 * 4 + j * 2 + (quad >> 1)) ^ a7) * 16) + (quad & 1) * 8;
  }

  const __bf16* qbase = Qt + (size_t)bh * 131072;
  bf16x8 bq[2][2];
  float Dm[2];
#pragma unroll
  for (int b = 0; b < 2; ++b) {
    const int t = t0 + wband + b * 16 + q16;
    const __bf16* qp = qbase + (size_t)t * 64 + quad * 8;
    bq[b][0] = *(const bf16x8*)qp;
    bq[b][1] = *(const bf16x8*)(qp + 32);
    Dm[b] = dq[(size_t)bh * 2048 + t] - C2_EXP;
  }

  f32x4 oacc[2][4] = {};
  float lsum[2] = {0.f, 0.f};
  float spsum[2] = {0.f, 0.f};

  // full 1056-slot pass. Interior while s0+31 < 1020 -> s0 < 992.
  const int send = 1056;
  uint4 kA = *(const uint4*)(kg);
  uint4 vA = *(const uint4*)(vg);

  for (int s0 = 0; s0 < 992; s0 += 32)
    attn_iter<false>(s0, send, quad, kg, vg, kw, vw, krp, vrp, pwp, prp,
                     bq, Dm, kA, vA, oacc, lsum, spsum);
  for (int s0 = 992; s0 < send; s0 += 32)
    attn_iter<true>(s0, send, quad, kg, vg, kw, vw, krp, vrp, pwp, prp,
                    bq, Dm, kA, vA, oacc, lsum, spsum);

  // epilogue-only uv load (kept out of the loop-live register set)
  float4 uv4[4];
  {
    const float* uvp = uv + (size_t)bh * 64;
#pragma unroll
    for (int jc = 0; jc < 4; ++jc)
      uv4[jc] = *(const float4*)(uvp + jc * 16 + quad * 4);
  }

#pragma unroll
  for (int b = 0; b < 2; ++b) {
    float l = lsum[b], sp = spsum[b];
    l += __shfl_xor(l, 16);
    l += __shfl_xor(l, 32);
    sp += __shfl_xor(sp, 16);
    sp += __shfl_xor(sp, 32);
    const float inv = 1.0f / l;         // l complete: self-normalize
    const float su = 2.0f * sp * inv;
    const int t = t0 + wband + b * 16 + q16;
    __bf16* opp = opart + ((size_t)bh * 2048 + t) * 64;
#pragma unroll
    for (int jc = 0; jc < 4; ++jc) {
      union { uint2 u; __bf16 h[4]; } pk;
      pk.h[0] = (__bf16)(oacc[b][jc][0] * inv + su * uv4[jc].x);
      pk.h[1] = (__bf16)(oacc[b][jc][1] * inv + su * uv4[jc].y);
      pk.h[2] = (__bf16)(oacc[b][jc][2] * inv + su * uv4[jc].z);
      pk.h[3] = (__bf16)(oacc[b][jc][3] * inv + su * uv4[jc].w);
      *(uint2*)(opp + jc * 16 + quad * 4) = pk.u;
    }
  }
}

// ---------------------------------------------------------------------------
// Kernel 6: proj GEMM (bf16 MFMA), double-buffered. r21: plain GEMM — opart
// is already normalized; no lpart, no 3-way combine. B staging is a direct
// uint4 copy (same as gemm_qkv).
// ---------------------------------------------------------------------------
__global__ __launch_bounds__(256) void k_gemm_proj(const float* __restrict__ W,
                                                   const __bf16* __restrict__ opart,
                                                   const float* __restrict__ bias,
                                                   float* __restrict__ C) {
  const int n0 = blockIdx.x * 128;
  const int bo = blockIdx.y * 64;
  const int b = blockIdx.z;
  float* Cb = C + (size_t)b * 524288;

  __shared__ __align__(16) char smem[30720];

  const int tid = threadIdx.x, lane = tid & 63, wv = tid >> 6;
  const int quad = lane >> 4, q16 = lane & 15, wn = wv * 32;

  const int rowA = tid >> 2, chA = (tid & 3) * 8;
  const int browB0 = tid >> 2, bchB = (tid & 3) * 8;
  const float* wA = W + (size_t)(bo + rowA) * 256 + chA;

  float4 aP0 = *(const float4*)(wA);
  float4 aP1 = *(const float4*)(wA + 4);
  uint4 oPd[2];
#pragma unroll
  for (int g = 0; g < 2; ++g) {
    const int t = n0 + browB0 + g * 64;
    // k0 = 0: channel = bchB (<64) -> head 0, cu = bchB
    const size_t rr = (size_t)(b * 4) * 2048 + t;
    oPd[g] = *(const uint4*)(opart + rr * 64 + bchB);
  }

  f32x4 acc[4][2] = {};
  int bsel = 0;
  for (int k0 = 0; k0 < 256; k0 += 32) {
    char* const Ab = smem + bsel;
    char* const Bb = smem + bsel + 5120;
    {
      union { uint4 u; __bf16 h[8]; } pa;
      pa.h[0] = (__bf16)aP0.x; pa.h[1] = (__bf16)aP0.y;
      pa.h[2] = (__bf16)aP0.z; pa.h[3] = (__bf16)aP0.w;
      pa.h[4] = (__bf16)aP1.x; pa.h[5] = (__bf16)aP1.y;
      pa.h[6] = (__bf16)aP1.z; pa.h[7] = (__bf16)aP1.w;
      *(uint4*)(Ab + rowA * 80 + chA * 2) = pa.u;
      *(uint4*)(Bb + browB0 * 80 + bchB * 2) = oPd[0];
      *(uint4*)(Bb + (browB0 + 64) * 80 + bchB * 2) = oPd[1];
    }
    __syncthreads();
    if (k0 + 32 < 256) {
      const int kn = k0 + 32;
      aP0 = *(const float4*)(wA + kn);
      aP1 = *(const float4*)(wA + kn + 4);
      const int c = kn + bchB;
      const int hd = c >> 6, cu = c & 63;
#pragma unroll
      for (int g = 0; g < 2; ++g) {
        const int t = n0 + browB0 + g * 64;
        const size_t rr = (size_t)(b * 4 + hd) * 2048 + t;
        oPd[g] = *(const uint4*)(opart + rr * 64 + cu);
      }
    }
    bf16x8 af[4], bfr[2];
#pragma unroll
    for (int mt = 0; mt < 4; ++mt)
      af[mt] = *(const bf16x8*)(Ab + (mt * 16 + q16) * 80 + quad * 16);
#pragma unroll
    for (int jn = 0; jn < 2; ++jn)
      bfr[jn] = *(const bf16x8*)(Bb + (wn + jn * 16 + q16) * 80 + quad * 16);
#pragma unroll
    for (int mt = 0; mt < 4; ++mt)
#pragma unroll
      for (int jn = 0; jn < 2; ++jn)
        acc[mt][jn] = __builtin_amdgcn_mfma_f32_16x16x32_bf16(af[mt], bfr[jn], acc[mt][jn], 0, 0, 0);
    bsel ^= 15360;
  }

#pragma unroll
  for (int mt = 0; mt < 4; ++mt)
#pragma unroll
    for (int r = 0; r < 4; ++r) {
      const int o = bo + mt * 16 + quad * 4 + r;
      const float bv = bias[o];
#pragma unroll
      for (int jn = 0; jn < 2; ++jn)
        Cb[(size_t)o * 2048 + n0 + wn + jn * 16 + q16] = acc[mt][jn][r] + bv;
    }
}

// ---------------------------------------------------------------------------
// Kernel 7: inverse FFT2 via split-bf16 MFMA. One slice per wave (r14 form),
// spec global loads issued before table staging.
// ---------------------------------------------------------------------------
__global__ __launch_bounds__(256) void k_ifft2(const float* __restrict__ spec,
                                               float* __restrict__ out,
                                               const __bf16* __restrict__ tw) {
  __shared__ __align__(16) char smem[51200];
  const int tid = threadIdx.x, lane = tid & 63, wv = tid >> 6;
  const int quad = lane >> 4, q16 = lane & 15;
  const int slice = blockIdx.x * 4 + wv;
  char* const wr_ = smem + 10240 + wv * 10240;

  // early spec global loads
  const float* sp = spec + (size_t)slice * 2048;
  float4 sv8[8];
#pragma unroll
  for (int u = 0; u < 8; ++u) sv8[u] = ((const float4*)sp)[u * 64 + lane];

  for (int i = tid; i < 512; i += 256) {
    const int t = i >> 7, r = (i >> 2) & 31, c8 = (i & 3) * 8;
    *(uint4*)(smem + t * 2560 + r * 80 + c8 * 2) =
        *(const uint4*)(tw + t * 1024 + r * 32 + c8);
  }

#pragma unroll
  for (int u = 0; u < 8; ++u) {
    const int f = u * 64 + lane;  // 0..511 float4 (2 complex each)
    const float4 v = sv8[u];
    const int k1 = f >> 4, k2 = (f & 15) * 2;
    char* base = wr_ + k1 * 80 + k2 * 2;
    union { unsigned int w; __bf16 b[2]; } p;
    const __bf16 rh0 = (__bf16)v.x, rh1 = (__bf16)v.z;
    const __bf16 ih0 = (__bf16)v.y, ih1 = (__bf16)v.w;
    p.b[0] = rh0; p.b[1] = rh1; *(unsigned int*)(base) = p.w;
    p.b[0] = (__bf16)(v.x - (float)rh0);
    p.b[1] = (__bf16)(v.z - (float)rh1); *(unsigned int*)(base + 2560) = p.w;
    p.b[0] = ih0; p.b[1] = ih1; *(unsigned int*)(base + 5120) = p.w;
    p.b[0] = (__bf16)(v.y - (float)ih0);
    p.b[1] = (__bf16)(v.w - (float)ih1); *(unsigned int*)(base + 7680) = p.w;
  }
  __syncthreads();  // tables visible; X same-wave ordered

  bf16x8 cch[2], ccl[2], ssh[2], ssl[2], ssnh[2], ssnl[2];
  bf16x8 xreh[2], xrel[2], ximh[2], ximl[2];
#pragma unroll
  for (int t2 = 0; t2 < 2; ++t2) {
    const int row = t2 * 16 + q16;
    cch[t2] = *(const bf16x8*)(smem + row * 80 + quad * 16);
    ccl[t2] = *(const bf16x8*)(smem + 2560 + row * 80 + quad * 16);
    ssh[t2] = *(const bf16x8*)(smem + 5120 + row * 80 + quad * 16);
    ssl[t2] = *(const bf16x8*)(smem + 7680 + row * 80 + quad * 16);
    xreh[t2] = *(const bf16x8*)(wr_ + row * 80 + quad * 16);
    xrel[t2] = *(const bf16x8*)(wr_ + 2560 + row * 80 + quad * 16);
    ximh[t2] = *(const bf16x8*)(wr_ + 5120 + row * 80 + quad * 16);
    ximl[t2] = *(const bf16x8*)(wr_ + 7680 + row * 80 + quad * 16);
  }
  ssnh[0] = neg8(ssh[0]); ssnh[1] = neg8(ssh[1]);
  ssnl[0] = neg8(ssl[0]); ssnl[1] = neg8(ssl[1]);

  // pass 1
  f32x4 yre[2][2] = {}, yim[2][2] = {};
#pragma unroll
  for (int mt = 0; mt < 2; ++mt)
#pragma unroll
    for (int nt = 0; nt < 2; ++nt) {
      MFMA3(yre[mt][nt], xreh[mt], xrel[mt], cch[nt], ccl[nt]);
      MFMA3(yre[mt][nt], ximh[mt], ximl[mt], ssnh[nt], ssnl[nt]);
      MFMA3(yim[mt][nt], xreh[mt], xrel[mt], ssh[nt], ssl[nt]);
      MFMA3(yim[mt][nt], ximh[mt], ximl[mt], cch[nt], ccl[nt]);
    }

  // write Yt transposed + split over the X regions (wave-private)
#pragma unroll
  for (int mt = 0; mt < 2; ++mt)
#pragma unroll
    for (int nt = 0; nt < 2; ++nt) {
      char* base = wr_ + (nt * 16 + q16) * 80 + (mt * 16 + quad * 4) * 2;
      union { unsigned long long q; __bf16 b[4]; } h, l;
#pragma unroll
      for (int r = 0; r < 4; ++r) {
        const float v = yre[mt][nt][r];
        h.b[r] = (__bf16)v; l.b[r] = (__bf16)(v - (float)h.b[r]);
      }
      *(unsigned long long*)(base) = h.q;
      *(unsigned long long*)(base + 2560) = l.q;
#pragma unroll
      for (int r = 0; r < 4; ++r) {
        const float v = yim[mt][nt][r];
        h.b[r] = (__bf16)v; l.b[r] = (__bf16)(v - (float)h.b[r]);
      }
      *(unsigned long long*)(base + 5120) = h.q;
      *(unsigned long long*)(base + 7680) = l.q;
    }
  asm volatile("" ::: "memory");

  bf16x8 yreh[2], yrel[2], yimh[2], yiml[2];
#pragma unroll
  for (int nt = 0; nt < 2; ++nt) {
    const int row = nt * 16 + q16;
    yreh[nt] = *(const bf16x8*)(wr_ + row * 80 + quad * 16);
    yrel[nt] = *(const bf16x8*)(wr_ + 2560 + row * 80 + quad * 16);
    yimh[nt] = *(const bf16x8*)(wr_ + 5120 + row * 80 + quad * 16);
    yiml[nt] = *(const bf16x8*)(wr_ + 7680 + row * 80 + quad * 16);
  }

  // pass 2
  f32x4 zre[2][2] = {}, zim[2][2] = {};
#pragma unroll
  for (int mt = 0; mt < 2; ++mt)
#pragma unroll
    for (int nt = 0; nt < 2; ++nt) {
      MFMA3(zre[mt][nt], cch[mt], ccl[mt], yreh[nt], yrel[nt]);
      MFMA3(zre[mt][nt], ssnh[mt], ssnl[mt], yimh[nt], yiml[nt]);
      MFMA3(zim[mt][nt], cch[mt], ccl[mt], yimh[nt], yiml[nt]);
      MFMA3(zim[mt][nt], ssh[mt], ssl[mt], yreh[nt], yrel[nt]);
    }

  float* op = out + (size_t)slice * 2048;
#pragma unroll
  for (int mt = 0; mt < 2; ++mt)
#pragma unroll
    for (int nt = 0; nt < 2; ++nt)
#pragma unroll
      for (int r = 0; r < 4; ++r) {
        const int n1 = mt * 16 + quad * 4 + r;
        const int n2 = nt * 16 + q16;
        float2 st;
        st.x = zre[mt][nt][r] * (1.0f / 1024.0f);
        st.y = zim[mt][nt][r] * (1.0f / 1024.0f);
        *(float2*)(op + 2 * (n1 * 32 + n2)) = st;
      }
}

// ---------------------------------------------------------------------------
extern "C" void kernel_launch(void* const* d_in, const int* in_sizes, int n_in,
                              void* d_out, int out_size, void* d_ws, size_t ws_size,
                              hipStream_t stream) {
  (void)in_sizes; (void)n_in; (void)out_size; (void)ws_size;
  const float* x      = (const float*)d_in[0];
  const float* gn_w   = (const float*)d_in[1];
  const float* gn_b   = (const float*)d_in[2];
  const float* qkv_w  = (const float*)d_in[3];
  const float* qkv_b  = (const float*)d_in[4];
  const float* proj_w = (const float*)d_in[5];
  const float* proj_b = (const float*)d_in[6];
  float* out = (float*)d_out;

  float* spec  = (float*)d_ws;
  __bf16* Qt   = (__bf16*)(spec + 4194304);   // 4194304 elems
  __bf16* Kt   = Qt + 4194304;                // 2359296 elems (32*1152*64)
  __bf16* Vt   = Kt + 2359296;                // 2359296 elems
  float* stats = (float*)(Vt + 2359296);      // 512
  float* xr    = stats + 512;                 // 4194304 floats
  __bf16* xt   = (__bf16*)(xr + 4194304);     // 4194304 bf16
  __bf16* opart = (__bf16*)xr;                // 4194304 bf16 (clobbers xr; single-part)
  float*  dq    = (float*)(opart + 12582912); // 65536 (offset kept from 3-part era)
  float*  uk    = dq + 65536;                 // 2048
  float*  uv    = uk + 2048;                  // 2048
  __bf16* tw    = (__bf16*)(uv + 2048);       // 4096 bf16 twiddle tables

  hipMemsetAsync(stats, 0, 512 * sizeof(float), stream);
  k_twid<<<1, 256, 0, stream>>>(tw);
  k_fft2<<<512, 256, 0, stream>>>(x, xr, stats, tw);
  k_uvec<<<64, 256, 0, stream>>>(stats, gn_w, gn_b, qkv_w, qkv_b, uk, uv);
  k_gntrans<<<dim3(32, 4, 8), 256, 0, stream>>>(xr, stats, gn_w, gn_b, xt);
  k_gemm_qkv<<<dim3(136, 8), 256, 0, stream>>>(qkv_w, xt, qkv_b, uk, dq,
                                               Qt, Kt, Vt);
  k_attn_mfma<<<dim3(16, 32), 256, 0, stream>>>(Qt, Kt, Vt, dq, uv, opart);
  k_gemm_proj<<<dim3(16, 4, 8), 256, 0, stream>>>(proj_w, opart, proj_b, spec);
  k_ifft2<<<512, 256, 0, stream>>>(spec, out, tw);
}

// Round 7
// 158.389 us; speedup vs baseline: 1.2064x; 1.0433x over previous
//
#include <hip/hip_runtime.h>
#include <hip/hip_bf16.h>
#include <stdint.h>

#define PI_F 3.14159265358979323846f
#define C1_EXP 0.18033688f   // log2(e)/8
#define C2_EXP 23.083120f    // 16*log2(e)

typedef __bf16 bf16x8 __attribute__((ext_vector_type(8)));
typedef float f32x4 __attribute__((ext_vector_type(4)));
typedef unsigned int uint32x4 __attribute__((ext_vector_type(4)));

// LDS-only barrier: s_barrier with lgkmcnt drain but NO vmcnt drain, so
// in-flight global prefetch loads survive across the barrier (T4-minimal).
// Proven +3us on attn in r20.
#define BAR_LDS() asm volatile("s_waitcnt lgkmcnt(0)\n\ts_barrier" ::: "memory")

__device__ __forceinline__ bf16x8 neg8(bf16x8 v) {
  union { bf16x8 b; uint32x4 u; } x;
  x.b = v;
  x.u ^= (uint32x4){0x80008000u, 0x80008000u, 0x80008000u, 0x80008000u};
  return x.b;
}

// 3-term split-accumulate: P*Q with P=Ph+Pl, Q=Qh+Ql (drop Pl*Ql ~2^-18)
#define MFMA3(acc, Ph, Pl, Qh, Ql)                                        \
  acc = __builtin_amdgcn_mfma_f32_16x16x32_bf16(Ph, Qh, acc, 0, 0, 0);    \
  acc = __builtin_amdgcn_mfma_f32_16x16x32_bf16(Ph, Ql, acc, 0, 0, 0);    \
  acc = __builtin_amdgcn_mfma_f32_16x16x32_bf16(Pl, Qh, acc, 0, 0, 0);

// Closed-form base-slot -> original column mapping.
__device__ __forceinline__ int slot2n(int slot) {
  const int pi = slot >> 1, im = slot & 1;
  int k1, k2;
  if (pi < 480)      { k1 = 1 + (pi >> 5); k2 = pi & 31; }
  else if (pi < 495) { k1 = 0;  k2 = pi - 479; }
  else if (pi < 510) { k1 = 16; k2 = pi - 494; }
  else if (pi < 514) { k1 = ((pi - 510) >> 1) * 16; k2 = ((pi - 510) & 1) * 16; }
  else               { k1 = 0; k2 = 0; }
  return 2 * (k1 * 32 + k2) + im;
}

// Inline twiddle-table build (r22: replaces k_twid kernel + global staging).
// Identical arithmetic to the old k_twid -> bit-identical tables. Writes the
// hi/lo-split bf16 tables into LDS at the same layout the staging produced:
// [cos_hi @0][cos_lo @2560][sin_hi @5120][sin_lo @7680], entry (j,k) at
// j*80 + k*2 within each region.
__device__ __forceinline__ void build_twiddle_lds(char* smem, int tid) {
  for (int e = tid; e < 1024; e += 256) {
    const int j = e >> 5, k = e & 31;
    const int t = (j * k) & 31;
    float sv, cv;
    sincosf(2.0f * PI_F * (float)t / 32.0f, &sv, &cv);
    const __bf16 ch = (__bf16)cv, sh = (__bf16)sv;
    *(__bf16*)(smem + j * 80 + k * 2) = ch;
    *(__bf16*)(smem + 2560 + j * 80 + k * 2) = (__bf16)(cv - (float)ch);
    *(__bf16*)(smem + 5120 + j * 80 + k * 2) = sh;
    *(__bf16*)(smem + 7680 + j * 80 + k * 2) = (__bf16)(sv - (float)sh);
  }
}

// ---------------------------------------------------------------------------
// Kernel 1: forward FFT2 via split-bf16 MFMA. One slice per wave (r14
// measured-best barrier-free form). r22: twiddle tables computed inline
// (k_twid deleted); stats written as per-slice partials (memset deleted).
// ---------------------------------------------------------------------------
__global__ __launch_bounds__(256) void k_fft2(const float* __restrict__ x,
                                              float* __restrict__ xr,
                                              float* __restrict__ stats_part) {
  __shared__ __align__(16) char smem[51200];
  const int tid = threadIdx.x, lane = tid & 63, wv = tid >> 6;
  const int quad = lane >> 4, q16 = lane & 15;
  const int slice = blockIdx.x * 4 + wv;
  char* const wr_ = smem + 10240 + wv * 10240;

  // early X global loads (wave-private region; overlap with table build)
  const float* xs = x + (size_t)slice * 1024;
  float4 xv[4];
#pragma unroll
  for (int u = 0; u < 4; ++u) xv[u] = ((const float4*)xs)[u * 64 + lane];

  build_twiddle_lds(smem, tid);

  // X split + stage (same-wave ds ordering)
#pragma unroll
  for (int u = 0; u < 4; ++u) {
    const int f = u * 64 + lane;
    const float4 v = xv[u];
    const int row = f >> 3, c4 = (f & 7) * 4;
    union { unsigned long long q; __bf16 b[4]; } ph, pl;
    ph.b[0] = (__bf16)v.x; ph.b[1] = (__bf16)v.y;
    ph.b[2] = (__bf16)v.z; ph.b[3] = (__bf16)v.w;
    pl.b[0] = (__bf16)(v.x - (float)ph.b[0]);
    pl.b[1] = (__bf16)(v.y - (float)ph.b[1]);
    pl.b[2] = (__bf16)(v.z - (float)ph.b[2]);
    pl.b[3] = (__bf16)(v.w - (float)ph.b[3]);
    *(unsigned long long*)(wr_ + row * 80 + c4 * 2) = ph.q;
    *(unsigned long long*)(wr_ + 2560 + row * 80 + c4 * 2) = pl.q;
  }
  __syncthreads();  // tables visible to all waves; X same-wave ordered

  bf16x8 cch[2], ccl[2], ssh[2], ssl[2], xh[2], xl[2];
#pragma unroll
  for (int t2 = 0; t2 < 2; ++t2) {
    const int row = t2 * 16 + q16;
    cch[t2] = *(const bf16x8*)(smem + row * 80 + quad * 16);
    ccl[t2] = *(const bf16x8*)(smem + 2560 + row * 80 + quad * 16);
    ssh[t2] = *(const bf16x8*)(smem + 5120 + row * 80 + quad * 16);
    ssl[t2] = *(const bf16x8*)(smem + 7680 + row * 80 + quad * 16);
    xh[t2] = *(const bf16x8*)(wr_ + row * 80 + quad * 16);
    xl[t2] = *(const bf16x8*)(wr_ + 2560 + row * 80 + quad * 16);
  }

  // pass 1: Yre = X@Cc, Yim = -(X@Ss)
  f32x4 yre[2][2] = {}, yim[2][2] = {};
#pragma unroll
  for (int mt = 0; mt < 2; ++mt)
#pragma unroll
    for (int nt = 0; nt < 2; ++nt) {
      MFMA3(yre[mt][nt], xh[mt], xl[mt], cch[nt], ccl[nt]);
      MFMA3(yim[mt][nt], xh[mt], xl[mt], ssh[nt], ssl[nt]);
    }

  // write Yt transposed + split (wave-private; same-wave ordering)
#pragma unroll
  for (int mt = 0; mt < 2; ++mt)
#pragma unroll
    for (int nt = 0; nt < 2; ++nt) {
      char* base = wr_ + (nt * 16 + q16) * 80 + (mt * 16 + quad * 4) * 2;
      union { unsigned long long q; __bf16 b[4]; } h, l;
#pragma unroll
      for (int r = 0; r < 4; ++r) {
        const float v = yre[mt][nt][r];
        h.b[r] = (__bf16)v; l.b[r] = (__bf16)(v - (float)h.b[r]);
      }
      *(unsigned long long*)(base) = h.q;
      *(unsigned long long*)(base + 2560) = l.q;
#pragma unroll
      for (int r = 0; r < 4; ++r) {
        const float v = -yim[mt][nt][r];
        h.b[r] = (__bf16)v; l.b[r] = (__bf16)(v - (float)h.b[r]);
      }
      *(unsigned long long*)(base + 5120) = h.q;
      *(unsigned long long*)(base + 7680) = l.q;
    }
  asm volatile("" ::: "memory");

  bf16x8 yreh[2], yrel[2], yimh[2], yiml[2];
#pragma unroll
  for (int nt = 0; nt < 2; ++nt) {
    const int row = nt * 16 + q16;
    yreh[nt] = *(const bf16x8*)(wr_ + row * 80 + quad * 16);
    yrel[nt] = *(const bf16x8*)(wr_ + 2560 + row * 80 + quad * 16);
    yimh[nt] = *(const bf16x8*)(wr_ + 5120 + row * 80 + quad * 16);
    yiml[nt] = *(const bf16x8*)(wr_ + 7680 + row * 80 + quad * 16);
  }

  // pass 2: Zre = Cc@Yre + Ss@Yim ; Zim = Cc@Yim - Ss@Yre
  f32x4 zre[2][2] = {}, zim[2][2] = {};
  bf16x8 ssnh[2], ssnl[2];
  ssnh[0] = neg8(ssh[0]); ssnh[1] = neg8(ssh[1]);
  ssnl[0] = neg8(ssl[0]); ssnl[1] = neg8(ssl[1]);
#pragma unroll
  for (int mt = 0; mt < 2; ++mt)
#pragma unroll
    for (int nt = 0; nt < 2; ++nt) {
      MFMA3(zre[mt][nt], cch[mt], ccl[mt], yreh[nt], yrel[nt]);
      MFMA3(zre[mt][nt], ssh[mt], ssl[mt], yimh[nt], yiml[nt]);
      MFMA3(zim[mt][nt], cch[mt], ccl[mt], yimh[nt], yiml[nt]);
      MFMA3(zim[mt][nt], ssnh[mt], ssnl[mt], yreh[nt], yrel[nt]);
    }

  // stats + store
  float* op = xr + (size_t)slice * 2048;
  float s1 = 0.f, s2 = 0.f;
#pragma unroll
  for (int mt = 0; mt < 2; ++mt)
#pragma unroll
    for (int nt = 0; nt < 2; ++nt)
#pragma unroll
      for (int r = 0; r < 4; ++r) {
        const int k1 = mt * 16 + quad * 4 + r;
        const int k2 = nt * 16 + q16;
        const float a = zre[mt][nt][r], bimg = zim[mt][nt][r];
        s1 += a + bimg;
        s2 += a * a + bimg * bimg;
        float2 st; st.x = a; st.y = bimg;
        *(float2*)(op + 2 * (k1 * 32 + k2)) = st;
      }
#pragma unroll
  for (int off = 1; off <= 32; off <<= 1) {
    s1 += __shfl_xor(s1, off);
    s2 += __shfl_xor(s2, off);
  }
  if (lane == 0) {
    // per-slice partial (written exactly once -> no zeroing, no atomics)
    const int bg = (slice >> 8) * 32 + ((slice & 255) >> 3);
    const int sub = slice & 7;
    float2 st; st.x = s1; st.y = s2;
    *(float2*)(stats_part + (size_t)(bg * 8 + sub) * 2) = st;
  }
}

// ---------------------------------------------------------------------------
// Kernel 2: mirror-correction vectors; r22: sums 8 stats partials.
// ---------------------------------------------------------------------------
__global__ __launch_bounds__(256) void k_uvec(const float* __restrict__ stats_part,
                                              const float* __restrict__ gn_w,
                                              const float* __restrict__ gn_b,
                                              const float* __restrict__ qkv_w,
                                              const float* __restrict__ qkv_b,
                                              float* __restrict__ uk,
                                              float* __restrict__ uv) {
  const int blk = blockIdx.x;
  const int tid = threadIdx.x;
  const int b = blk >> 3, h = (blk >> 1) & 3, role = blk & 1;
  __shared__ float Bsh[256];
  {
    const int g = tid >> 3;
    float S = 0.f, S2 = 0.f;
#pragma unroll
    for (int s = 0; s < 8; ++s) {
      S  += stats_part[((b * 32 + g) * 8 + s) * 2];
      S2 += stats_part[((b * 32 + g) * 8 + s) * 2 + 1];
    }
    const float mean = S * (1.0f / 16384.0f);
    const float var = S2 * (1.0f / 16384.0f) - mean * mean;
    const float rstd = rsqrtf(var + 1e-5f);
    Bsh[tid] = gn_b[tid] - mean * rstd * gn_w[tid];
  }
  __syncthreads();
  const int cp = tid >> 2, seg = tid & 3;
  const int row = h * 192 + 64 + role * 64 + cp;
  const float* wr_ = qkv_w + (size_t)row * 256 + seg * 64;
  const float* bs = Bsh + seg * 64;
  float s = 0.f;
#pragma unroll
  for (int i = 0; i < 16; ++i) {
    const float4 w4 = *(const float4*)(wr_ + i * 4);
    const float4 b4 = *(const float4*)(bs + i * 4);
    s += w4.x * b4.x + w4.y * b4.y + w4.z * b4.z + w4.w * b4.w;
  }
  s += __shfl_xor(s, 1);
  s += __shfl_xor(s, 2);
  if (seg == 0) {
    float* dst = (role == 0) ? uk : uv;
    dst[(size_t)(b * 4 + h) * 64 + cp] = s + qkv_b[row];
  }
}

// ---------------------------------------------------------------------------
// Kernel 3: GroupNorm apply + transpose to bf16 X^T [b][n][c];
// r22: per-block gsum reduction of the 8 stats partials (tid<8 pre-step).
// ---------------------------------------------------------------------------
__global__ __launch_bounds__(256) void k_gntrans(const float* __restrict__ xr,
                                                 const float* __restrict__ stats_part,
                                                 const float* __restrict__ w,
                                                 const float* __restrict__ bias,
                                                 __bf16* __restrict__ xt) {
  const int n0 = blockIdx.x * 64;
  const int c0 = blockIdx.y * 64;
  const int b = blockIdx.z;
  __shared__ __bf16 Lt[64][72];
  __shared__ float gsum[8][2];
  const int tid = threadIdx.x;
  if (tid < 8) {
    const int g = (c0 >> 3) + tid;
    float S = 0.f, S2 = 0.f;
#pragma unroll
    for (int s = 0; s < 8; ++s) {
      S  += stats_part[((b * 32 + g) * 8 + s) * 2];
      S2 += stats_part[((b * 32 + g) * 8 + s) * 2 + 1];
    }
    gsum[tid][0] = S;
    gsum[tid][1] = S2;
  }
  __syncthreads();
  for (int i = tid; i < 1024; i += 256) {
    const int cl = i >> 4, c = c0 + cl, nl = (i & 15) * 4;
    const float S = gsum[cl >> 3][0];
    const float S2 = gsum[cl >> 3][1];
    const float mean = S * (1.0f / 16384.0f);
    const float var = S2 * (1.0f / 16384.0f) - mean * mean;
    const float rstd = rsqrtf(var + 1e-5f);
    const float sc = rstd * w[c];
    const float sh = bias[c] - mean * sc;
    const float4 v = *(const float4*)(xr + ((size_t)b * 256 + c) * 2048 + n0 + nl);
    Lt[nl][cl] = (__bf16)(v.x * sc + sh);
    Lt[nl + 1][cl] = (__bf16)(v.y * sc + sh);
    Lt[nl + 2][cl] = (__bf16)(v.z * sc + sh);
    Lt[nl + 3][cl] = (__bf16)(v.w * sc + sh);
  }
  __syncthreads();
  __bf16* dst = xt + (size_t)b * 524288 + (size_t)n0 * 256 + c0;
  for (int i = tid; i < 512; i += 256) {
    const int nl = i >> 3, cch = (i & 7) * 8;
    *(uint4*)(dst + (size_t)nl * 256 + cch) = *(const uint4*)&Lt[nl][cch];
  }
}

// ---------------------------------------------------------------------------
// Kernel 4: QKV GEMM (bf16 MFMA), double-buffered LDS; unchanged.
// ---------------------------------------------------------------------------
__global__ __launch_bounds__(256) void k_gemm_qkv(const float* __restrict__ W,
                                                  const __bf16* __restrict__ X,
                                                  const float* __restrict__ bias,
                                                  const float* __restrict__ uk,
                                                  float* __restrict__ dq,
                                                  __bf16* __restrict__ Qt,
                                                  __bf16* __restrict__ Kt,
                                                  __bf16* __restrict__ Vt) {
  const int tx = blockIdx.x;
  const int b = blockIdx.y;
  int role, hd, nt;
  if (tx < 64) { role = 0; hd = tx >> 4; nt = tx & 15; }
  else if (tx < 100) { role = 1; const int i = tx - 64; hd = i / 9; nt = i - hd * 9; }
  else { role = 2; const int i = tx - 100; hd = i / 9; nt = i - hd * 9; }
  const int n0 = nt * 128;
  const int bo = hd * 192 + role * 64;
  const __bf16* Xb = X + (size_t)b * 524288;

  __shared__ __align__(16) char smem[30720];
  __bf16 (*Ot)[72] = (__bf16(*)[72])smem;
  __bf16 (*Ot2)[136] = (__bf16(*)[136])smem;

  const int tid = threadIdx.x, lane = tid & 63, wv = tid >> 6;
  const int quad = lane >> 4, q16 = lane & 15, wn = wv * 32;

  const int rowA = tid >> 2, chA = (tid & 3) * 8;
  const int browB0 = tid >> 2, bchB = (tid & 3) * 8;
  const float* wA = W + (size_t)(bo + rowA) * 256 + chA;

  const int s0r = n0 + browB0, s1r = n0 + browB0 + 64;
  const int pn0 = (role == 0) ? s0r : slot2n(s0r);
  const int pn1 = (role == 0) ? s1r : slot2n(s1r);

  float4 aP0 = *(const float4*)(wA);
  float4 aP1 = *(const float4*)(wA + 4);
  uint4 bP0 = *(const uint4*)(Xb + (size_t)pn0 * 256 + bchB);
  uint4 bP1 = *(const uint4*)(Xb + (size_t)pn1 * 256 + bchB);

  f32x4 acc[4][2] = {};
  int bsel = 0;
  for (int k0 = 0; k0 < 256; k0 += 32) {
    char* const Ab = smem + bsel;
    char* const Bb = smem + bsel + 5120;
    {
      union { uint4 u; __bf16 h[8]; } pa;
      pa.h[0] = (__bf16)aP0.x; pa.h[1] = (__bf16)aP0.y;
      pa.h[2] = (__bf16)aP0.z; pa.h[3] = (__bf16)aP0.w;
      pa.h[4] = (__bf16)aP1.x; pa.h[5] = (__bf16)aP1.y;
      pa.h[6] = (__bf16)aP1.z; pa.h[7] = (__bf16)aP1.w;
      *(uint4*)(Ab + rowA * 80 + chA * 2) = pa.u;
      *(uint4*)(Bb + browB0 * 80 + bchB * 2) = bP0;
      *(uint4*)(Bb + (browB0 + 64) * 80 + bchB * 2) = bP1;
    }
    __syncthreads();
    if (k0 + 32 < 256) {
      const int kn = k0 + 32;
      aP0 = *(const float4*)(wA + kn);
      aP1 = *(const float4*)(wA + kn + 4);
      bP0 = *(const uint4*)(Xb + (size_t)pn0 * 256 + kn + bchB);
      bP1 = *(const uint4*)(Xb + (size_t)pn1 * 256 + kn + bchB);
    }
    bf16x8 af[4], bfr[2];
#pragma unroll
    for (int mt = 0; mt < 4; ++mt)
      af[mt] = *(const bf16x8*)(Ab + (mt * 16 + q16) * 80 + quad * 16);
#pragma unroll
    for (int jn = 0; jn < 2; ++jn)
      bfr[jn] = *(const bf16x8*)(Bb + (wn + jn * 16 + q16) * 80 + quad * 16);
#pragma unroll
    for (int mt = 0; mt < 4; ++mt)
#pragma unroll
      for (int jn = 0; jn < 2; ++jn)
        acc[mt][jn] = __builtin_amdgcn_mfma_f32_16x16x32_bf16(af[mt], bfr[jn], acc[mt][jn], 0, 0, 0);
    bsel ^= 15360;
  }
  __syncthreads();

  const int bh = b * 4 + hd;
  if (role == 2) {
#pragma unroll
    for (int mt = 0; mt < 4; ++mt)
#pragma unroll
      for (int r = 0; r < 4; ++r) {
        const int c = mt * 16 + quad * 4 + r;
        const float bv = bias[bo + c];
#pragma unroll
        for (int jn = 0; jn < 2; ++jn)
          Ot2[c][wn + jn * 16 + q16] = (__bf16)(acc[mt][jn][r] + bv);
      }
    __syncthreads();
    __bf16* dst = Vt + (size_t)bh * 73728;  // [c][1152]
    for (int i = tid; i < 1024; i += 256) {
      const int c = i >> 4, sg = (i & 15) * 8;
      *(uint4*)(dst + (size_t)c * 1152 + n0 + sg) = *(const uint4*)&Ot2[c][sg];
    }
  } else {
    __bf16* dst = (role == 0 ? Qt + (size_t)bh * 131072
                             : Kt + (size_t)bh * 73728);  // [n][64]
#pragma unroll
    for (int mt = 0; mt < 4; ++mt)
#pragma unroll
      for (int r = 0; r < 4; ++r) {
        const int c = mt * 16 + quad * 4 + r;
        const float bv = bias[bo + c];
#pragma unroll
        for (int jn = 0; jn < 2; ++jn)
          Ot[wn + jn * 16 + q16][c] = (__bf16)(acc[mt][jn][r] + bv);
      }
    __syncthreads();
    for (int i = tid; i < 1024; i += 256) {
      const int nl = i >> 3, cch = (i & 7) * 8;
      *(uint4*)(dst + (size_t)(n0 + nl) * 64 + cch) = *(const uint4*)&Ot[nl][cch];
    }
    if (role == 0 && tid < 128) {
      const float* ukp = uk + (size_t)bh * 64;
      float dv = 0.f;
#pragma unroll
      for (int g8 = 0; g8 < 8; ++g8) {
        const bf16x8 qv = *(const bf16x8*)&Ot[tid][g8 * 8];
#pragma unroll
        for (int k = 0; k < 8; ++k) dv += (float)qv[k] * ukp[g8 * 8 + k];
      }
      dq[(size_t)bh * 2048 + n0 + tid] = dv * (2.0f * C1_EXP);
    }
  }
}

// ---------------------------------------------------------------------------
// Kernel 5: MFMA flash attention. r21 single-part form (self-normalized
// output); unchanged.
// ---------------------------------------------------------------------------
template <bool EDGE>
__device__ __forceinline__ void attn_iter(
    const int s0, const int send, const int quad,
    const __bf16* __restrict__ kg, const __bf16* __restrict__ vg,
    char* const kw, char* const vw,
    const char* const (&krp)[2][2], const char* const (&vrp)[4],
    char* const (&pwp)[2][2], const char* const (&prp)[2],
    const bf16x8 (&bq)[2][2], const float (&Dm)[2],
    uint4& kA, uint4& vA, f32x4 (&oacc)[2][4],
    float (&lsum)[2], float (&spsum)[2]) {
  *(uint4*)kw = kA;
  *(uint4*)vw = vA;
  BAR_LDS();
  if (s0 + 32 < send) {
    kA = *(const uint4*)(kg + (size_t)(s0 + 32) * 64);
    vA = *(const uint4*)(vg + s0 + 32);
  }

  f32x4 sacc[2][2] = {};
#pragma unroll
  for (int j = 0; j < 2; ++j)
#pragma unroll
    for (int kk = 0; kk < 2; ++kk) {
      const bf16x8 ak = *(const bf16x8*)krp[j][kk];
      sacc[0][j] = __builtin_amdgcn_mfma_f32_16x16x32_bf16(ak, bq[0][kk], sacc[0][j], 0, 0, 0);
      sacc[1][j] = __builtin_amdgcn_mfma_f32_16x16x32_bf16(ak, bq[1][kk], sacc[1][j], 0, 0, 0);
    }

#pragma unroll
  for (int b = 0; b < 2; ++b) {
    float lacc = 0.f, spacc = 0.f;
#pragma unroll
    for (int j = 0; j < 2; ++j) {
      float B0, B2, Bv1, Bv3, Bm1, Bm3;
      if (EDGE) {
        const int sg = s0 + j * 16 + quad * 4;
        B0 = (sg < 1020) ? (1.0f - C2_EXP) : ((sg < 1028) ? -C2_EXP : -1e30f);
        B2 = (sg + 2 < 1020) ? (1.0f - C2_EXP)
                             : ((sg + 2 < 1028) ? -C2_EXP : -1e30f);
        Bv1 = (sg + 1 < 1028) ? -C2_EXP : -1e30f;
        Bv3 = (sg + 3 < 1028) ? -C2_EXP : -1e30f;
        Bm1 = (sg + 1 < 1020) ? Dm[b] : -1e30f;
        Bm3 = (sg + 3 < 1020) ? Dm[b] : -1e30f;
      } else {
        B0 = 1.0f - C2_EXP;
        B2 = 1.0f - C2_EXP;
        Bv1 = -C2_EXP;
        Bv3 = -C2_EXP;
        Bm1 = Dm[b];
        Bm3 = Dm[b];
      }
      const float P0  = __builtin_amdgcn_exp2f(fmaf(sacc[b][j][0],  C1_EXP, B0));
      const float Pv1 = __builtin_amdgcn_exp2f(fmaf(sacc[b][j][1],  C1_EXP, Bv1));
      const float P2  = __builtin_amdgcn_exp2f(fmaf(sacc[b][j][2],  C1_EXP, B2));
      const float Pv3 = __builtin_amdgcn_exp2f(fmaf(sacc[b][j][3],  C1_EXP, Bv3));
      const float pm1 = __builtin_amdgcn_exp2f(fmaf(sacc[b][j][1], -C1_EXP, Bm1));
      const float pm3 = __builtin_amdgcn_exp2f(fmaf(sacc[b][j][3], -C1_EXP, Bm3));
      const float mm = pm1 + pm3;
      lacc += (P0 + P2) + (Pv1 + Pv3) + mm;
      spacc += mm;
      union { uint2 u; __bf16 h[4]; } pk;
      pk.h[0] = (__bf16)P0;
      pk.h[1] = (__bf16)(Pv1 - pm1);
      pk.h[2] = (__bf16)P2;
      pk.h[3] = (__bf16)(Pv3 - pm3);
      *(uint2*)pwp[b][j] = pk.u;
    }
    lsum[b] += lacc;
    spsum[b] += spacc;
  }
  asm volatile("" ::: "memory");

  bf16x8 bp[2];
  bp[0] = *(const bf16x8*)prp[0];
  bp[1] = *(const bf16x8*)prp[1];
#pragma unroll
  for (int jc = 0; jc < 4; ++jc) {
    const bf16x8 av = *(const bf16x8*)vrp[jc];
    oacc[0][jc] = __builtin_amdgcn_mfma_f32_16x16x32_bf16(av, bp[0], oacc[0][jc], 0, 0, 0);
    oacc[1][jc] = __builtin_amdgcn_mfma_f32_16x16x32_bf16(av, bp[1], oacc[1][jc], 0, 0, 0);
  }
  BAR_LDS();
}

__global__ __launch_bounds__(256, 4) void k_attn_mfma(const __bf16* __restrict__ Qt,
                                                      const __bf16* __restrict__ Kt,
                                                      const __bf16* __restrict__ Vt,
                                                      const float* __restrict__ dq,
                                                      const float* __restrict__ uv,
                                                      __bf16* __restrict__ opart) {
  const int t0 = blockIdx.x * 128;
  const int bh = blockIdx.y;
  const __bf16* kt = Kt + (size_t)bh * 73728;
  const __bf16* vt = Vt + (size_t)bh * 73728;

  __shared__ __align__(16) char smem[16384];

  const int tid = threadIdx.x, lane = tid & 63, wv = tid >> 6;
  const int quad = lane >> 4, q16 = lane & 15;
  const int wband = wv * 32;

  const int rK = tid >> 3, gK = tid & 7;
  char* const kw = smem + rK * 128 + ((gK ^ (rK & 7)) * 16);
  const int cV = tid >> 2, gV = tid & 3;
  char* const vw = smem + 4096 + (cV >> 1) * 128 +
                   ((((cV & 1) * 4 + gV) ^ ((cV >> 1) & 7)) * 16);
  const __bf16* const kg = kt + (size_t)rK * 64 + gK * 8;
  const __bf16* const vg = vt + (size_t)cV * 1152 + gV * 8;

  const char* krp[2][2];
#pragma unroll
  for (int j = 0; j < 2; ++j)
#pragma unroll
    for (int kk = 0; kk < 2; ++kk)
      krp[j][kk] = smem + (j * 16 + q16) * 128 + (((kk * 4 + quad) ^ (q16 & 7)) * 16);
  const int a7 = (q16 >> 1) & 7, p1 = q16 & 1;
  const char* vrp[4];
#pragma unroll
  for (int jc = 0; jc < 4; ++jc)
    vrp[jc] = smem + 4096 + (jc * 8 + (q16 >> 1)) * 128 +
              (((p1 * 4 + quad) ^ a7) * 16);
  char* pwp[2][2];
  const char* prp[2];
#pragma unroll
  for (int b = 0; b < 2; ++b) {
    const int mrow = ((wband + b * 16) >> 1) + (q16 >> 1);
    prp[b] = smem + 8192 + mrow * 128 + (((p1 * 4 + quad) ^ a7) * 16);
#pragma unroll
    for (int j = 0; j < 2; ++j)
      pwp[b][j] = smem + 8192 + mrow * 128 +
                  (((p1 * 4 + j * 2 + (quad >> 1)) ^ a7) * 16) + (quad & 1) * 8;
  }

  const __bf16* qbase = Qt + (size_t)bh * 131072;
  bf16x8 bq[2][2];
  float Dm[2];
#pragma unroll
  for (int b = 0; b < 2; ++b) {
    const int t = t0 + wband + b * 16 + q16;
    const __bf16* qp = qbase + (size_t)t * 64 + quad * 8;
    bq[b][0] = *(const bf16x8*)qp;
    bq[b][1] = *(const bf16x8*)(qp + 32);
    Dm[b] = dq[(size_t)bh * 2048 + t] - C2_EXP;
  }

  f32x4 oacc[2][4] = {};
  float lsum[2] = {0.f, 0.f};
  float spsum[2] = {0.f, 0.f};

  // full 1056-slot pass. Interior while s0+31 < 1020 -> s0 < 992.
  const int send = 1056;
  uint4 kA = *(const uint4*)(kg);
  uint4 vA = *(const uint4*)(vg);

  for (int s0 = 0; s0 < 992; s0 += 32)
    attn_iter<false>(s0, send, quad, kg, vg, kw, vw, krp, vrp, pwp, prp,
                     bq, Dm, kA, vA, oacc, lsum, spsum);
  for (int s0 = 992; s0 < send; s0 += 32)
    attn_iter<true>(s0, send, quad, kg, vg, kw, vw, krp, vrp, pwp, prp,
                    bq, Dm, kA, vA, oacc, lsum, spsum);

  // epilogue-only uv load (kept out of the loop-live register set)
  float4 uv4[4];
  {
    const float* uvp = uv + (size_t)bh * 64;
#pragma unroll
    for (int jc = 0; jc < 4; ++jc)
      uv4[jc] = *(const float4*)(uvp + jc * 16 + quad * 4);
  }

#pragma unroll
  for (int b = 0; b < 2; ++b) {
    float l = lsum[b], sp = spsum[b];
    l += __shfl_xor(l, 16);
    l += __shfl_xor(l, 32);
    sp += __shfl_xor(sp, 16);
    sp += __shfl_xor(sp, 32);
    const float inv = 1.0f / l;         // l complete: self-normalize
    const float su = 2.0f * sp * inv;
    const int t = t0 + wband + b * 16 + q16;
    __bf16* opp = opart + ((size_t)bh * 2048 + t) * 64;
#pragma unroll
    for (int jc = 0; jc < 4; ++jc) {
      union { uint2 u; __bf16 h[4]; } pk;
      pk.h[0] = (__bf16)(oacc[b][jc][0] * inv + su * uv4[jc].x);
      pk.h[1] = (__bf16)(oacc[b][jc][1] * inv + su * uv4[jc].y);
      pk.h[2] = (__bf16)(oacc[b][jc][2] * inv + su * uv4[jc].z);
      pk.h[3] = (__bf16)(oacc[b][jc][3] * inv + su * uv4[jc].w);
      *(uint2*)(opp + jc * 16 + quad * 4) = pk.u;
    }
  }
}

// ---------------------------------------------------------------------------
// Kernel 6: proj GEMM (bf16 MFMA), double-buffered, plain GEMM; unchanged.
// ---------------------------------------------------------------------------
__global__ __launch_bounds__(256) void k_gemm_proj(const float* __restrict__ W,
                                                   const __bf16* __restrict__ opart,
                                                   const float* __restrict__ bias,
                                                   float* __restrict__ C) {
  const int n0 = blockIdx.x * 128;
  const int bo = blockIdx.y * 64;
  const int b = blockIdx.z;
  float* Cb = C + (size_t)b * 524288;

  __shared__ __align__(16) char smem[30720];

  const int tid = threadIdx.x, lane = tid & 63, wv = tid >> 6;
  const int quad = lane >> 4, q16 = lane & 15, wn = wv * 32;

  const int rowA = tid >> 2, chA = (tid & 3) * 8;
  const int browB0 = tid >> 2, bchB = (tid & 3) * 8;
  const float* wA = W + (size_t)(bo + rowA) * 256 + chA;

  float4 aP0 = *(const float4*)(wA);
  float4 aP1 = *(const float4*)(wA + 4);
  uint4 oPd[2];
#pragma unroll
  for (int g = 0; g < 2; ++g) {
    const int t = n0 + browB0 + g * 64;
    // k0 = 0: channel = bchB (<64) -> head 0, cu = bchB
    const size_t rr = (size_t)(b * 4) * 2048 + t;
    oPd[g] = *(const uint4*)(opart + rr * 64 + bchB);
  }

  f32x4 acc[4][2] = {};
  int bsel = 0;
  for (int k0 = 0; k0 < 256; k0 += 32) {
    char* const Ab = smem + bsel;
    char* const Bb = smem + bsel + 5120;
    {
      union { uint4 u; __bf16 h[8]; } pa;
      pa.h[0] = (__bf16)aP0.x; pa.h[1] = (__bf16)aP0.y;
      pa.h[2] = (__bf16)aP0.z; pa.h[3] = (__bf16)aP0.w;
      pa.h[4] = (__bf16)aP1.x; pa.h[5] = (__bf16)aP1.y;
      pa.h[6] = (__bf16)aP1.z; pa.h[7] = (__bf16)aP1.w;
      *(uint4*)(Ab + rowA * 80 + chA * 2) = pa.u;
      *(uint4*)(Bb + browB0 * 80 + bchB * 2) = oPd[0];
      *(uint4*)(Bb + (browB0 + 64) * 80 + bchB * 2) = oPd[1];
    }
    __syncthreads();
    if (k0 + 32 < 256) {
      const int kn = k0 + 32;
      aP0 = *(const float4*)(wA + kn);
      aP1 = *(const float4*)(wA + kn + 4);
      const int c = kn + bchB;
      const int hd = c >> 6, cu = c & 63;
#pragma unroll
      for (int g = 0; g < 2; ++g) {
        const int t = n0 + browB0 + g * 64;
        const size_t rr = (size_t)(b * 4 + hd) * 2048 + t;
        oPd[g] = *(const uint4*)(opart + rr * 64 + cu);
      }
    }
    bf16x8 af[4], bfr[2];
#pragma unroll
    for (int mt = 0; mt < 4; ++mt)
      af[mt] = *(const bf16x8*)(Ab + (mt * 16 + q16) * 80 + quad * 16);
#pragma unroll
    for (int jn = 0; jn < 2; ++jn)
      bfr[jn] = *(const bf16x8*)(Bb + (wn + jn * 16 + q16) * 80 + quad * 16);
#pragma unroll
    for (int mt = 0; mt < 4; ++mt)
#pragma unroll
      for (int jn = 0; jn < 2; ++jn)
        acc[mt][jn] = __builtin_amdgcn_mfma_f32_16x16x32_bf16(af[mt], bfr[jn], acc[mt][jn], 0, 0, 0);
    bsel ^= 15360;
  }

#pragma unroll
  for (int mt = 0; mt < 4; ++mt)
#pragma unroll
    for (int r = 0; r < 4; ++r) {
      const int o = bo + mt * 16 + quad * 4 + r;
      const float bv = bias[o];
#pragma unroll
      for (int jn = 0; jn < 2; ++jn)
        Cb[(size_t)o * 2048 + n0 + wn + jn * 16 + q16] = acc[mt][jn][r] + bv;
    }
}

// ---------------------------------------------------------------------------
// Kernel 7: inverse FFT2 via split-bf16 MFMA. One slice per wave (r14 form).
// r22: twiddle tables computed inline (k_twid deleted).
// ---------------------------------------------------------------------------
__global__ __launch_bounds__(256) void k_ifft2(const float* __restrict__ spec,
                                               float* __restrict__ out) {
  __shared__ __align__(16) char smem[51200];
  const int tid = threadIdx.x, lane = tid & 63, wv = tid >> 6;
  const int quad = lane >> 4, q16 = lane & 15;
  const int slice = blockIdx.x * 4 + wv;
  char* const wr_ = smem + 10240 + wv * 10240;

  // early spec global loads
  const float* sp = spec + (size_t)slice * 2048;
  float4 sv8[8];
#pragma unroll
  for (int u = 0; u < 8; ++u) sv8[u] = ((const float4*)sp)[u * 64 + lane];

  build_twiddle_lds(smem, tid);

#pragma unroll
  for (int u = 0; u < 8; ++u) {
    const int f = u * 64 + lane;  // 0..511 float4 (2 complex each)
    const float4 v = sv8[u];
    const int k1 = f >> 4, k2 = (f & 15) * 2;
    char* base = wr_ + k1 * 80 + k2 * 2;
    union { unsigned int w; __bf16 b[2]; } p;
    const __bf16 rh0 = (__bf16)v.x, rh1 = (__bf16)v.z;
    const __bf16 ih0 = (__bf16)v.y, ih1 = (__bf16)v.w;
    p.b[0] = rh0; p.b[1] = rh1; *(unsigned int*)(base) = p.w;
    p.b[0] = (__bf16)(v.x - (float)rh0);
    p.b[1] = (__bf16)(v.z - (float)rh1); *(unsigned int*)(base + 2560) = p.w;
    p.b[0] = ih0; p.b[1] = ih1; *(unsigned int*)(base + 5120) = p.w;
    p.b[0] = (__bf16)(v.y - (float)ih0);
    p.b[1] = (__bf16)(v.w - (float)ih1); *(unsigned int*)(base + 7680) = p.w;
  }
  __syncthreads();  // tables visible; X same-wave ordered

  bf16x8 cch[2], ccl[2], ssh[2], ssl[2], ssnh[2], ssnl[2];
  bf16x8 xreh[2], xrel[2], ximh[2], ximl[2];
#pragma unroll
  for (int t2 = 0; t2 < 2; ++t2) {
    const int row = t2 * 16 + q16;
    cch[t2] = *(const bf16x8*)(smem + row * 80 + quad * 16);
    ccl[t2] = *(const bf16x8*)(smem + 2560 + row * 80 + quad * 16);
    ssh[t2] = *(const bf16x8*)(smem + 5120 + row * 80 + quad * 16);
    ssl[t2] = *(const bf16x8*)(smem + 7680 + row * 80 + quad * 16);
    xreh[t2] = *(const bf16x8*)(wr_ + row * 80 + quad * 16);
    xrel[t2] = *(const bf16x8*)(wr_ + 2560 + row * 80 + quad * 16);
    ximh[t2] = *(const bf16x8*)(wr_ + 5120 + row * 80 + quad * 16);
    ximl[t2] = *(const bf16x8*)(wr_ + 7680 + row * 80 + quad * 16);
  }
  ssnh[0] = neg8(ssh[0]); ssnh[1] = neg8(ssh[1]);
  ssnl[0] = neg8(ssl[0]); ssnl[1] = neg8(ssl[1]);

  // pass 1
  f32x4 yre[2][2] = {}, yim[2][2] = {};
#pragma unroll
  for (int mt = 0; mt < 2; ++mt)
#pragma unroll
    for (int nt = 0; nt < 2; ++nt) {
      MFMA3(yre[mt][nt], xreh[mt], xrel[mt], cch[nt], ccl[nt]);
      MFMA3(yre[mt][nt], ximh[mt], ximl[mt], ssnh[nt], ssnl[nt]);
      MFMA3(yim[mt][nt], xreh[mt], xrel[mt], ssh[nt], ssl[nt]);
      MFMA3(yim[mt][nt], ximh[mt], ximl[mt], cch[nt], ccl[nt]);
    }

  // write Yt transposed + split over the X regions (wave-private)
#pragma unroll
  for (int mt = 0; mt < 2; ++mt)
#pragma unroll
    for (int nt = 0; nt < 2; ++nt) {
      char* base = wr_ + (nt * 16 + q16) * 80 + (mt * 16 + quad * 4) * 2;
      union { unsigned long long q; __bf16 b[4]; } h, l;
#pragma unroll
      for (int r = 0; r < 4; ++r) {
        const float v = yre[mt][nt][r];
        h.b[r] = (__bf16)v; l.b[r] = (__bf16)(v - (float)h.b[r]);
      }
      *(unsigned long long*)(base) = h.q;
      *(unsigned long long*)(base + 2560) = l.q;
#pragma unroll
      for (int r = 0; r < 4; ++r) {
        const float v = yim[mt][nt][r];
        h.b[r] = (__bf16)v; l.b[r] = (__bf16)(v - (float)h.b[r]);
      }
      *(unsigned long long*)(base + 5120) = h.q;
      *(unsigned long long*)(base + 7680) = l.q;
    }
  asm volatile("" ::: "memory");

  bf16x8 yreh[2], yrel[2], yimh[2], yiml[2];
#pragma unroll
  for (int nt = 0; nt < 2; ++nt) {
    const int row = nt * 16 + q16;
    yreh[nt] = *(const bf16x8*)(wr_ + row * 80 + quad * 16);
    yrel[nt] = *(const bf16x8*)(wr_ + 2560 + row * 80 + quad * 16);
    yimh[nt] = *(const bf16x8*)(wr_ + 5120 + row * 80 + quad * 16);
    yiml[nt] = *(const bf16x8*)(wr_ + 7680 + row * 80 + quad * 16);
  }

  // pass 2
  f32x4 zre[2][2] = {}, zim[2][2] = {};
#pragma unroll
  for (int mt = 0; mt < 2; ++mt)
#pragma unroll
    for (int nt = 0; nt < 2; ++nt) {
      MFMA3(zre[mt][nt], cch[mt], ccl[mt], yreh[nt], yrel[nt]);
      MFMA3(zre[mt][nt], ssnh[mt], ssnl[mt], yimh[nt], yiml[nt]);
      MFMA3(zim[mt][nt], cch[mt], ccl[mt], yimh[nt], yiml[nt]);
      MFMA3(zim[mt][nt], ssh[mt], ssl[mt], yreh[nt], yrel[nt]);
    }

  float* op = out + (size_t)slice * 2048;
#pragma unroll
  for (int mt = 0; mt < 2; ++mt)
#pragma unroll
    for (int nt = 0; nt < 2; ++nt)
#pragma unroll
      for (int r = 0; r < 4; ++r) {
        const int n1 = mt * 16 + quad * 4 + r;
        const int n2 = nt * 16 + q16;
        float2 st;
        st.x = zre[mt][nt][r] * (1.0f / 1024.0f);
        st.y = zim[mt][nt][r] * (1.0f / 1024.0f);
        *(float2*)(op + 2 * (n1 * 32 + n2)) = st;
      }
}

// ---------------------------------------------------------------------------
extern "C" void kernel_launch(void* const* d_in, const int* in_sizes, int n_in,
                              void* d_out, int out_size, void* d_ws, size_t ws_size,
                              hipStream_t stream) {
  (void)in_sizes; (void)n_in; (void)out_size; (void)ws_size;
  const float* x      = (const float*)d_in[0];
  const float* gn_w   = (const float*)d_in[1];
  const float* gn_b   = (const float*)d_in[2];
  const float* qkv_w  = (const float*)d_in[3];
  const float* qkv_b  = (const float*)d_in[4];
  const float* proj_w = (const float*)d_in[5];
  const float* proj_b = (const float*)d_in[6];
  float* out = (float*)d_out;

  float* spec  = (float*)d_ws;
  __bf16* Qt   = (__bf16*)(spec + 4194304);   // 4194304 elems
  __bf16* Kt   = Qt + 4194304;                // 2359296 elems (32*1152*64)
  __bf16* Vt   = Kt + 2359296;                // 2359296 elems
  float* xr    = (float*)(Vt + 2359296) + 512; // 512-float hole (old stats slot)
  __bf16* xt   = (__bf16*)(xr + 4194304);     // 4194304 bf16
  __bf16* opart = (__bf16*)xr;                // 4194304 bf16 (clobbers xr; single-part)
  float*  dq    = (float*)(opart + 12582912); // 65536 (offset kept from 3-part era)
  float*  uk    = dq + 65536;                 // 2048
  float*  uv    = uk + 2048;                  // 2048
  float*  stats_part = uv + 2048;             // 4096 floats (256 bg x 8 sub x 2)

  k_fft2<<<512, 256, 0, stream>>>(x, xr, stats_part);
  k_uvec<<<64, 256, 0, stream>>>(stats_part, gn_w, gn_b, qkv_w, qkv_b, uk, uv);
  k_gntrans<<<dim3(32, 4, 8), 256, 0, stream>>>(xr, stats_part, gn_w, gn_b, xt);
  k_gemm_qkv<<<dim3(136, 8), 256, 0, stream>>>(qkv_w, xt, qkv_b, uk, dq,
                                               Qt, Kt, Vt);
  k_attn_mfma<<<dim3(16, 32), 256, 0, stream>>>(Qt, Kt, Vt, dq, uv, opart);
  k_gemm_proj<<<dim3(16, 4, 8), 256, 0, stream>>>(proj_w, opart, proj_b, spec);
  k_ifft2<<<512, 256, 0, stream>>>(spec, out);
}

// Round 8
// 155.844 us; speedup vs baseline: 1.2262x; 1.0163x over previous
//
#include <hip/hip_runtime.h>
#include <hip/hip_bf16.h>
#include <stdint.h>

#define PI_F 3.14159265358979323846f
#define C1_EXP 0.18033688f   // log2(e)/8
#define C2_EXP 23.083120f    // 16*log2(e)

typedef __bf16 bf16x8 __attribute__((ext_vector_type(8)));
typedef float f32x4 __attribute__((ext_vector_type(4)));
typedef unsigned int uint32x4 __attribute__((ext_vector_type(4)));

// LDS-only barrier: s_barrier with lgkmcnt drain but NO vmcnt drain, so
// in-flight global prefetch loads survive across the barrier (T4-minimal).
// Proven +3us on attn in r20.
#define BAR_LDS() asm volatile("s_waitcnt lgkmcnt(0)\n\ts_barrier" ::: "memory")

__device__ __forceinline__ bf16x8 neg8(bf16x8 v) {
  union { bf16x8 b; uint32x4 u; } x;
  x.b = v;
  x.u ^= (uint32x4){0x80008000u, 0x80008000u, 0x80008000u, 0x80008000u};
  return x.b;
}

// 3-term split-accumulate: P*Q with P=Ph+Pl, Q=Qh+Ql (drop Pl*Ql ~2^-18)
#define MFMA3(acc, Ph, Pl, Qh, Ql)                                        \
  acc = __builtin_amdgcn_mfma_f32_16x16x32_bf16(Ph, Qh, acc, 0, 0, 0);    \
  acc = __builtin_amdgcn_mfma_f32_16x16x32_bf16(Ph, Ql, acc, 0, 0, 0);    \
  acc = __builtin_amdgcn_mfma_f32_16x16x32_bf16(Pl, Qh, acc, 0, 0, 0);

// Closed-form base-slot -> original column mapping.
__device__ __forceinline__ int slot2n(int slot) {
  const int pi = slot >> 1, im = slot & 1;
  int k1, k2;
  if (pi < 480)      { k1 = 1 + (pi >> 5); k2 = pi & 31; }
  else if (pi < 495) { k1 = 0;  k2 = pi - 479; }
  else if (pi < 510) { k1 = 16; k2 = pi - 494; }
  else if (pi < 514) { k1 = ((pi - 510) >> 1) * 16; k2 = ((pi - 510) & 1) * 16; }
  else               { k1 = 0; k2 = 0; }
  return 2 * (k1 * 32 + k2) + im;
}

// Inline twiddle-table build (r22: replaces k_twid kernel + global staging).
__device__ __forceinline__ void build_twiddle_lds(char* smem, int tid) {
  for (int e = tid; e < 1024; e += 256) {
    const int j = e >> 5, k = e & 31;
    const int t = (j * k) & 31;
    float sv, cv;
    sincosf(2.0f * PI_F * (float)t / 32.0f, &sv, &cv);
    const __bf16 ch = (__bf16)cv, sh = (__bf16)sv;
    *(__bf16*)(smem + j * 80 + k * 2) = ch;
    *(__bf16*)(smem + 2560 + j * 80 + k * 2) = (__bf16)(cv - (float)ch);
    *(__bf16*)(smem + 5120 + j * 80 + k * 2) = sh;
    *(__bf16*)(smem + 7680 + j * 80 + k * 2) = (__bf16)(sv - (float)sh);
  }
}

// ---------------------------------------------------------------------------
// Kernel 1: forward FFT2 via split-bf16 MFMA. One slice per wave; r22 form.
// ---------------------------------------------------------------------------
__global__ __launch_bounds__(256) void k_fft2(const float* __restrict__ x,
                                              float* __restrict__ xr,
                                              float* __restrict__ stats_part) {
  __shared__ __align__(16) char smem[51200];
  const int tid = threadIdx.x, lane = tid & 63, wv = tid >> 6;
  const int quad = lane >> 4, q16 = lane & 15;
  const int slice = blockIdx.x * 4 + wv;
  char* const wr_ = smem + 10240 + wv * 10240;

  // early X global loads (wave-private region; overlap with table build)
  const float* xs = x + (size_t)slice * 1024;
  float4 xv[4];
#pragma unroll
  for (int u = 0; u < 4; ++u) xv[u] = ((const float4*)xs)[u * 64 + lane];

  build_twiddle_lds(smem, tid);

  // X split + stage (same-wave ds ordering)
#pragma unroll
  for (int u = 0; u < 4; ++u) {
    const int f = u * 64 + lane;
    const float4 v = xv[u];
    const int row = f >> 3, c4 = (f & 7) * 4;
    union { unsigned long long q; __bf16 b[4]; } ph, pl;
    ph.b[0] = (__bf16)v.x; ph.b[1] = (__bf16)v.y;
    ph.b[2] = (__bf16)v.z; ph.b[3] = (__bf16)v.w;
    pl.b[0] = (__bf16)(v.x - (float)ph.b[0]);
    pl.b[1] = (__bf16)(v.y - (float)ph.b[1]);
    pl.b[2] = (__bf16)(v.z - (float)ph.b[2]);
    pl.b[3] = (__bf16)(v.w - (float)ph.b[3]);
    *(unsigned long long*)(wr_ + row * 80 + c4 * 2) = ph.q;
    *(unsigned long long*)(wr_ + 2560 + row * 80 + c4 * 2) = pl.q;
  }
  __syncthreads();  // tables visible to all waves; X same-wave ordered

  bf16x8 cch[2], ccl[2], ssh[2], ssl[2], xh[2], xl[2];
#pragma unroll
  for (int t2 = 0; t2 < 2; ++t2) {
    const int row = t2 * 16 + q16;
    cch[t2] = *(const bf16x8*)(smem + row * 80 + quad * 16);
    ccl[t2] = *(const bf16x8*)(smem + 2560 + row * 80 + quad * 16);
    ssh[t2] = *(const bf16x8*)(smem + 5120 + row * 80 + quad * 16);
    ssl[t2] = *(const bf16x8*)(smem + 7680 + row * 80 + quad * 16);
    xh[t2] = *(const bf16x8*)(wr_ + row * 80 + quad * 16);
    xl[t2] = *(const bf16x8*)(wr_ + 2560 + row * 80 + quad * 16);
  }

  // pass 1: Yre = X@Cc, Yim = -(X@Ss)
  f32x4 yre[2][2] = {}, yim[2][2] = {};
#pragma unroll
  for (int mt = 0; mt < 2; ++mt)
#pragma unroll
    for (int nt = 0; nt < 2; ++nt) {
      MFMA3(yre[mt][nt], xh[mt], xl[mt], cch[nt], ccl[nt]);
      MFMA3(yim[mt][nt], xh[mt], xl[mt], ssh[nt], ssl[nt]);
    }

  // write Yt transposed + split (wave-private; same-wave ordering)
#pragma unroll
  for (int mt = 0; mt < 2; ++mt)
#pragma unroll
    for (int nt = 0; nt < 2; ++nt) {
      char* base = wr_ + (nt * 16 + q16) * 80 + (mt * 16 + quad * 4) * 2;
      union { unsigned long long q; __bf16 b[4]; } h, l;
#pragma unroll
      for (int r = 0; r < 4; ++r) {
        const float v = yre[mt][nt][r];
        h.b[r] = (__bf16)v; l.b[r] = (__bf16)(v - (float)h.b[r]);
      }
      *(unsigned long long*)(base) = h.q;
      *(unsigned long long*)(base + 2560) = l.q;
#pragma unroll
      for (int r = 0; r < 4; ++r) {
        const float v = -yim[mt][nt][r];
        h.b[r] = (__bf16)v; l.b[r] = (__bf16)(v - (float)h.b[r]);
      }
      *(unsigned long long*)(base + 5120) = h.q;
      *(unsigned long long*)(base + 7680) = l.q;
    }
  asm volatile("" ::: "memory");

  bf16x8 yreh[2], yrel[2], yimh[2], yiml[2];
#pragma unroll
  for (int nt = 0; nt < 2; ++nt) {
    const int row = nt * 16 + q16;
    yreh[nt] = *(const bf16x8*)(wr_ + row * 80 + quad * 16);
    yrel[nt] = *(const bf16x8*)(wr_ + 2560 + row * 80 + quad * 16);
    yimh[nt] = *(const bf16x8*)(wr_ + 5120 + row * 80 + quad * 16);
    yiml[nt] = *(const bf16x8*)(wr_ + 7680 + row * 80 + quad * 16);
  }

  // pass 2: Zre = Cc@Yre + Ss@Yim ; Zim = Cc@Yim - Ss@Yre
  f32x4 zre[2][2] = {}, zim[2][2] = {};
  bf16x8 ssnh[2], ssnl[2];
  ssnh[0] = neg8(ssh[0]); ssnh[1] = neg8(ssh[1]);
  ssnl[0] = neg8(ssl[0]); ssnl[1] = neg8(ssl[1]);
#pragma unroll
  for (int mt = 0; mt < 2; ++mt)
#pragma unroll
    for (int nt = 0; nt < 2; ++nt) {
      MFMA3(zre[mt][nt], cch[mt], ccl[mt], yreh[nt], yrel[nt]);
      MFMA3(zre[mt][nt], ssh[mt], ssl[mt], yimh[nt], yiml[nt]);
      MFMA3(zim[mt][nt], cch[mt], ccl[mt], yimh[nt], yiml[nt]);
      MFMA3(zim[mt][nt], ssnh[mt], ssnl[mt], yreh[nt], yrel[nt]);
    }

  // stats + store
  float* op = xr + (size_t)slice * 2048;
  float s1 = 0.f, s2 = 0.f;
#pragma unroll
  for (int mt = 0; mt < 2; ++mt)
#pragma unroll
    for (int nt = 0; nt < 2; ++nt)
#pragma unroll
      for (int r = 0; r < 4; ++r) {
        const int k1 = mt * 16 + quad * 4 + r;
        const int k2 = nt * 16 + q16;
        const float a = zre[mt][nt][r], bimg = zim[mt][nt][r];
        s1 += a + bimg;
        s2 += a * a + bimg * bimg;
        float2 st; st.x = a; st.y = bimg;
        *(float2*)(op + 2 * (k1 * 32 + k2)) = st;
      }
#pragma unroll
  for (int off = 1; off <= 32; off <<= 1) {
    s1 += __shfl_xor(s1, off);
    s2 += __shfl_xor(s2, off);
  }
  if (lane == 0) {
    const int bg = (slice >> 8) * 32 + ((slice & 255) >> 3);
    const int sub = slice & 7;
    float2 st; st.x = s1; st.y = s2;
    *(float2*)(stats_part + (size_t)(bg * 8 + sub) * 2) = st;
  }
}

// ---------------------------------------------------------------------------
// Kernel 2: mirror-correction vectors; sums 8 stats partials.
// ---------------------------------------------------------------------------
__global__ __launch_bounds__(256) void k_uvec(const float* __restrict__ stats_part,
                                              const float* __restrict__ gn_w,
                                              const float* __restrict__ gn_b,
                                              const float* __restrict__ qkv_w,
                                              const float* __restrict__ qkv_b,
                                              float* __restrict__ uk,
                                              float* __restrict__ uv) {
  const int blk = blockIdx.x;
  const int tid = threadIdx.x;
  const int b = blk >> 3, h = (blk >> 1) & 3, role = blk & 1;
  __shared__ float Bsh[256];
  {
    const int g = tid >> 3;
    float S = 0.f, S2 = 0.f;
#pragma unroll
    for (int s = 0; s < 8; ++s) {
      S  += stats_part[((b * 32 + g) * 8 + s) * 2];
      S2 += stats_part[((b * 32 + g) * 8 + s) * 2 + 1];
    }
    const float mean = S * (1.0f / 16384.0f);
    const float var = S2 * (1.0f / 16384.0f) - mean * mean;
    const float rstd = rsqrtf(var + 1e-5f);
    Bsh[tid] = gn_b[tid] - mean * rstd * gn_w[tid];
  }
  __syncthreads();
  const int cp = tid >> 2, seg = tid & 3;
  const int row = h * 192 + 64 + role * 64 + cp;
  const float* wr_ = qkv_w + (size_t)row * 256 + seg * 64;
  const float* bs = Bsh + seg * 64;
  float s = 0.f;
#pragma unroll
  for (int i = 0; i < 16; ++i) {
    const float4 w4 = *(const float4*)(wr_ + i * 4);
    const float4 b4 = *(const float4*)(bs + i * 4);
    s += w4.x * b4.x + w4.y * b4.y + w4.z * b4.z + w4.w * b4.w;
  }
  s += __shfl_xor(s, 1);
  s += __shfl_xor(s, 2);
  if (seg == 0) {
    float* dst = (role == 0) ? uk : uv;
    dst[(size_t)(b * 4 + h) * 64 + cp] = s + qkv_b[row];
  }
}

// ---------------------------------------------------------------------------
// Kernel 3: GroupNorm apply + transpose to bf16 X^T [b][n][c]; r22 form.
// ---------------------------------------------------------------------------
__global__ __launch_bounds__(256) void k_gntrans(const float* __restrict__ xr,
                                                 const float* __restrict__ stats_part,
                                                 const float* __restrict__ w,
                                                 const float* __restrict__ bias,
                                                 __bf16* __restrict__ xt) {
  const int n0 = blockIdx.x * 64;
  const int c0 = blockIdx.y * 64;
  const int b = blockIdx.z;
  __shared__ __bf16 Lt[64][72];
  __shared__ float gsum[8][2];
  const int tid = threadIdx.x;
  if (tid < 8) {
    const int g = (c0 >> 3) + tid;
    float S = 0.f, S2 = 0.f;
#pragma unroll
    for (int s = 0; s < 8; ++s) {
      S  += stats_part[((b * 32 + g) * 8 + s) * 2];
      S2 += stats_part[((b * 32 + g) * 8 + s) * 2 + 1];
    }
    gsum[tid][0] = S;
    gsum[tid][1] = S2;
  }
  __syncthreads();
  for (int i = tid; i < 1024; i += 256) {
    const int cl = i >> 4, c = c0 + cl, nl = (i & 15) * 4;
    const float S = gsum[cl >> 3][0];
    const float S2 = gsum[cl >> 3][1];
    const float mean = S * (1.0f / 16384.0f);
    const float var = S2 * (1.0f / 16384.0f) - mean * mean;
    const float rstd = rsqrtf(var + 1e-5f);
    const float sc = rstd * w[c];
    const float sh = bias[c] - mean * sc;
    const float4 v = *(const float4*)(xr + ((size_t)b * 256 + c) * 2048 + n0 + nl);
    Lt[nl][cl] = (__bf16)(v.x * sc + sh);
    Lt[nl + 1][cl] = (__bf16)(v.y * sc + sh);
    Lt[nl + 2][cl] = (__bf16)(v.z * sc + sh);
    Lt[nl + 3][cl] = (__bf16)(v.w * sc + sh);
  }
  __syncthreads();
  __bf16* dst = xt + (size_t)b * 524288 + (size_t)n0 * 256 + c0;
  for (int i = tid; i < 512; i += 256) {
    const int nl = i >> 3, cch = (i & 7) * 8;
    *(uint4*)(dst + (size_t)nl * 256 + cch) = *(const uint4*)&Lt[nl][cch];
  }
}

// ---------------------------------------------------------------------------
// Kernel 4: QKV GEMM (bf16 MFMA), double-buffered LDS; unchanged.
// ---------------------------------------------------------------------------
__global__ __launch_bounds__(256) void k_gemm_qkv(const float* __restrict__ W,
                                                  const __bf16* __restrict__ X,
                                                  const float* __restrict__ bias,
                                                  const float* __restrict__ uk,
                                                  float* __restrict__ dq,
                                                  __bf16* __restrict__ Qt,
                                                  __bf16* __restrict__ Kt,
                                                  __bf16* __restrict__ Vt) {
  const int tx = blockIdx.x;
  const int b = blockIdx.y;
  int role, hd, nt;
  if (tx < 64) { role = 0; hd = tx >> 4; nt = tx & 15; }
  else if (tx < 100) { role = 1; const int i = tx - 64; hd = i / 9; nt = i - hd * 9; }
  else { role = 2; const int i = tx - 100; hd = i / 9; nt = i - hd * 9; }
  const int n0 = nt * 128;
  const int bo = hd * 192 + role * 64;
  const __bf16* Xb = X + (size_t)b * 524288;

  __shared__ __align__(16) char smem[30720];
  __bf16 (*Ot)[72] = (__bf16(*)[72])smem;
  __bf16 (*Ot2)[136] = (__bf16(*)[136])smem;

  const int tid = threadIdx.x, lane = tid & 63, wv = tid >> 6;
  const int quad = lane >> 4, q16 = lane & 15, wn = wv * 32;

  const int rowA = tid >> 2, chA = (tid & 3) * 8;
  const int browB0 = tid >> 2, bchB = (tid & 3) * 8;
  const float* wA = W + (size_t)(bo + rowA) * 256 + chA;

  const int s0r = n0 + browB0, s1r = n0 + browB0 + 64;
  const int pn0 = (role == 0) ? s0r : slot2n(s0r);
  const int pn1 = (role == 0) ? s1r : slot2n(s1r);

  float4 aP0 = *(const float4*)(wA);
  float4 aP1 = *(const float4*)(wA + 4);
  uint4 bP0 = *(const uint4*)(Xb + (size_t)pn0 * 256 + bchB);
  uint4 bP1 = *(const uint4*)(Xb + (size_t)pn1 * 256 + bchB);

  f32x4 acc[4][2] = {};
  int bsel = 0;
  for (int k0 = 0; k0 < 256; k0 += 32) {
    char* const Ab = smem + bsel;
    char* const Bb = smem + bsel + 5120;
    {
      union { uint4 u; __bf16 h[8]; } pa;
      pa.h[0] = (__bf16)aP0.x; pa.h[1] = (__bf16)aP0.y;
      pa.h[2] = (__bf16)aP0.z; pa.h[3] = (__bf16)aP0.w;
      pa.h[4] = (__bf16)aP1.x; pa.h[5] = (__bf16)aP1.y;
      pa.h[6] = (__bf16)aP1.z; pa.h[7] = (__bf16)aP1.w;
      *(uint4*)(Ab + rowA * 80 + chA * 2) = pa.u;
      *(uint4*)(Bb + browB0 * 80 + bchB * 2) = bP0;
      *(uint4*)(Bb + (browB0 + 64) * 80 + bchB * 2) = bP1;
    }
    __syncthreads();
    if (k0 + 32 < 256) {
      const int kn = k0 + 32;
      aP0 = *(const float4*)(wA + kn);
      aP1 = *(const float4*)(wA + kn + 4);
      bP0 = *(const uint4*)(Xb + (size_t)pn0 * 256 + kn + bchB);
      bP1 = *(const uint4*)(Xb + (size_t)pn1 * 256 + kn + bchB);
    }
    bf16x8 af[4], bfr[2];
#pragma unroll
    for (int mt = 0; mt < 4; ++mt)
      af[mt] = *(const bf16x8*)(Ab + (mt * 16 + q16) * 80 + quad * 16);
#pragma unroll
    for (int jn = 0; jn < 2; ++jn)
      bfr[jn] = *(const bf16x8*)(Bb + (wn + jn * 16 + q16) * 80 + quad * 16);
#pragma unroll
    for (int mt = 0; mt < 4; ++mt)
#pragma unroll
      for (int jn = 0; jn < 2; ++jn)
        acc[mt][jn] = __builtin_amdgcn_mfma_f32_16x16x32_bf16(af[mt], bfr[jn], acc[mt][jn], 0, 0, 0);
    bsel ^= 15360;
  }
  __syncthreads();

  const int bh = b * 4 + hd;
  if (role == 2) {
#pragma unroll
    for (int mt = 0; mt < 4; ++mt)
#pragma unroll
      for (int r = 0; r < 4; ++r) {
        const int c = mt * 16 + quad * 4 + r;
        const float bv = bias[bo + c];
#pragma unroll
        for (int jn = 0; jn < 2; ++jn)
          Ot2[c][wn + jn * 16 + q16] = (__bf16)(acc[mt][jn][r] + bv);
      }
    __syncthreads();
    __bf16* dst = Vt + (size_t)bh * 73728;  // [c][1152]
    for (int i = tid; i < 1024; i += 256) {
      const int c = i >> 4, sg = (i & 15) * 8;
      *(uint4*)(dst + (size_t)c * 1152 + n0 + sg) = *(const uint4*)&Ot2[c][sg];
    }
  } else {
    __bf16* dst = (role == 0 ? Qt + (size_t)bh * 131072
                             : Kt + (size_t)bh * 73728);  // [n][64]
#pragma unroll
    for (int mt = 0; mt < 4; ++mt)
#pragma unroll
      for (int r = 0; r < 4; ++r) {
        const int c = mt * 16 + quad * 4 + r;
        const float bv = bias[bo + c];
#pragma unroll
        for (int jn = 0; jn < 2; ++jn)
          Ot[wn + jn * 16 + q16][c] = (__bf16)(acc[mt][jn][r] + bv);
      }
    __syncthreads();
    for (int i = tid; i < 1024; i += 256) {
      const int nl = i >> 3, cch = (i & 7) * 8;
      *(uint4*)(dst + (size_t)(n0 + nl) * 64 + cch) = *(const uint4*)&Ot[nl][cch];
    }
    if (role == 0 && tid < 128) {
      const float* ukp = uk + (size_t)bh * 64;
      float dv = 0.f;
#pragma unroll
      for (int g8 = 0; g8 < 8; ++g8) {
        const bf16x8 qv = *(const bf16x8*)&Ot[tid][g8 * 8];
#pragma unroll
        for (int k = 0; k < 8; ++k) dv += (float)qv[k] * ukp[g8 * 8 + k];
      }
      dq[(size_t)bh * 2048 + n0 + tid] = dv * (2.0f * C1_EXP);
    }
  }
}

// ---------------------------------------------------------------------------
// Kernel 5: MFMA flash attention. r23: KVBLK=64 — stage 64 K/V slots per
// barrier pair (two 4KB halves each, compile-time +0/+4096 offsets), run the
// proven 32-slot compute body twice between barriers. Barriers 66 -> 36.
// Single-buffered (no cross-iteration LDS state, const pointer arrays —
// avoids the r18/r19 regalloc failure mode). LDS: K 8K + V 8K + P 8K = 24KB.
// ---------------------------------------------------------------------------
template <bool EDGE, int OFF>
__device__ __forceinline__ void attn_half(
    const int s0, const int quad,
    const char* const (&krp)[2][2], const char* const (&vrp)[4],
    char* const (&pwp)[2][2], const char* const (&prp)[2],
    const bf16x8 (&bq)[2][2], const float (&Dm)[2],
    f32x4 (&oacc)[2][4], float (&lsum)[2], float (&spsum)[2]) {
  f32x4 sacc[2][2] = {};
#pragma unroll
  for (int j = 0; j < 2; ++j)
#pragma unroll
    for (int kk = 0; kk < 2; ++kk) {
      const bf16x8 ak = *(const bf16x8*)(krp[j][kk] + OFF);
      sacc[0][j] = __builtin_amdgcn_mfma_f32_16x16x32_bf16(ak, bq[0][kk], sacc[0][j], 0, 0, 0);
      sacc[1][j] = __builtin_amdgcn_mfma_f32_16x16x32_bf16(ak, bq[1][kk], sacc[1][j], 0, 0, 0);
    }

#pragma unroll
  for (int b = 0; b < 2; ++b) {
    float lacc = 0.f, spacc = 0.f;
#pragma unroll
    for (int j = 0; j < 2; ++j) {
      float B0, B2, Bv1, Bv3, Bm1, Bm3;
      if (EDGE) {
        const int sg = s0 + j * 16 + quad * 4;
        B0 = (sg < 1020) ? (1.0f - C2_EXP) : ((sg < 1028) ? -C2_EXP : -1e30f);
        B2 = (sg + 2 < 1020) ? (1.0f - C2_EXP)
                             : ((sg + 2 < 1028) ? -C2_EXP : -1e30f);
        Bv1 = (sg + 1 < 1028) ? -C2_EXP : -1e30f;
        Bv3 = (sg + 3 < 1028) ? -C2_EXP : -1e30f;
        Bm1 = (sg + 1 < 1020) ? Dm[b] : -1e30f;
        Bm3 = (sg + 3 < 1020) ? Dm[b] : -1e30f;
      } else {
        B0 = 1.0f - C2_EXP;
        B2 = 1.0f - C2_EXP;
        Bv1 = -C2_EXP;
        Bv3 = -C2_EXP;
        Bm1 = Dm[b];
        Bm3 = Dm[b];
      }
      const float P0  = __builtin_amdgcn_exp2f(fmaf(sacc[b][j][0],  C1_EXP, B0));
      const float Pv1 = __builtin_amdgcn_exp2f(fmaf(sacc[b][j][1],  C1_EXP, Bv1));
      const float P2  = __builtin_amdgcn_exp2f(fmaf(sacc[b][j][2],  C1_EXP, B2));
      const float Pv3 = __builtin_amdgcn_exp2f(fmaf(sacc[b][j][3],  C1_EXP, Bv3));
      const float pm1 = __builtin_amdgcn_exp2f(fmaf(sacc[b][j][1], -C1_EXP, Bm1));
      const float pm3 = __builtin_amdgcn_exp2f(fmaf(sacc[b][j][3], -C1_EXP, Bm3));
      const float mm = pm1 + pm3;
      lacc += (P0 + P2) + (Pv1 + Pv3) + mm;
      spacc += mm;
      union { uint2 u; __bf16 h[4]; } pk;
      pk.h[0] = (__bf16)P0;
      pk.h[1] = (__bf16)(Pv1 - pm1);
      pk.h[2] = (__bf16)P2;
      pk.h[3] = (__bf16)(Pv3 - pm3);
      *(uint2*)pwp[b][j] = pk.u;
    }
    lsum[b] += lacc;
    spsum[b] += spacc;
  }
  asm volatile("" ::: "memory");

  bf16x8 bp[2];
  bp[0] = *(const bf16x8*)prp[0];
  bp[1] = *(const bf16x8*)prp[1];
#pragma unroll
  for (int jc = 0; jc < 4; ++jc) {
    const bf16x8 av = *(const bf16x8*)(vrp[jc] + OFF);
    oacc[0][jc] = __builtin_amdgcn_mfma_f32_16x16x32_bf16(av, bp[0], oacc[0][jc], 0, 0, 0);
    oacc[1][jc] = __builtin_amdgcn_mfma_f32_16x16x32_bf16(av, bp[1], oacc[1][jc], 0, 0, 0);
  }
}

__global__ __launch_bounds__(256, 4) void k_attn_mfma(const __bf16* __restrict__ Qt,
                                                      const __bf16* __restrict__ Kt,
                                                      const __bf16* __restrict__ Vt,
                                                      const float* __restrict__ dq,
                                                      const float* __restrict__ uv,
                                                      __bf16* __restrict__ opart) {
  const int t0 = blockIdx.x * 128;
  const int bh = blockIdx.y;
  const __bf16* kt = Kt + (size_t)bh * 73728;
  const __bf16* vt = Vt + (size_t)bh * 73728;

  __shared__ __align__(16) char smem[24576];

  const int tid = threadIdx.x, lane = tid & 63, wv = tid >> 6;
  const int quad = lane >> 4, q16 = lane & 15;
  const int wband = wv * 32;

  const int rK = tid >> 3, gK = tid & 7;
  char* const kw = smem + rK * 128 + ((gK ^ (rK & 7)) * 16);
  const int cV = tid >> 2, gV = tid & 3;
  char* const vw = smem + 8192 + (cV >> 1) * 128 +
                   ((((cV & 1) * 4 + gV) ^ ((cV >> 1) & 7)) * 16);
  const __bf16* const kg = kt + (size_t)rK * 64 + gK * 8;
  const __bf16* const vg = vt + (size_t)cV * 1152 + gV * 8;

  const char* krp[2][2];
#pragma unroll
  for (int j = 0; j < 2; ++j)
#pragma unroll
    for (int kk = 0; kk < 2; ++kk)
      krp[j][kk] = smem + (j * 16 + q16) * 128 + (((kk * 4 + quad) ^ (q16 & 7)) * 16);
  const int a7 = (q16 >> 1) & 7, p1 = q16 & 1;
  const char* vrp[4];
#pragma unroll
  for (int jc = 0; jc < 4; ++jc)
    vrp[jc] = smem + 8192 + (jc * 8 + (q16 >> 1)) * 128 +
              (((p1 * 4 + quad) ^ a7) * 16);
  char* pwp[2][2];
  const char* prp[2];
#pragma unroll
  for (int b = 0; b < 2; ++b) {
    const int mrow = ((wband + b * 16) >> 1) + (q16 >> 1);
    prp[b] = smem + 16384 + mrow * 128 + (((p1 * 4 + quad) ^ a7) * 16);
#pragma unroll
    for (int j = 0; j < 2; ++j)
      pwp[b][j] = smem + 16384 + mrow * 128 +
                  (((p1 * 4 + j * 2 + (quad >> 1)) ^ a7) * 16) + (quad & 1) * 8;
  }

  const __bf16* qbase = Qt + (size_t)bh * 131072;
  bf16x8 bq[2][2];
  float Dm[2];
#pragma unroll
  for (int b = 0; b < 2; ++b) {
    const int t = t0 + wband + b * 16 + q16;
    const __bf16* qp = qbase + (size_t)t * 64 + quad * 8;
    bq[b][0] = *(const bf16x8*)qp;
    bq[b][1] = *(const bf16x8*)(qp + 32);
    Dm[b] = dq[(size_t)bh * 2048 + t] - C2_EXP;
  }

  f32x4 oacc[2][4] = {};
  float lsum[2] = {0.f, 0.f};
  float spsum[2] = {0.f, 0.f};

  // 1056 slots = 15 x dbl(64) [0..959] + dbl(64) with edge second half
  // [960..1023] + single(32) edge [1024..1055].
  uint4 kA0 = *(const uint4*)(kg);
  uint4 kA1 = *(const uint4*)(kg + (size_t)32 * 64);
  uint4 vA0 = *(const uint4*)(vg);
  uint4 vA1 = *(const uint4*)(vg + 32);

  int s0 = 0;
#pragma unroll 1
  for (int it = 0; it < 15; ++it) {
    *(uint4*)kw = kA0;
    *(uint4*)(kw + 4096) = kA1;
    *(uint4*)vw = vA0;
    *(uint4*)(vw + 4096) = vA1;
    BAR_LDS();
    kA0 = *(const uint4*)(kg + (size_t)(s0 + 64) * 64);
    kA1 = *(const uint4*)(kg + (size_t)(s0 + 96) * 64);
    vA0 = *(const uint4*)(vg + s0 + 64);
    vA1 = *(const uint4*)(vg + s0 + 96);
    attn_half<false, 0>(s0, quad, krp, vrp, pwp, prp, bq, Dm,
                        oacc, lsum, spsum);
    attn_half<false, 4096>(s0 + 32, quad, krp, vrp, pwp, prp, bq, Dm,
                           oacc, lsum, spsum);
    BAR_LDS();
    s0 += 64;
  }
  // s0 == 960; kA0/vA0 hold tiles 960, kA1/vA1 hold 992.
  *(uint4*)kw = kA0;
  *(uint4*)(kw + 4096) = kA1;
  *(uint4*)vw = vA0;
  *(uint4*)(vw + 4096) = vA1;
  BAR_LDS();
  kA0 = *(const uint4*)(kg + (size_t)1024 * 64);
  vA0 = *(const uint4*)(vg + 1024);
  attn_half<false, 0>(960, quad, krp, vrp, pwp, prp, bq, Dm,
                      oacc, lsum, spsum);
  attn_half<true, 4096>(992, quad, krp, vrp, pwp, prp, bq, Dm,
                        oacc, lsum, spsum);
  BAR_LDS();
  // final single 32-slot tile at base offsets
  *(uint4*)kw = kA0;
  *(uint4*)vw = vA0;
  BAR_LDS();
  attn_half<true, 0>(1024, quad, krp, vrp, pwp, prp, bq, Dm,
                     oacc, lsum, spsum);

  // epilogue-only uv load (kept out of the loop-live register set)
  float4 uv4[4];
  {
    const float* uvp = uv + (size_t)bh * 64;
#pragma unroll
    for (int jc = 0; jc < 4; ++jc)
      uv4[jc] = *(const float4*)(uvp + jc * 16 + quad * 4);
  }

#pragma unroll
  for (int b = 0; b < 2; ++b) {
    float l = lsum[b], sp = spsum[b];
    l += __shfl_xor(l, 16);
    l += __shfl_xor(l, 32);
    sp += __shfl_xor(sp, 16);
    sp += __shfl_xor(sp, 32);
    const float inv = 1.0f / l;         // l complete: self-normalize
    const float su = 2.0f * sp * inv;
    const int t = t0 + wband + b * 16 + q16;
    __bf16* opp = opart + ((size_t)bh * 2048 + t) * 64;
#pragma unroll
    for (int jc = 0; jc < 4; ++jc) {
      union { uint2 u; __bf16 h[4]; } pk;
      pk.h[0] = (__bf16)(oacc[b][jc][0] * inv + su * uv4[jc].x);
      pk.h[1] = (__bf16)(oacc[b][jc][1] * inv + su * uv4[jc].y);
      pk.h[2] = (__bf16)(oacc[b][jc][2] * inv + su * uv4[jc].z);
      pk.h[3] = (__bf16)(oacc[b][jc][3] * inv + su * uv4[jc].w);
      *(uint2*)(opp + jc * 16 + quad * 4) = pk.u;
    }
  }
}

// ---------------------------------------------------------------------------
// Kernel 6: proj GEMM (bf16 MFMA), double-buffered, plain GEMM; unchanged.
// ---------------------------------------------------------------------------
__global__ __launch_bounds__(256) void k_gemm_proj(const float* __restrict__ W,
                                                   const __bf16* __restrict__ opart,
                                                   const float* __restrict__ bias,
                                                   float* __restrict__ C) {
  const int n0 = blockIdx.x * 128;
  const int bo = blockIdx.y * 64;
  const int b = blockIdx.z;
  float* Cb = C + (size_t)b * 524288;

  __shared__ __align__(16) char smem[30720];

  const int tid = threadIdx.x, lane = tid & 63, wv = tid >> 6;
  const int quad = lane >> 4, q16 = lane & 15, wn = wv * 32;

  const int rowA = tid >> 2, chA = (tid & 3) * 8;
  const int browB0 = tid >> 2, bchB = (tid & 3) * 8;
  const float* wA = W + (size_t)(bo + rowA) * 256 + chA;

  float4 aP0 = *(const float4*)(wA);
  float4 aP1 = *(const float4*)(wA + 4);
  uint4 oPd[2];
#pragma unroll
  for (int g = 0; g < 2; ++g) {
    const int t = n0 + browB0 + g * 64;
    const size_t rr = (size_t)(b * 4) * 2048 + t;
    oPd[g] = *(const uint4*)(opart + rr * 64 + bchB);
  }

  f32x4 acc[4][2] = {};
  int bsel = 0;
  for (int k0 = 0; k0 < 256; k0 += 32) {
    char* const Ab = smem + bsel;
    char* const Bb = smem + bsel + 5120;
    {
      union { uint4 u; __bf16 h[8]; } pa;
      pa.h[0] = (__bf16)aP0.x; pa.h[1] = (__bf16)aP0.y;
      pa.h[2] = (__bf16)aP0.z; pa.h[3] = (__bf16)aP0.w;
      pa.h[4] = (__bf16)aP1.x; pa.h[5] = (__bf16)aP1.y;
      pa.h[6] = (__bf16)aP1.z; pa.h[7] = (__bf16)aP1.w;
      *(uint4*)(Ab + rowA * 80 + chA * 2) = pa.u;
      *(uint4*)(Bb + browB0 * 80 + bchB * 2) = oPd[0];
      *(uint4*)(Bb + (browB0 + 64) * 80 + bchB * 2) = oPd[1];
    }
    __syncthreads();
    if (k0 + 32 < 256) {
      const int kn = k0 + 32;
      aP0 = *(const float4*)(wA + kn);
      aP1 = *(const float4*)(wA + kn + 4);
      const int c = kn + bchB;
      const int hd = c >> 6, cu = c & 63;
#pragma unroll
      for (int g = 0; g < 2; ++g) {
        const int t = n0 + browB0 + g * 64;
        const size_t rr = (size_t)(b * 4 + hd) * 2048 + t;
        oPd[g] = *(const uint4*)(opart + rr * 64 + cu);
      }
    }
    bf16x8 af[4], bfr[2];
#pragma unroll
    for (int mt = 0; mt < 4; ++mt)
      af[mt] = *(const bf16x8*)(Ab + (mt * 16 + q16) * 80 + quad * 16);
#pragma unroll
    for (int jn = 0; jn < 2; ++jn)
      bfr[jn] = *(const bf16x8*)(Bb + (wn + jn * 16 + q16) * 80 + quad * 16);
#pragma unroll
    for (int mt = 0; mt < 4; ++mt)
#pragma unroll
      for (int jn = 0; jn < 2; ++jn)
        acc[mt][jn] = __builtin_amdgcn_mfma_f32_16x16x32_bf16(af[mt], bfr[jn], acc[mt][jn], 0, 0, 0);
    bsel ^= 15360;
  }

#pragma unroll
  for (int mt = 0; mt < 4; ++mt)
#pragma unroll
    for (int r = 0; r < 4; ++r) {
      const int o = bo + mt * 16 + quad * 4 + r;
      const float bv = bias[o];
#pragma unroll
      for (int jn = 0; jn < 2; ++jn)
        Cb[(size_t)o * 2048 + n0 + wn + jn * 16 + q16] = acc[mt][jn][r] + bv;
    }
}

// ---------------------------------------------------------------------------
// Kernel 7: inverse FFT2 via split-bf16 MFMA. One slice per wave; r22 form.
// ---------------------------------------------------------------------------
__global__ __launch_bounds__(256) void k_ifft2(const float* __restrict__ spec,
                                               float* __restrict__ out) {
  __shared__ __align__(16) char smem[51200];
  const int tid = threadIdx.x, lane = tid & 63, wv = tid >> 6;
  const int quad = lane >> 4, q16 = lane & 15;
  const int slice = blockIdx.x * 4 + wv;
  char* const wr_ = smem + 10240 + wv * 10240;

  // early spec global loads
  const float* sp = spec + (size_t)slice * 2048;
  float4 sv8[8];
#pragma unroll
  for (int u = 0; u < 8; ++u) sv8[u] = ((const float4*)sp)[u * 64 + lane];

  build_twiddle_lds(smem, tid);

#pragma unroll
  for (int u = 0; u < 8; ++u) {
    const int f = u * 64 + lane;  // 0..511 float4 (2 complex each)
    const float4 v = sv8[u];
    const int k1 = f >> 4, k2 = (f & 15) * 2;
    char* base = wr_ + k1 * 80 + k2 * 2;
    union { unsigned int w; __bf16 b[2]; } p;
    const __bf16 rh0 = (__bf16)v.x, rh1 = (__bf16)v.z;
    const __bf16 ih0 = (__bf16)v.y, ih1 = (__bf16)v.w;
    p.b[0] = rh0; p.b[1] = rh1; *(unsigned int*)(base) = p.w;
    p.b[0] = (__bf16)(v.x - (float)rh0);
    p.b[1] = (__bf16)(v.z - (float)rh1); *(unsigned int*)(base + 2560) = p.w;
    p.b[0] = ih0; p.b[1] = ih1; *(unsigned int*)(base + 5120) = p.w;
    p.b[0] = (__bf16)(v.y - (float)ih0);
    p.b[1] = (__bf16)(v.w - (float)ih1); *(unsigned int*)(base + 7680) = p.w;
  }
  __syncthreads();  // tables visible; X same-wave ordered

  bf16x8 cch[2], ccl[2], ssh[2], ssl[2], ssnh[2], ssnl[2];
  bf16x8 xreh[2], xrel[2], ximh[2], ximl[2];
#pragma unroll
  for (int t2 = 0; t2 < 2; ++t2) {
    const int row = t2 * 16 + q16;
    cch[t2] = *(const bf16x8*)(smem + row * 80 + quad * 16);
    ccl[t2] = *(const bf16x8*)(smem + 2560 + row * 80 + quad * 16);
    ssh[t2] = *(const bf16x8*)(smem + 5120 + row * 80 + quad * 16);
    ssl[t2] = *(const bf16x8*)(smem + 7680 + row * 80 + quad * 16);
    xreh[t2] = *(const bf16x8*)(wr_ + row * 80 + quad * 16);
    xrel[t2] = *(const bf16x8*)(wr_ + 2560 + row * 80 + quad * 16);
    ximh[t2] = *(const bf16x8*)(wr_ + 5120 + row * 80 + quad * 16);
    ximl[t2] = *(const bf16x8*)(wr_ + 7680 + row * 80 + quad * 16);
  }
  ssnh[0] = neg8(ssh[0]); ssnh[1] = neg8(ssh[1]);
  ssnl[0] = neg8(ssl[0]); ssnl[1] = neg8(ssl[1]);

  // pass 1
  f32x4 yre[2][2] = {}, yim[2][2] = {};
#pragma unroll
  for (int mt = 0; mt < 2; ++mt)
#pragma unroll
    for (int nt = 0; nt < 2; ++nt) {
      MFMA3(yre[mt][nt], xreh[mt], xrel[mt], cch[nt], ccl[nt]);
      MFMA3(yre[mt][nt], ximh[mt], ximl[mt], ssnh[nt], ssnl[nt]);
      MFMA3(yim[mt][nt], xreh[mt], xrel[mt], ssh[nt], ssl[nt]);
      MFMA3(yim[mt][nt], ximh[mt], ximl[mt], cch[nt], ccl[nt]);
    }

  // write Yt transposed + split over the X regions (wave-private)
#pragma unroll
  for (int mt = 0; mt < 2; ++mt)
#pragma unroll
    for (int nt = 0; nt < 2; ++nt) {
      char* base = wr_ + (nt * 16 + q16) * 80 + (mt * 16 + quad * 4) * 2;
      union { unsigned long long q; __bf16 b[4]; } h, l;
#pragma unroll
      for (int r = 0; r < 4; ++r) {
        const float v = yre[mt][nt][r];
        h.b[r] = (__bf16)v; l.b[r] = (__bf16)(v - (float)h.b[r]);
      }
      *(unsigned long long*)(base) = h.q;
      *(unsigned long long*)(base + 2560) = l.q;
#pragma unroll
      for (int r = 0; r < 4; ++r) {
        const float v = yim[mt][nt][r];
        h.b[r] = (__bf16)v; l.b[r] = (__bf16)(v - (float)h.b[r]);
      }
      *(unsigned long long*)(base + 5120) = h.q;
      *(unsigned long long*)(base + 7680) = l.q;
    }
  asm volatile("" ::: "memory");

  bf16x8 yreh[2], yrel[2], yimh[2], yiml[2];
#pragma unroll
  for (int nt = 0; nt < 2; ++nt) {
    const int row = nt * 16 + q16;
    yreh[nt] = *(const bf16x8*)(wr_ + row * 80 + quad * 16);
    yrel[nt] = *(const bf16x8*)(wr_ + 2560 + row * 80 + quad * 16);
    yimh[nt] = *(const bf16x8*)(wr_ + 5120 + row * 80 + quad * 16);
    yiml[nt] = *(const bf16x8*)(wr_ + 7680 + row * 80 + quad * 16);
  }

  // pass 2
  f32x4 zre[2][2] = {}, zim[2][2] = {};
#pragma unroll
  for (int mt = 0; mt < 2; ++mt)
#pragma unroll
    for (int nt = 0; nt < 2; ++nt) {
      MFMA3(zre[mt][nt], cch[mt], ccl[mt], yreh[nt], yrel[nt]);
      MFMA3(zre[mt][nt], ssnh[mt], ssnl[mt], yimh[nt], yiml[nt]);
      MFMA3(zim[mt][nt], cch[mt], ccl[mt], yimh[nt], yiml[nt]);
      MFMA3(zim[mt][nt], ssh[mt], ssl[mt], yreh[nt], yrel[nt]);
    }

  float* op = out + (size_t)slice * 2048;
#pragma unroll
  for (int mt = 0; mt < 2; ++mt)
#pragma unroll
    for (int nt = 0; nt < 2; ++nt)
#pragma unroll
      for (int r = 0; r < 4; ++r) {
        const int n1 = mt * 16 + quad * 4 + r;
        const int n2 = nt * 16 + q16;
        float2 st;
        st.x = zre[mt][nt][r] * (1.0f / 1024.0f);
        st.y = zim[mt][nt][r] * (1.0f / 1024.0f);
        *(float2*)(op + 2 * (n1 * 32 + n2)) = st;
      }
}

// ---------------------------------------------------------------------------
extern "C" void kernel_launch(void* const* d_in, const int* in_sizes, int n_in,
                              void* d_out, int out_size, void* d_ws, size_t ws_size,
                              hipStream_t stream) {
  (void)in_sizes; (void)n_in; (void)out_size; (void)ws_size;
  const float* x      = (const float*)d_in[0];
  const float* gn_w   = (const float*)d_in[1];
  const float* gn_b   = (const float*)d_in[2];
  const float* qkv_w  = (const float*)d_in[3];
  const float* qkv_b  = (const float*)d_in[4];
  const float* proj_w = (const float*)d_in[5];
  const float* proj_b = (const float*)d_in[6];
  float* out = (float*)d_out;

  float* spec  = (float*)d_ws;
  __bf16* Qt   = (__bf16*)(spec + 4194304);   // 4194304 elems
  __bf16* Kt   = Qt + 4194304;                // 2359296 elems (32*1152*64)
  __bf16* Vt   = Kt + 2359296;                // 2359296 elems
  float* xr    = (float*)(Vt + 2359296) + 512; // 512-float hole (old stats slot)
  __bf16* xt   = (__bf16*)(xr + 4194304);     // 4194304 bf16
  __bf16* opart = (__bf16*)xr;                // 4194304 bf16 (clobbers xr; single-part)
  float*  dq    = (float*)(opart + 12582912); // 65536 (offset kept from 3-part era)
  float*  uk    = dq + 65536;                 // 2048
  float*  uv    = uk + 2048;                  // 2048
  float*  stats_part = uv + 2048;             // 4096 floats (256 bg x 8 sub x 2)

  k_fft2<<<512, 256, 0, stream>>>(x, xr, stats_part);
  k_uvec<<<64, 256, 0, stream>>>(stats_part, gn_w, gn_b, qkv_w, qkv_b, uk, uv);
  k_gntrans<<<dim3(32, 4, 8), 256, 0, stream>>>(xr, stats_part, gn_w, gn_b, xt);
  k_gemm_qkv<<<dim3(136, 8), 256, 0, stream>>>(qkv_w, xt, qkv_b, uk, dq,
                                               Qt, Kt, Vt);
  k_attn_mfma<<<dim3(16, 32), 256, 0, stream>>>(Qt, Kt, Vt, dq, uv, opart);
  k_gemm_proj<<<dim3(16, 4, 8), 256, 0, stream>>>(proj_w, opart, proj_b, spec);
  k_ifft2<<<512, 256, 0, stream>>>(spec, out);
}

// Round 9
// 154.126 us; speedup vs baseline: 1.2398x; 1.0111x over previous
//
#include <hip/hip_runtime.h>
#include <hip/hip_bf16.h>
#include <stdint.h>

#define PI_F 3.14159265358979323846f
#define C1_EXP 0.18033688f   // log2(e)/8
#define C2_EXP 23.083120f    // 16*log2(e)

typedef __bf16 bf16x8 __attribute__((ext_vector_type(8)));
typedef float f32x4 __attribute__((ext_vector_type(4)));
typedef unsigned int uint32x4 __attribute__((ext_vector_type(4)));

// LDS-only barrier: s_barrier with lgkmcnt drain but NO vmcnt drain, so
// in-flight global prefetch loads survive across the barrier (T4-minimal).
// Proven +3us on attn in r20.
#define BAR_LDS() asm volatile("s_waitcnt lgkmcnt(0)\n\ts_barrier" ::: "memory")

__device__ __forceinline__ bf16x8 neg8(bf16x8 v) {
  union { bf16x8 b; uint32x4 u; } x;
  x.b = v;
  x.u ^= (uint32x4){0x80008000u, 0x80008000u, 0x80008000u, 0x80008000u};
  return x.b;
}

// 3-term split-accumulate: P*Q with P=Ph+Pl, Q=Qh+Ql (drop Pl*Ql ~2^-18)
#define MFMA3(acc, Ph, Pl, Qh, Ql)                                        \
  acc = __builtin_amdgcn_mfma_f32_16x16x32_bf16(Ph, Qh, acc, 0, 0, 0);    \
  acc = __builtin_amdgcn_mfma_f32_16x16x32_bf16(Ph, Ql, acc, 0, 0, 0);    \
  acc = __builtin_amdgcn_mfma_f32_16x16x32_bf16(Pl, Qh, acc, 0, 0, 0);

// Closed-form base-slot -> original column mapping.
__device__ __forceinline__ int slot2n(int slot) {
  const int pi = slot >> 1, im = slot & 1;
  int k1, k2;
  if (pi < 480)      { k1 = 1 + (pi >> 5); k2 = pi & 31; }
  else if (pi < 495) { k1 = 0;  k2 = pi - 479; }
  else if (pi < 510) { k1 = 16; k2 = pi - 494; }
  else if (pi < 514) { k1 = ((pi - 510) >> 1) * 16; k2 = ((pi - 510) & 1) * 16; }
  else               { k1 = 0; k2 = 0; }
  return 2 * (k1 * 32 + k2) + im;
}

// Inline twiddle-table build (r22: replaces k_twid kernel + global staging).
__device__ __forceinline__ void build_twiddle_lds(char* smem, int tid) {
  for (int e = tid; e < 1024; e += 256) {
    const int j = e >> 5, k = e & 31;
    const int t = (j * k) & 31;
    float sv, cv;
    sincosf(2.0f * PI_F * (float)t / 32.0f, &sv, &cv);
    const __bf16 ch = (__bf16)cv, sh = (__bf16)sv;
    *(__bf16*)(smem + j * 80 + k * 2) = ch;
    *(__bf16*)(smem + 2560 + j * 80 + k * 2) = (__bf16)(cv - (float)ch);
    *(__bf16*)(smem + 5120 + j * 80 + k * 2) = sh;
    *(__bf16*)(smem + 7680 + j * 80 + k * 2) = (__bf16)(sv - (float)sh);
  }
}

// ---------------------------------------------------------------------------
// Kernel 1: forward FFT2 via split-bf16 MFMA. One slice per wave; r22 form.
// ---------------------------------------------------------------------------
__global__ __launch_bounds__(256) void k_fft2(const float* __restrict__ x,
                                              float* __restrict__ xr,
                                              float* __restrict__ stats_part) {
  __shared__ __align__(16) char smem[51200];
  const int tid = threadIdx.x, lane = tid & 63, wv = tid >> 6;
  const int quad = lane >> 4, q16 = lane & 15;
  const int slice = blockIdx.x * 4 + wv;
  char* const wr_ = smem + 10240 + wv * 10240;

  // early X global loads (wave-private region; overlap with table build)
  const float* xs = x + (size_t)slice * 1024;
  float4 xv[4];
#pragma unroll
  for (int u = 0; u < 4; ++u) xv[u] = ((const float4*)xs)[u * 64 + lane];

  build_twiddle_lds(smem, tid);

  // X split + stage (same-wave ds ordering)
#pragma unroll
  for (int u = 0; u < 4; ++u) {
    const int f = u * 64 + lane;
    const float4 v = xv[u];
    const int row = f >> 3, c4 = (f & 7) * 4;
    union { unsigned long long q; __bf16 b[4]; } ph, pl;
    ph.b[0] = (__bf16)v.x; ph.b[1] = (__bf16)v.y;
    ph.b[2] = (__bf16)v.z; ph.b[3] = (__bf16)v.w;
    pl.b[0] = (__bf16)(v.x - (float)ph.b[0]);
    pl.b[1] = (__bf16)(v.y - (float)ph.b[1]);
    pl.b[2] = (__bf16)(v.z - (float)ph.b[2]);
    pl.b[3] = (__bf16)(v.w - (float)ph.b[3]);
    *(unsigned long long*)(wr_ + row * 80 + c4 * 2) = ph.q;
    *(unsigned long long*)(wr_ + 2560 + row * 80 + c4 * 2) = pl.q;
  }
  __syncthreads();  // tables visible to all waves; X same-wave ordered

  bf16x8 cch[2], ccl[2], ssh[2], ssl[2], xh[2], xl[2];
#pragma unroll
  for (int t2 = 0; t2 < 2; ++t2) {
    const int row = t2 * 16 + q16;
    cch[t2] = *(const bf16x8*)(smem + row * 80 + quad * 16);
    ccl[t2] = *(const bf16x8*)(smem + 2560 + row * 80 + quad * 16);
    ssh[t2] = *(const bf16x8*)(smem + 5120 + row * 80 + quad * 16);
    ssl[t2] = *(const bf16x8*)(smem + 7680 + row * 80 + quad * 16);
    xh[t2] = *(const bf16x8*)(wr_ + row * 80 + quad * 16);
    xl[t2] = *(const bf16x8*)(wr_ + 2560 + row * 80 + quad * 16);
  }

  // pass 1: Yre = X@Cc, Yim = -(X@Ss)
  f32x4 yre[2][2] = {}, yim[2][2] = {};
#pragma unroll
  for (int mt = 0; mt < 2; ++mt)
#pragma unroll
    for (int nt = 0; nt < 2; ++nt) {
      MFMA3(yre[mt][nt], xh[mt], xl[mt], cch[nt], ccl[nt]);
      MFMA3(yim[mt][nt], xh[mt], xl[mt], ssh[nt], ssl[nt]);
    }

  // write Yt transposed + split (wave-private; same-wave ordering)
#pragma unroll
  for (int mt = 0; mt < 2; ++mt)
#pragma unroll
    for (int nt = 0; nt < 2; ++nt) {
      char* base = wr_ + (nt * 16 + q16) * 80 + (mt * 16 + quad * 4) * 2;
      union { unsigned long long q; __bf16 b[4]; } h, l;
#pragma unroll
      for (int r = 0; r < 4; ++r) {
        const float v = yre[mt][nt][r];
        h.b[r] = (__bf16)v; l.b[r] = (__bf16)(v - (float)h.b[r]);
      }
      *(unsigned long long*)(base) = h.q;
      *(unsigned long long*)(base + 2560) = l.q;
#pragma unroll
      for (int r = 0; r < 4; ++r) {
        const float v = -yim[mt][nt][r];
        h.b[r] = (__bf16)v; l.b[r] = (__bf16)(v - (float)h.b[r]);
      }
      *(unsigned long long*)(base + 5120) = h.q;
      *(unsigned long long*)(base + 7680) = l.q;
    }
  asm volatile("" ::: "memory");

  bf16x8 yreh[2], yrel[2], yimh[2], yiml[2];
#pragma unroll
  for (int nt = 0; nt < 2; ++nt) {
    const int row = nt * 16 + q16;
    yreh[nt] = *(const bf16x8*)(wr_ + row * 80 + quad * 16);
    yrel[nt] = *(const bf16x8*)(wr_ + 2560 + row * 80 + quad * 16);
    yimh[nt] = *(const bf16x8*)(wr_ + 5120 + row * 80 + quad * 16);
    yiml[nt] = *(const bf16x8*)(wr_ + 7680 + row * 80 + quad * 16);
  }

  // pass 2: Zre = Cc@Yre + Ss@Yim ; Zim = Cc@Yim - Ss@Yre
  f32x4 zre[2][2] = {}, zim[2][2] = {};
  bf16x8 ssnh[2], ssnl[2];
  ssnh[0] = neg8(ssh[0]); ssnh[1] = neg8(ssh[1]);
  ssnl[0] = neg8(ssl[0]); ssnl[1] = neg8(ssl[1]);
#pragma unroll
  for (int mt = 0; mt < 2; ++mt)
#pragma unroll
    for (int nt = 0; nt < 2; ++nt) {
      MFMA3(zre[mt][nt], cch[mt], ccl[mt], yreh[nt], yrel[nt]);
      MFMA3(zre[mt][nt], ssh[mt], ssl[mt], yimh[nt], yiml[nt]);
      MFMA3(zim[mt][nt], cch[mt], ccl[mt], yimh[nt], yiml[nt]);
      MFMA3(zim[mt][nt], ssnh[mt], ssnl[mt], yreh[nt], yrel[nt]);
    }

  // stats + store
  float* op = xr + (size_t)slice * 2048;
  float s1 = 0.f, s2 = 0.f;
#pragma unroll
  for (int mt = 0; mt < 2; ++mt)
#pragma unroll
    for (int nt = 0; nt < 2; ++nt)
#pragma unroll
      for (int r = 0; r < 4; ++r) {
        const int k1 = mt * 16 + quad * 4 + r;
        const int k2 = nt * 16 + q16;
        const float a = zre[mt][nt][r], bimg = zim[mt][nt][r];
        s1 += a + bimg;
        s2 += a * a + bimg * bimg;
        float2 st; st.x = a; st.y = bimg;
        *(float2*)(op + 2 * (k1 * 32 + k2)) = st;
      }
#pragma unroll
  for (int off = 1; off <= 32; off <<= 1) {
    s1 += __shfl_xor(s1, off);
    s2 += __shfl_xor(s2, off);
  }
  if (lane == 0) {
    const int bg = (slice >> 8) * 32 + ((slice & 255) >> 3);
    const int sub = slice & 7;
    float2 st; st.x = s1; st.y = s2;
    *(float2*)(stats_part + (size_t)(bg * 8 + sub) * 2) = st;
  }
}

// ---------------------------------------------------------------------------
// Kernel 2+3 merged (r24): GroupNorm-apply/transpose AND mirror-correction
// vectors in ONE launch. Blocks 0..1023 = gntrans tiles (decode matches the
// old dim3(32,4,8)); blocks 1024..1087 = uvec work (old 64-block grid).
// The two halves are data-independent (both consume only fft2 outputs), so
// they are safely coscheduled; uvec's 64 blocks fill CUs alongside the
// memory-bound gntrans blocks, and one dispatch boundary disappears.
// ---------------------------------------------------------------------------
__global__ __launch_bounds__(256) void k_gnuv(const float* __restrict__ xr,
                                              const float* __restrict__ stats_part,
                                              const float* __restrict__ gn_w,
                                              const float* __restrict__ gn_b,
                                              const float* __restrict__ qkv_w,
                                              const float* __restrict__ qkv_b,
                                              __bf16* __restrict__ xt,
                                              float* __restrict__ uk,
                                              float* __restrict__ uv) {
  const int bid = blockIdx.x;
  const int tid = threadIdx.x;
  if (bid >= 1024) {
    // ---- uvec body (identical arithmetic to old k_uvec) ----
    const int blk = bid - 1024;
    const int b = blk >> 3, h = (blk >> 1) & 3, role = blk & 1;
    __shared__ float Bsh[256];
    {
      const int g = tid >> 3;
      float S = 0.f, S2 = 0.f;
#pragma unroll
      for (int s = 0; s < 8; ++s) {
        S  += stats_part[((b * 32 + g) * 8 + s) * 2];
        S2 += stats_part[((b * 32 + g) * 8 + s) * 2 + 1];
      }
      const float mean = S * (1.0f / 16384.0f);
      const float var = S2 * (1.0f / 16384.0f) - mean * mean;
      const float rstd = rsqrtf(var + 1e-5f);
      Bsh[tid] = gn_b[tid] - mean * rstd * gn_w[tid];
    }
    __syncthreads();
    const int cp = tid >> 2, seg = tid & 3;
    const int row = h * 192 + 64 + role * 64 + cp;
    const float* wr_ = qkv_w + (size_t)row * 256 + seg * 64;
    const float* bs = Bsh + seg * 64;
    float s = 0.f;
#pragma unroll
    for (int i = 0; i < 16; ++i) {
      const float4 w4 = *(const float4*)(wr_ + i * 4);
      const float4 b4 = *(const float4*)(bs + i * 4);
      s += w4.x * b4.x + w4.y * b4.y + w4.z * b4.z + w4.w * b4.w;
    }
    s += __shfl_xor(s, 1);
    s += __shfl_xor(s, 2);
    if (seg == 0) {
      float* dst = (role == 0) ? uk : uv;
      dst[(size_t)(b * 4 + h) * 64 + cp] = s + qkv_b[row];
    }
    return;
  }
  // ---- gntrans body (identical arithmetic to old k_gntrans) ----
  const int n0 = (bid & 31) * 64;
  const int c0 = ((bid >> 5) & 3) * 64;
  const int b = bid >> 7;
  __shared__ __bf16 Lt[64][72];
  __shared__ float gsum[8][2];
  if (tid < 8) {
    const int g = (c0 >> 3) + tid;
    float S = 0.f, S2 = 0.f;
#pragma unroll
    for (int s = 0; s < 8; ++s) {
      S  += stats_part[((b * 32 + g) * 8 + s) * 2];
      S2 += stats_part[((b * 32 + g) * 8 + s) * 2 + 1];
    }
    gsum[tid][0] = S;
    gsum[tid][1] = S2;
  }
  __syncthreads();
  for (int i = tid; i < 1024; i += 256) {
    const int cl = i >> 4, c = c0 + cl, nl = (i & 15) * 4;
    const float S = gsum[cl >> 3][0];
    const float S2 = gsum[cl >> 3][1];
    const float mean = S * (1.0f / 16384.0f);
    const float var = S2 * (1.0f / 16384.0f) - mean * mean;
    const float rstd = rsqrtf(var + 1e-5f);
    const float sc = rstd * gn_w[c];
    const float sh = gn_b[c] - mean * sc;
    const float4 v = *(const float4*)(xr + ((size_t)b * 256 + c) * 2048 + n0 + nl);
    Lt[nl][cl] = (__bf16)(v.x * sc + sh);
    Lt[nl + 1][cl] = (__bf16)(v.y * sc + sh);
    Lt[nl + 2][cl] = (__bf16)(v.z * sc + sh);
    Lt[nl + 3][cl] = (__bf16)(v.w * sc + sh);
  }
  __syncthreads();
  __bf16* dst = xt + (size_t)b * 524288 + (size_t)n0 * 256 + c0;
  for (int i = tid; i < 512; i += 256) {
    const int nl = i >> 3, cch = (i & 7) * 8;
    *(uint4*)(dst + (size_t)nl * 256 + cch) = *(const uint4*)&Lt[nl][cch];
  }
}

// ---------------------------------------------------------------------------
// Kernel 4: QKV GEMM (bf16 MFMA), double-buffered LDS; unchanged.
// ---------------------------------------------------------------------------
__global__ __launch_bounds__(256) void k_gemm_qkv(const float* __restrict__ W,
                                                  const __bf16* __restrict__ X,
                                                  const float* __restrict__ bias,
                                                  const float* __restrict__ uk,
                                                  float* __restrict__ dq,
                                                  __bf16* __restrict__ Qt,
                                                  __bf16* __restrict__ Kt,
                                                  __bf16* __restrict__ Vt) {
  const int tx = blockIdx.x;
  const int b = blockIdx.y;
  int role, hd, nt;
  if (tx < 64) { role = 0; hd = tx >> 4; nt = tx & 15; }
  else if (tx < 100) { role = 1; const int i = tx - 64; hd = i / 9; nt = i - hd * 9; }
  else { role = 2; const int i = tx - 100; hd = i / 9; nt = i - hd * 9; }
  const int n0 = nt * 128;
  const int bo = hd * 192 + role * 64;
  const __bf16* Xb = X + (size_t)b * 524288;

  __shared__ __align__(16) char smem[30720];
  __bf16 (*Ot)[72] = (__bf16(*)[72])smem;
  __bf16 (*Ot2)[136] = (__bf16(*)[136])smem;

  const int tid = threadIdx.x, lane = tid & 63, wv = tid >> 6;
  const int quad = lane >> 4, q16 = lane & 15, wn = wv * 32;

  const int rowA = tid >> 2, chA = (tid & 3) * 8;
  const int browB0 = tid >> 2, bchB = (tid & 3) * 8;
  const float* wA = W + (size_t)(bo + rowA) * 256 + chA;

  const int s0r = n0 + browB0, s1r = n0 + browB0 + 64;
  const int pn0 = (role == 0) ? s0r : slot2n(s0r);
  const int pn1 = (role == 0) ? s1r : slot2n(s1r);

  float4 aP0 = *(const float4*)(wA);
  float4 aP1 = *(const float4*)(wA + 4);
  uint4 bP0 = *(const uint4*)(Xb + (size_t)pn0 * 256 + bchB);
  uint4 bP1 = *(const uint4*)(Xb + (size_t)pn1 * 256 + bchB);

  f32x4 acc[4][2] = {};
  int bsel = 0;
  for (int k0 = 0; k0 < 256; k0 += 32) {
    char* const Ab = smem + bsel;
    char* const Bb = smem + bsel + 5120;
    {
      union { uint4 u; __bf16 h[8]; } pa;
      pa.h[0] = (__bf16)aP0.x; pa.h[1] = (__bf16)aP0.y;
      pa.h[2] = (__bf16)aP0.z; pa.h[3] = (__bf16)aP0.w;
      pa.h[4] = (__bf16)aP1.x; pa.h[5] = (__bf16)aP1.y;
      pa.h[6] = (__bf16)aP1.z; pa.h[7] = (__bf16)aP1.w;
      *(uint4*)(Ab + rowA * 80 + chA * 2) = pa.u;
      *(uint4*)(Bb + browB0 * 80 + bchB * 2) = bP0;
      *(uint4*)(Bb + (browB0 + 64) * 80 + bchB * 2) = bP1;
    }
    __syncthreads();
    if (k0 + 32 < 256) {
      const int kn = k0 + 32;
      aP0 = *(const float4*)(wA + kn);
      aP1 = *(const float4*)(wA + kn + 4);
      bP0 = *(const uint4*)(Xb + (size_t)pn0 * 256 + kn + bchB);
      bP1 = *(const uint4*)(Xb + (size_t)pn1 * 256 + kn + bchB);
    }
    bf16x8 af[4], bfr[2];
#pragma unroll
    for (int mt = 0; mt < 4; ++mt)
      af[mt] = *(const bf16x8*)(Ab + (mt * 16 + q16) * 80 + quad * 16);
#pragma unroll
    for (int jn = 0; jn < 2; ++jn)
      bfr[jn] = *(const bf16x8*)(Bb + (wn + jn * 16 + q16) * 80 + quad * 16);
#pragma unroll
    for (int mt = 0; mt < 4; ++mt)
#pragma unroll
      for (int jn = 0; jn < 2; ++jn)
        acc[mt][jn] = __builtin_amdgcn_mfma_f32_16x16x32_bf16(af[mt], bfr[jn], acc[mt][jn], 0, 0, 0);
    bsel ^= 15360;
  }
  __syncthreads();

  const int bh = b * 4 + hd;
  if (role == 2) {
#pragma unroll
    for (int mt = 0; mt < 4; ++mt)
#pragma unroll
      for (int r = 0; r < 4; ++r) {
        const int c = mt * 16 + quad * 4 + r;
        const float bv = bias[bo + c];
#pragma unroll
        for (int jn = 0; jn < 2; ++jn)
          Ot2[c][wn + jn * 16 + q16] = (__bf16)(acc[mt][jn][r] + bv);
      }
    __syncthreads();
    __bf16* dst = Vt + (size_t)bh * 73728;  // [c][1152]
    for (int i = tid; i < 1024; i += 256) {
      const int c = i >> 4, sg = (i & 15) * 8;
      *(uint4*)(dst + (size_t)c * 1152 + n0 + sg) = *(const uint4*)&Ot2[c][sg];
    }
  } else {
    __bf16* dst = (role == 0 ? Qt + (size_t)bh * 131072
                             : Kt + (size_t)bh * 73728);  // [n][64]
#pragma unroll
    for (int mt = 0; mt < 4; ++mt)
#pragma unroll
      for (int r = 0; r < 4; ++r) {
        const int c = mt * 16 + quad * 4 + r;
        const float bv = bias[bo + c];
#pragma unroll
        for (int jn = 0; jn < 2; ++jn)
          Ot[wn + jn * 16 + q16][c] = (__bf16)(acc[mt][jn][r] + bv);
      }
    __syncthreads();
    for (int i = tid; i < 1024; i += 256) {
      const int nl = i >> 3, cch = (i & 7) * 8;
      *(uint4*)(dst + (size_t)(n0 + nl) * 64 + cch) = *(const uint4*)&Ot[nl][cch];
    }
    if (role == 0 && tid < 128) {
      const float* ukp = uk + (size_t)bh * 64;
      float dv = 0.f;
#pragma unroll
      for (int g8 = 0; g8 < 8; ++g8) {
        const bf16x8 qv = *(const bf16x8*)&Ot[tid][g8 * 8];
#pragma unroll
        for (int k = 0; k < 8; ++k) dv += (float)qv[k] * ukp[g8 * 8 + k];
      }
      dq[(size_t)bh * 2048 + n0 + tid] = dv * (2.0f * C1_EXP);
    }
  }
}

// ---------------------------------------------------------------------------
// Kernel 5: MFMA flash attention. r23 KVBLK=64 form; unchanged.
// ---------------------------------------------------------------------------
template <bool EDGE, int OFF>
__device__ __forceinline__ void attn_half(
    const int s0, const int quad,
    const char* const (&krp)[2][2], const char* const (&vrp)[4],
    char* const (&pwp)[2][2], const char* const (&prp)[2],
    const bf16x8 (&bq)[2][2], const float (&Dm)[2],
    f32x4 (&oacc)[2][4], float (&lsum)[2], float (&spsum)[2]) {
  f32x4 sacc[2][2] = {};
#pragma unroll
  for (int j = 0; j < 2; ++j)
#pragma unroll
    for (int kk = 0; kk < 2; ++kk) {
      const bf16x8 ak = *(const bf16x8*)(krp[j][kk] + OFF);
      sacc[0][j] = __builtin_amdgcn_mfma_f32_16x16x32_bf16(ak, bq[0][kk], sacc[0][j], 0, 0, 0);
      sacc[1][j] = __builtin_amdgcn_mfma_f32_16x16x32_bf16(ak, bq[1][kk], sacc[1][j], 0, 0, 0);
    }

#pragma unroll
  for (int b = 0; b < 2; ++b) {
    float lacc = 0.f, spacc = 0.f;
#pragma unroll
    for (int j = 0; j < 2; ++j) {
      float B0, B2, Bv1, Bv3, Bm1, Bm3;
      if (EDGE) {
        const int sg = s0 + j * 16 + quad * 4;
        B0 = (sg < 1020) ? (1.0f - C2_EXP) : ((sg < 1028) ? -C2_EXP : -1e30f);
        B2 = (sg + 2 < 1020) ? (1.0f - C2_EXP)
                             : ((sg + 2 < 1028) ? -C2_EXP : -1e30f);
        Bv1 = (sg + 1 < 1028) ? -C2_EXP : -1e30f;
        Bv3 = (sg + 3 < 1028) ? -C2_EXP : -1e30f;
        Bm1 = (sg + 1 < 1020) ? Dm[b] : -1e30f;
        Bm3 = (sg + 3 < 1020) ? Dm[b] : -1e30f;
      } else {
        B0 = 1.0f - C2_EXP;
        B2 = 1.0f - C2_EXP;
        Bv1 = -C2_EXP;
        Bv3 = -C2_EXP;
        Bm1 = Dm[b];
        Bm3 = Dm[b];
      }
      const float P0  = __builtin_amdgcn_exp2f(fmaf(sacc[b][j][0],  C1_EXP, B0));
      const float Pv1 = __builtin_amdgcn_exp2f(fmaf(sacc[b][j][1],  C1_EXP, Bv1));
      const float P2  = __builtin_amdgcn_exp2f(fmaf(sacc[b][j][2],  C1_EXP, B2));
      const float Pv3 = __builtin_amdgcn_exp2f(fmaf(sacc[b][j][3],  C1_EXP, Bv3));
      const float pm1 = __builtin_amdgcn_exp2f(fmaf(sacc[b][j][1], -C1_EXP, Bm1));
      const float pm3 = __builtin_amdgcn_exp2f(fmaf(sacc[b][j][3], -C1_EXP, Bm3));
      const float mm = pm1 + pm3;
      lacc += (P0 + P2) + (Pv1 + Pv3) + mm;
      spacc += mm;
      union { uint2 u; __bf16 h[4]; } pk;
      pk.h[0] = (__bf16)P0;
      pk.h[1] = (__bf16)(Pv1 - pm1);
      pk.h[2] = (__bf16)P2;
      pk.h[3] = (__bf16)(Pv3 - pm3);
      *(uint2*)pwp[b][j] = pk.u;
    }
    lsum[b] += lacc;
    spsum[b] += spacc;
  }
  asm volatile("" ::: "memory");

  bf16x8 bp[2];
  bp[0] = *(const bf16x8*)prp[0];
  bp[1] = *(const bf16x8*)prp[1];
#pragma unroll
  for (int jc = 0; jc < 4; ++jc) {
    const bf16x8 av = *(const bf16x8*)(vrp[jc] + OFF);
    oacc[0][jc] = __builtin_amdgcn_mfma_f32_16x16x32_bf16(av, bp[0], oacc[0][jc], 0, 0, 0);
    oacc[1][jc] = __builtin_amdgcn_mfma_f32_16x16x32_bf16(av, bp[1], oacc[1][jc], 0, 0, 0);
  }
}

__global__ __launch_bounds__(256, 4) void k_attn_mfma(const __bf16* __restrict__ Qt,
                                                      const __bf16* __restrict__ Kt,
                                                      const __bf16* __restrict__ Vt,
                                                      const float* __restrict__ dq,
                                                      const float* __restrict__ uv,
                                                      __bf16* __restrict__ opart) {
  const int t0 = blockIdx.x * 128;
  const int bh = blockIdx.y;
  const __bf16* kt = Kt + (size_t)bh * 73728;
  const __bf16* vt = Vt + (size_t)bh * 73728;

  __shared__ __align__(16) char smem[24576];

  const int tid = threadIdx.x, lane = tid & 63, wv = tid >> 6;
  const int quad = lane >> 4, q16 = lane & 15;
  const int wband = wv * 32;

  const int rK = tid >> 3, gK = tid & 7;
  char* const kw = smem + rK * 128 + ((gK ^ (rK & 7)) * 16);
  const int cV = tid >> 2, gV = tid & 3;
  char* const vw = smem + 8192 + (cV >> 1) * 128 +
                   ((((cV & 1) * 4 + gV) ^ ((cV >> 1) & 7)) * 16);
  const __bf16* const kg = kt + (size_t)rK * 64 + gK * 8;
  const __bf16* const vg = vt + (size_t)cV * 1152 + gV * 8;

  const char* krp[2][2];
#pragma unroll
  for (int j = 0; j < 2; ++j)
#pragma unroll
    for (int kk = 0; kk < 2; ++kk)
      krp[j][kk] = smem + (j * 16 + q16) * 128 + (((kk * 4 + quad) ^ (q16 & 7)) * 16);
  const int a7 = (q16 >> 1) & 7, p1 = q16 & 1;
  const char* vrp[4];
#pragma unroll
  for (int jc = 0; jc < 4; ++jc)
    vrp[jc] = smem + 8192 + (jc * 8 + (q16 >> 1)) * 128 +
              (((p1 * 4 + quad) ^ a7) * 16);
  char* pwp[2][2];
  const char* prp[2];
#pragma unroll
  for (int b = 0; b < 2; ++b) {
    const int mrow = ((wband + b * 16) >> 1) + (q16 >> 1);
    prp[b] = smem + 16384 + mrow * 128 + (((p1 * 4 + quad) ^ a7) * 16);
#pragma unroll
    for (int j = 0; j < 2; ++j)
      pwp[b][j] = smem + 16384 + mrow * 128 +
                  (((p1 * 4 + j * 2 + (quad >> 1)) ^ a7) * 16) + (quad & 1) * 8;
  }

  const __bf16* qbase = Qt + (size_t)bh * 131072;
  bf16x8 bq[2][2];
  float Dm[2];
#pragma unroll
  for (int b = 0; b < 2; ++b) {
    const int t = t0 + wband + b * 16 + q16;
    const __bf16* qp = qbase + (size_t)t * 64 + quad * 8;
    bq[b][0] = *(const bf16x8*)qp;
    bq[b][1] = *(const bf16x8*)(qp + 32);
    Dm[b] = dq[(size_t)bh * 2048 + t] - C2_EXP;
  }

  f32x4 oacc[2][4] = {};
  float lsum[2] = {0.f, 0.f};
  float spsum[2] = {0.f, 0.f};

  // 1056 slots = 15 x dbl(64) [0..959] + dbl(64) with edge second half
  // [960..1023] + single(32) edge [1024..1055].
  uint4 kA0 = *(const uint4*)(kg);
  uint4 kA1 = *(const uint4*)(kg + (size_t)32 * 64);
  uint4 vA0 = *(const uint4*)(vg);
  uint4 vA1 = *(const uint4*)(vg + 32);

  int s0 = 0;
#pragma unroll 1
  for (int it = 0; it < 15; ++it) {
    *(uint4*)kw = kA0;
    *(uint4*)(kw + 4096) = kA1;
    *(uint4*)vw = vA0;
    *(uint4*)(vw + 4096) = vA1;
    BAR_LDS();
    kA0 = *(const uint4*)(kg + (size_t)(s0 + 64) * 64);
    kA1 = *(const uint4*)(kg + (size_t)(s0 + 96) * 64);
    vA0 = *(const uint4*)(vg + s0 + 64);
    vA1 = *(const uint4*)(vg + s0 + 96);
    attn_half<false, 0>(s0, quad, krp, vrp, pwp, prp, bq, Dm,
                        oacc, lsum, spsum);
    attn_half<false, 4096>(s0 + 32, quad, krp, vrp, pwp, prp, bq, Dm,
                           oacc, lsum, spsum);
    BAR_LDS();
    s0 += 64;
  }
  // s0 == 960; kA0/vA0 hold tiles 960, kA1/vA1 hold 992.
  *(uint4*)kw = kA0;
  *(uint4*)(kw + 4096) = kA1;
  *(uint4*)vw = vA0;
  *(uint4*)(vw + 4096) = vA1;
  BAR_LDS();
  kA0 = *(const uint4*)(kg + (size_t)1024 * 64);
  vA0 = *(const uint4*)(vg + 1024);
  attn_half<false, 0>(960, quad, krp, vrp, pwp, prp, bq, Dm,
                      oacc, lsum, spsum);
  attn_half<true, 4096>(992, quad, krp, vrp, pwp, prp, bq, Dm,
                        oacc, lsum, spsum);
  BAR_LDS();
  // final single 32-slot tile at base offsets
  *(uint4*)kw = kA0;
  *(uint4*)vw = vA0;
  BAR_LDS();
  attn_half<true, 0>(1024, quad, krp, vrp, pwp, prp, bq, Dm,
                     oacc, lsum, spsum);

  // epilogue-only uv load (kept out of the loop-live register set)
  float4 uv4[4];
  {
    const float* uvp = uv + (size_t)bh * 64;
#pragma unroll
    for (int jc = 0; jc < 4; ++jc)
      uv4[jc] = *(const float4*)(uvp + jc * 16 + quad * 4);
  }

#pragma unroll
  for (int b = 0; b < 2; ++b) {
    float l = lsum[b], sp = spsum[b];
    l += __shfl_xor(l, 16);
    l += __shfl_xor(l, 32);
    sp += __shfl_xor(sp, 16);
    sp += __shfl_xor(sp, 32);
    const float inv = 1.0f / l;         // l complete: self-normalize
    const float su = 2.0f * sp * inv;
    const int t = t0 + wband + b * 16 + q16;
    __bf16* opp = opart + ((size_t)bh * 2048 + t) * 64;
#pragma unroll
    for (int jc = 0; jc < 4; ++jc) {
      union { uint2 u; __bf16 h[4]; } pk;
      pk.h[0] = (__bf16)(oacc[b][jc][0] * inv + su * uv4[jc].x);
      pk.h[1] = (__bf16)(oacc[b][jc][1] * inv + su * uv4[jc].y);
      pk.h[2] = (__bf16)(oacc[b][jc][2] * inv + su * uv4[jc].z);
      pk.h[3] = (__bf16)(oacc[b][jc][3] * inv + su * uv4[jc].w);
      *(uint2*)(opp + jc * 16 + quad * 4) = pk.u;
    }
  }
}

// ---------------------------------------------------------------------------
// Kernel 6: proj GEMM (bf16 MFMA), double-buffered, plain GEMM; unchanged.
// ---------------------------------------------------------------------------
__global__ __launch_bounds__(256) void k_gemm_proj(const float* __restrict__ W,
                                                   const __bf16* __restrict__ opart,
                                                   const float* __restrict__ bias,
                                                   float* __restrict__ C) {
  const int n0 = blockIdx.x * 128;
  const int bo = blockIdx.y * 64;
  const int b = blockIdx.z;
  float* Cb = C + (size_t)b * 524288;

  __shared__ __align__(16) char smem[30720];

  const int tid = threadIdx.x, lane = tid & 63, wv = tid >> 6;
  const int quad = lane >> 4, q16 = lane & 15, wn = wv * 32;

  const int rowA = tid >> 2, chA = (tid & 3) * 8;
  const int browB0 = tid >> 2, bchB = (tid & 3) * 8;
  const float* wA = W + (size_t)(bo + rowA) * 256 + chA;

  float4 aP0 = *(const float4*)(wA);
  float4 aP1 = *(const float4*)(wA + 4);
  uint4 oPd[2];
#pragma unroll
  for (int g = 0; g < 2; ++g) {
    const int t = n0 + browB0 + g * 64;
    const size_t rr = (size_t)(b * 4) * 2048 + t;
    oPd[g] = *(const uint4*)(opart + rr * 64 + bchB);
  }

  f32x4 acc[4][2] = {};
  int bsel = 0;
  for (int k0 = 0; k0 < 256; k0 += 32) {
    char* const Ab = smem + bsel;
    char* const Bb = smem + bsel + 5120;
    {
      union { uint4 u; __bf16 h[8]; } pa;
      pa.h[0] = (__bf16)aP0.x; pa.h[1] = (__bf16)aP0.y;
      pa.h[2] = (__bf16)aP0.z; pa.h[3] = (__bf16)aP0.w;
      pa.h[4] = (__bf16)aP1.x; pa.h[5] = (__bf16)aP1.y;
      pa.h[6] = (__bf16)aP1.z; pa.h[7] = (__bf16)aP1.w;
      *(uint4*)(Ab + rowA * 80 + chA * 2) = pa.u;
      *(uint4*)(Bb + browB0 * 80 + bchB * 2) = oPd[0];
      *(uint4*)(Bb + (browB0 + 64) * 80 + bchB * 2) = oPd[1];
    }
    __syncthreads();
    if (k0 + 32 < 256) {
      const int kn = k0 + 32;
      aP0 = *(const float4*)(wA + kn);
      aP1 = *(const float4*)(wA + kn + 4);
      const int c = kn + bchB;
      const int hd = c >> 6, cu = c & 63;
#pragma unroll
      for (int g = 0; g < 2; ++g) {
        const int t = n0 + browB0 + g * 64;
        const size_t rr = (size_t)(b * 4 + hd) * 2048 + t;
        oPd[g] = *(const uint4*)(opart + rr * 64 + cu);
      }
    }
    bf16x8 af[4], bfr[2];
#pragma unroll
    for (int mt = 0; mt < 4; ++mt)
      af[mt] = *(const bf16x8*)(Ab + (mt * 16 + q16) * 80 + quad * 16);
#pragma unroll
    for (int jn = 0; jn < 2; ++jn)
      bfr[jn] = *(const bf16x8*)(Bb + (wn + jn * 16 + q16) * 80 + quad * 16);
#pragma unroll
    for (int mt = 0; mt < 4; ++mt)
#pragma unroll
      for (int jn = 0; jn < 2; ++jn)
        acc[mt][jn] = __builtin_amdgcn_mfma_f32_16x16x32_bf16(af[mt], bfr[jn], acc[mt][jn], 0, 0, 0);
    bsel ^= 15360;
  }

#pragma unroll
  for (int mt = 0; mt < 4; ++mt)
#pragma unroll
    for (int r = 0; r < 4; ++r) {
      const int o = bo + mt * 16 + quad * 4 + r;
      const float bv = bias[o];
#pragma unroll
      for (int jn = 0; jn < 2; ++jn)
        Cb[(size_t)o * 2048 + n0 + wn + jn * 16 + q16] = acc[mt][jn][r] + bv;
    }
}

// ---------------------------------------------------------------------------
// Kernel 7: inverse FFT2 via split-bf16 MFMA. One slice per wave; r22 form.
// ---------------------------------------------------------------------------
__global__ __launch_bounds__(256) void k_ifft2(const float* __restrict__ spec,
                                               float* __restrict__ out) {
  __shared__ __align__(16) char smem[51200];
  const int tid = threadIdx.x, lane = tid & 63, wv = tid >> 6;
  const int quad = lane >> 4, q16 = lane & 15;
  const int slice = blockIdx.x * 4 + wv;
  char* const wr_ = smem + 10240 + wv * 10240;

  // early spec global loads
  const float* sp = spec + (size_t)slice * 2048;
  float4 sv8[8];
#pragma unroll
  for (int u = 0; u < 8; ++u) sv8[u] = ((const float4*)sp)[u * 64 + lane];

  build_twiddle_lds(smem, tid);

#pragma unroll
  for (int u = 0; u < 8; ++u) {
    const int f = u * 64 + lane;  // 0..511 float4 (2 complex each)
    const float4 v = sv8[u];
    const int k1 = f >> 4, k2 = (f & 15) * 2;
    char* base = wr_ + k1 * 80 + k2 * 2;
    union { unsigned int w; __bf16 b[2]; } p;
    const __bf16 rh0 = (__bf16)v.x, rh1 = (__bf16)v.z;
    const __bf16 ih0 = (__bf16)v.y, ih1 = (__bf16)v.w;
    p.b[0] = rh0; p.b[1] = rh1; *(unsigned int*)(base) = p.w;
    p.b[0] = (__bf16)(v.x - (float)rh0);
    p.b[1] = (__bf16)(v.z - (float)rh1); *(unsigned int*)(base + 2560) = p.w;
    p.b[0] = ih0; p.b[1] = ih1; *(unsigned int*)(base + 5120) = p.w;
    p.b[0] = (__bf16)(v.y - (float)ih0);
    p.b[1] = (__bf16)(v.w - (float)ih1); *(unsigned int*)(base + 7680) = p.w;
  }
  __syncthreads();  // tables visible; X same-wave ordered

  bf16x8 cch[2], ccl[2], ssh[2], ssl[2], ssnh[2], ssnl[2];
  bf16x8 xreh[2], xrel[2], ximh[2], ximl[2];
#pragma unroll
  for (int t2 = 0; t2 < 2; ++t2) {
    const int row = t2 * 16 + q16;
    cch[t2] = *(const bf16x8*)(smem + row * 80 + quad * 16);
    ccl[t2] = *(const bf16x8*)(smem + 2560 + row * 80 + quad * 16);
    ssh[t2] = *(const bf16x8*)(smem + 5120 + row * 80 + quad * 16);
    ssl[t2] = *(const bf16x8*)(smem + 7680 + row * 80 + quad * 16);
    xreh[t2] = *(const bf16x8*)(wr_ + row * 80 + quad * 16);
    xrel[t2] = *(const bf16x8*)(wr_ + 2560 + row * 80 + quad * 16);
    ximh[t2] = *(const bf16x8*)(wr_ + 5120 + row * 80 + quad * 16);
    ximl[t2] = *(const bf16x8*)(wr_ + 7680 + row * 80 + quad * 16);
  }
  ssnh[0] = neg8(ssh[0]); ssnh[1] = neg8(ssh[1]);
  ssnl[0] = neg8(ssl[0]); ssnl[1] = neg8(ssl[1]);

  // pass 1
  f32x4 yre[2][2] = {}, yim[2][2] = {};
#pragma unroll
  for (int mt = 0; mt < 2; ++mt)
#pragma unroll
    for (int nt = 0; nt < 2; ++nt) {
      MFMA3(yre[mt][nt], xreh[mt], xrel[mt], cch[nt], ccl[nt]);
      MFMA3(yre[mt][nt], ximh[mt], ximl[mt], ssnh[nt], ssnl[nt]);
      MFMA3(yim[mt][nt], xreh[mt], xrel[mt], ssh[nt], ssl[nt]);
      MFMA3(yim[mt][nt], ximh[mt], ximl[mt], cch[nt], ccl[nt]);
    }

  // write Yt transposed + split over the X regions (wave-private)
#pragma unroll
  for (int mt = 0; mt < 2; ++mt)
#pragma unroll
    for (int nt = 0; nt < 2; ++nt) {
      char* base = wr_ + (nt * 16 + q16) * 80 + (mt * 16 + quad * 4) * 2;
      union { unsigned long long q; __bf16 b[4]; } h, l;
#pragma unroll
      for (int r = 0; r < 4; ++r) {
        const float v = yre[mt][nt][r];
        h.b[r] = (__bf16)v; l.b[r] = (__bf16)(v - (float)h.b[r]);
      }
      *(unsigned long long*)(base) = h.q;
      *(unsigned long long*)(base + 2560) = l.q;
#pragma unroll
      for (int r = 0; r < 4; ++r) {
        const float v = yim[mt][nt][r];
        h.b[r] = (__bf16)v; l.b[r] = (__bf16)(v - (float)h.b[r]);
      }
      *(unsigned long long*)(base + 5120) = h.q;
      *(unsigned long long*)(base + 7680) = l.q;
    }
  asm volatile("" ::: "memory");

  bf16x8 yreh[2], yrel[2], yimh[2], yiml[2];
#pragma unroll
  for (int nt = 0; nt < 2; ++nt) {
    const int row = nt * 16 + q16;
    yreh[nt] = *(const bf16x8*)(wr_ + row * 80 + quad * 16);
    yrel[nt] = *(const bf16x8*)(wr_ + 2560 + row * 80 + quad * 16);
    yimh[nt] = *(const bf16x8*)(wr_ + 5120 + row * 80 + quad * 16);
    yiml[nt] = *(const bf16x8*)(wr_ + 7680 + row * 80 + quad * 16);
  }

  // pass 2
  f32x4 zre[2][2] = {}, zim[2][2] = {};
#pragma unroll
  for (int mt = 0; mt < 2; ++mt)
#pragma unroll
    for (int nt = 0; nt < 2; ++nt) {
      MFMA3(zre[mt][nt], cch[mt], ccl[mt], yreh[nt], yrel[nt]);
      MFMA3(zre[mt][nt], ssnh[mt], ssnl[mt], yimh[nt], yiml[nt]);
      MFMA3(zim[mt][nt], cch[mt], ccl[mt], yimh[nt], yiml[nt]);
      MFMA3(zim[mt][nt], ssh[mt], ssl[mt], yreh[nt], yrel[nt]);
    }

  float* op = out + (size_t)slice * 2048;
#pragma unroll
  for (int mt = 0; mt < 2; ++mt)
#pragma unroll
    for (int nt = 0; nt < 2; ++nt)
#pragma unroll
      for (int r = 0; r < 4; ++r) {
        const int n1 = mt * 16 + quad * 4 + r;
        const int n2 = nt * 16 + q16;
        float2 st;
        st.x = zre[mt][nt][r] * (1.0f / 1024.0f);
        st.y = zim[mt][nt][r] * (1.0f / 1024.0f);
        *(float2*)(op + 2 * (n1 * 32 + n2)) = st;
      }
}

// ---------------------------------------------------------------------------
extern "C" void kernel_launch(void* const* d_in, const int* in_sizes, int n_in,
                              void* d_out, int out_size, void* d_ws, size_t ws_size,
                              hipStream_t stream) {
  (void)in_sizes; (void)n_in; (void)out_size; (void)ws_size;
  const float* x      = (const float*)d_in[0];
  const float* gn_w   = (const float*)d_in[1];
  const float* gn_b   = (const float*)d_in[2];
  const float* qkv_w  = (const float*)d_in[3];
  const float* qkv_b  = (const float*)d_in[4];
  const float* proj_w = (const float*)d_in[5];
  const float* proj_b = (const float*)d_in[6];
  float* out = (float*)d_out;

  float* spec  = (float*)d_ws;
  __bf16* Qt   = (__bf16*)(spec + 4194304);   // 4194304 elems
  __bf16* Kt   = Qt + 4194304;                // 2359296 elems (32*1152*64)
  __bf16* Vt   = Kt + 2359296;                // 2359296 elems
  float* xr    = (float*)(Vt + 2359296) + 512; // 512-float hole (old stats slot)
  __bf16* xt   = (__bf16*)(xr + 4194304);     // 4194304 bf16
  __bf16* opart = (__bf16*)xr;                // 4194304 bf16 (clobbers xr; single-part)
  float*  dq    = (float*)(opart + 12582912); // 65536 (offset kept from 3-part era)
  float*  uk    = dq + 65536;                 // 2048
  float*  uv    = uk + 2048;                  // 2048
  float*  stats_part = uv + 2048;             // 4096 floats (256 bg x 8 sub x 2)

  k_fft2<<<512, 256, 0, stream>>>(x, xr, stats_part);
  k_gnuv<<<1088, 256, 0, stream>>>(xr, stats_part, gn_w, gn_b, qkv_w, qkv_b,
                                   xt, uk, uv);
  k_gemm_qkv<<<dim3(136, 8), 256, 0, stream>>>(qkv_w, xt, qkv_b, uk, dq,
                                               Qt, Kt, Vt);
  k_attn_mfma<<<dim3(16, 32), 256, 0, stream>>>(Qt, Kt, Vt, dq, uv, opart);
  k_gemm_proj<<<dim3(16, 4, 8), 256, 0, stream>>>(proj_w, opart, proj_b, spec);
  k_ifft2<<<512, 256, 0, stream>>>(spec, out);
}

// Round 10
// 153.460 us; speedup vs baseline: 1.2452x; 1.0043x over previous
//
#include <hip/hip_runtime.h>
#include <hip/hip_bf16.h>
#include <stdint.h>

#define PI_F 3.14159265358979323846f
#define C1_EXP 0.18033688f   // log2(e)/8
#define C2_EXP 23.083120f    // 16*log2(e)

typedef __bf16 bf16x8 __attribute__((ext_vector_type(8)));
typedef float f32x4 __attribute__((ext_vector_type(4)));
typedef unsigned int uint32x4 __attribute__((ext_vector_type(4)));

// LDS-only barrier: s_barrier with lgkmcnt drain but NO vmcnt drain, so
// in-flight global prefetch loads survive across the barrier (T4-minimal).
// Proven +3us on attn in r20.
#define BAR_LDS() asm volatile("s_waitcnt lgkmcnt(0)\n\ts_barrier" ::: "memory")

__device__ __forceinline__ bf16x8 neg8(bf16x8 v) {
  union { bf16x8 b; uint32x4 u; } x;
  x.b = v;
  x.u ^= (uint32x4){0x80008000u, 0x80008000u, 0x80008000u, 0x80008000u};
  return x.b;
}

// 3-term split-accumulate: P*Q with P=Ph+Pl, Q=Qh+Ql (drop Pl*Ql ~2^-18)
#define MFMA3(acc, Ph, Pl, Qh, Ql)                                        \
  acc = __builtin_amdgcn_mfma_f32_16x16x32_bf16(Ph, Qh, acc, 0, 0, 0);    \
  acc = __builtin_amdgcn_mfma_f32_16x16x32_bf16(Ph, Ql, acc, 0, 0, 0);    \
  acc = __builtin_amdgcn_mfma_f32_16x16x32_bf16(Pl, Qh, acc, 0, 0, 0);

// Closed-form base-slot -> original column mapping.
__device__ __forceinline__ int slot2n(int slot) {
  const int pi = slot >> 1, im = slot & 1;
  int k1, k2;
  if (pi < 480)      { k1 = 1 + (pi >> 5); k2 = pi & 31; }
  else if (pi < 495) { k1 = 0;  k2 = pi - 479; }
  else if (pi < 510) { k1 = 16; k2 = pi - 494; }
  else if (pi < 514) { k1 = ((pi - 510) >> 1) * 16; k2 = ((pi - 510) & 1) * 16; }
  else               { k1 = 0; k2 = 0; }
  return 2 * (k1 * 32 + k2) + im;
}

// Inline twiddle-table build (r22: replaces k_twid kernel + global staging).
__device__ __forceinline__ void build_twiddle_lds(char* smem, int tid) {
  for (int e = tid; e < 1024; e += 256) {
    const int j = e >> 5, k = e & 31;
    const int t = (j * k) & 31;
    float sv, cv;
    sincosf(2.0f * PI_F * (float)t / 32.0f, &sv, &cv);
    const __bf16 ch = (__bf16)cv, sh = (__bf16)sv;
    *(__bf16*)(smem + j * 80 + k * 2) = ch;
    *(__bf16*)(smem + 2560 + j * 80 + k * 2) = (__bf16)(cv - (float)ch);
    *(__bf16*)(smem + 5120 + j * 80 + k * 2) = sh;
    *(__bf16*)(smem + 7680 + j * 80 + k * 2) = (__bf16)(sv - (float)sh);
  }
}

// ---------------------------------------------------------------------------
// Kernel 1: forward FFT2 via split-bf16 MFMA. One slice per wave; r22 form.
// ---------------------------------------------------------------------------
__global__ __launch_bounds__(256) void k_fft2(const float* __restrict__ x,
                                              float* __restrict__ xr,
                                              float* __restrict__ stats_part) {
  __shared__ __align__(16) char smem[51200];
  const int tid = threadIdx.x, lane = tid & 63, wv = tid >> 6;
  const int quad = lane >> 4, q16 = lane & 15;
  const int slice = blockIdx.x * 4 + wv;
  char* const wr_ = smem + 10240 + wv * 10240;

  // early X global loads (wave-private region; overlap with table build)
  const float* xs = x + (size_t)slice * 1024;
  float4 xv[4];
#pragma unroll
  for (int u = 0; u < 4; ++u) xv[u] = ((const float4*)xs)[u * 64 + lane];

  build_twiddle_lds(smem, tid);

  // X split + stage (same-wave ds ordering)
#pragma unroll
  for (int u = 0; u < 4; ++u) {
    const int f = u * 64 + lane;
    const float4 v = xv[u];
    const int row = f >> 3, c4 = (f & 7) * 4;
    union { unsigned long long q; __bf16 b[4]; } ph, pl;
    ph.b[0] = (__bf16)v.x; ph.b[1] = (__bf16)v.y;
    ph.b[2] = (__bf16)v.z; ph.b[3] = (__bf16)v.w;
    pl.b[0] = (__bf16)(v.x - (float)ph.b[0]);
    pl.b[1] = (__bf16)(v.y - (float)ph.b[1]);
    pl.b[2] = (__bf16)(v.z - (float)ph.b[2]);
    pl.b[3] = (__bf16)(v.w - (float)ph.b[3]);
    *(unsigned long long*)(wr_ + row * 80 + c4 * 2) = ph.q;
    *(unsigned long long*)(wr_ + 2560 + row * 80 + c4 * 2) = pl.q;
  }
  __syncthreads();  // tables visible to all waves; X same-wave ordered

  bf16x8 cch[2], ccl[2], ssh[2], ssl[2], xh[2], xl[2];
#pragma unroll
  for (int t2 = 0; t2 < 2; ++t2) {
    const int row = t2 * 16 + q16;
    cch[t2] = *(const bf16x8*)(smem + row * 80 + quad * 16);
    ccl[t2] = *(const bf16x8*)(smem + 2560 + row * 80 + quad * 16);
    ssh[t2] = *(const bf16x8*)(smem + 5120 + row * 80 + quad * 16);
    ssl[t2] = *(const bf16x8*)(smem + 7680 + row * 80 + quad * 16);
    xh[t2] = *(const bf16x8*)(wr_ + row * 80 + quad * 16);
    xl[t2] = *(const bf16x8*)(wr_ + 2560 + row * 80 + quad * 16);
  }

  // pass 1: Yre = X@Cc, Yim = -(X@Ss)
  f32x4 yre[2][2] = {}, yim[2][2] = {};
#pragma unroll
  for (int mt = 0; mt < 2; ++mt)
#pragma unroll
    for (int nt = 0; nt < 2; ++nt) {
      MFMA3(yre[mt][nt], xh[mt], xl[mt], cch[nt], ccl[nt]);
      MFMA3(yim[mt][nt], xh[mt], xl[mt], ssh[nt], ssl[nt]);
    }

  // write Yt transposed + split (wave-private; same-wave ordering)
#pragma unroll
  for (int mt = 0; mt < 2; ++mt)
#pragma unroll
    for (int nt = 0; nt < 2; ++nt) {
      char* base = wr_ + (nt * 16 + q16) * 80 + (mt * 16 + quad * 4) * 2;
      union { unsigned long long q; __bf16 b[4]; } h, l;
#pragma unroll
      for (int r = 0; r < 4; ++r) {
        const float v = yre[mt][nt][r];
        h.b[r] = (__bf16)v; l.b[r] = (__bf16)(v - (float)h.b[r]);
      }
      *(unsigned long long*)(base) = h.q;
      *(unsigned long long*)(base + 2560) = l.q;
#pragma unroll
      for (int r = 0; r < 4; ++r) {
        const float v = -yim[mt][nt][r];
        h.b[r] = (__bf16)v; l.b[r] = (__bf16)(v - (float)h.b[r]);
      }
      *(unsigned long long*)(base + 5120) = h.q;
      *(unsigned long long*)(base + 7680) = l.q;
    }
  asm volatile("" ::: "memory");

  bf16x8 yreh[2], yrel[2], yimh[2], yiml[2];
#pragma unroll
  for (int nt = 0; nt < 2; ++nt) {
    const int row = nt * 16 + q16;
    yreh[nt] = *(const bf16x8*)(wr_ + row * 80 + quad * 16);
    yrel[nt] = *(const bf16x8*)(wr_ + 2560 + row * 80 + quad * 16);
    yimh[nt] = *(const bf16x8*)(wr_ + 5120 + row * 80 + quad * 16);
    yiml[nt] = *(const bf16x8*)(wr_ + 7680 + row * 80 + quad * 16);
  }

  // pass 2: Zre = Cc@Yre + Ss@Yim ; Zim = Cc@Yim - Ss@Yre
  f32x4 zre[2][2] = {}, zim[2][2] = {};
  bf16x8 ssnh[2], ssnl[2];
  ssnh[0] = neg8(ssh[0]); ssnh[1] = neg8(ssh[1]);
  ssnl[0] = neg8(ssl[0]); ssnl[1] = neg8(ssl[1]);
#pragma unroll
  for (int mt = 0; mt < 2; ++mt)
#pragma unroll
    for (int nt = 0; nt < 2; ++nt) {
      MFMA3(zre[mt][nt], cch[mt], ccl[mt], yreh[nt], yrel[nt]);
      MFMA3(zre[mt][nt], ssh[mt], ssl[mt], yimh[nt], yiml[nt]);
      MFMA3(zim[mt][nt], cch[mt], ccl[mt], yimh[nt], yiml[nt]);
      MFMA3(zim[mt][nt], ssnh[mt], ssnl[mt], yreh[nt], yrel[nt]);
    }

  // stats + store
  float* op = xr + (size_t)slice * 2048;
  float s1 = 0.f, s2 = 0.f;
#pragma unroll
  for (int mt = 0; mt < 2; ++mt)
#pragma unroll
    for (int nt = 0; nt < 2; ++nt)
#pragma unroll
      for (int r = 0; r < 4; ++r) {
        const int k1 = mt * 16 + quad * 4 + r;
        const int k2 = nt * 16 + q16;
        const float a = zre[mt][nt][r], bimg = zim[mt][nt][r];
        s1 += a + bimg;
        s2 += a * a + bimg * bimg;
        float2 st; st.x = a; st.y = bimg;
        *(float2*)(op + 2 * (k1 * 32 + k2)) = st;
      }
#pragma unroll
  for (int off = 1; off <= 32; off <<= 1) {
    s1 += __shfl_xor(s1, off);
    s2 += __shfl_xor(s2, off);
  }
  if (lane == 0) {
    const int bg = (slice >> 8) * 32 + ((slice & 255) >> 3);
    const int sub = slice & 7;
    float2 st; st.x = s1; st.y = s2;
    *(float2*)(stats_part + (size_t)(bg * 8 + sub) * 2) = st;
  }
}

// ---------------------------------------------------------------------------
// Kernel 2+3 merged (r24): GroupNorm-apply/transpose AND mirror-correction
// vectors in ONE launch. Blocks 0..1023 = gntrans tiles; 1024..1087 = uvec.
// ---------------------------------------------------------------------------
__global__ __launch_bounds__(256) void k_gnuv(const float* __restrict__ xr,
                                              const float* __restrict__ stats_part,
                                              const float* __restrict__ gn_w,
                                              const float* __restrict__ gn_b,
                                              const float* __restrict__ qkv_w,
                                              const float* __restrict__ qkv_b,
                                              __bf16* __restrict__ xt,
                                              float* __restrict__ uk,
                                              float* __restrict__ uv) {
  const int bid = blockIdx.x;
  const int tid = threadIdx.x;
  if (bid >= 1024) {
    // ---- uvec body (identical arithmetic to old k_uvec) ----
    const int blk = bid - 1024;
    const int b = blk >> 3, h = (blk >> 1) & 3, role = blk & 1;
    __shared__ float Bsh[256];
    {
      const int g = tid >> 3;
      float S = 0.f, S2 = 0.f;
#pragma unroll
      for (int s = 0; s < 8; ++s) {
        S  += stats_part[((b * 32 + g) * 8 + s) * 2];
        S2 += stats_part[((b * 32 + g) * 8 + s) * 2 + 1];
      }
      const float mean = S * (1.0f / 16384.0f);
      const float var = S2 * (1.0f / 16384.0f) - mean * mean;
      const float rstd = rsqrtf(var + 1e-5f);
      Bsh[tid] = gn_b[tid] - mean * rstd * gn_w[tid];
    }
    __syncthreads();
    const int cp = tid >> 2, seg = tid & 3;
    const int row = h * 192 + 64 + role * 64 + cp;
    const float* wr_ = qkv_w + (size_t)row * 256 + seg * 64;
    const float* bs = Bsh + seg * 64;
    float s = 0.f;
#pragma unroll
    for (int i = 0; i < 16; ++i) {
      const float4 w4 = *(const float4*)(wr_ + i * 4);
      const float4 b4 = *(const float4*)(bs + i * 4);
      s += w4.x * b4.x + w4.y * b4.y + w4.z * b4.z + w4.w * b4.w;
    }
    s += __shfl_xor(s, 1);
    s += __shfl_xor(s, 2);
    if (seg == 0) {
      float* dst = (role == 0) ? uk : uv;
      dst[(size_t)(b * 4 + h) * 64 + cp] = s + qkv_b[row];
    }
    return;
  }
  // ---- gntrans body (identical arithmetic to old k_gntrans) ----
  const int n0 = (bid & 31) * 64;
  const int c0 = ((bid >> 5) & 3) * 64;
  const int b = bid >> 7;
  __shared__ __bf16 Lt[64][72];
  __shared__ float gsum[8][2];
  if (tid < 8) {
    const int g = (c0 >> 3) + tid;
    float S = 0.f, S2 = 0.f;
#pragma unroll
    for (int s = 0; s < 8; ++s) {
      S  += stats_part[((b * 32 + g) * 8 + s) * 2];
      S2 += stats_part[((b * 32 + g) * 8 + s) * 2 + 1];
    }
    gsum[tid][0] = S;
    gsum[tid][1] = S2;
  }
  __syncthreads();
  for (int i = tid; i < 1024; i += 256) {
    const int cl = i >> 4, c = c0 + cl, nl = (i & 15) * 4;
    const float S = gsum[cl >> 3][0];
    const float S2 = gsum[cl >> 3][1];
    const float mean = S * (1.0f / 16384.0f);
    const float var = S2 * (1.0f / 16384.0f) - mean * mean;
    const float rstd = rsqrtf(var + 1e-5f);
    const float sc = rstd * gn_w[c];
    const float sh = gn_b[c] - mean * sc;
    const float4 v = *(const float4*)(xr + ((size_t)b * 256 + c) * 2048 + n0 + nl);
    Lt[nl][cl] = (__bf16)(v.x * sc + sh);
    Lt[nl + 1][cl] = (__bf16)(v.y * sc + sh);
    Lt[nl + 2][cl] = (__bf16)(v.z * sc + sh);
    Lt[nl + 3][cl] = (__bf16)(v.w * sc + sh);
  }
  __syncthreads();
  __bf16* dst = xt + (size_t)b * 524288 + (size_t)n0 * 256 + c0;
  for (int i = tid; i < 512; i += 256) {
    const int nl = i >> 3, cch = (i & 7) * 8;
    *(uint4*)(dst + (size_t)nl * 256 + cch) = *(const uint4*)&Lt[nl][cch];
  }
}

// ---------------------------------------------------------------------------
// Kernel 4: QKV GEMM (bf16 MFMA), double-buffered LDS; unchanged.
// ---------------------------------------------------------------------------
__global__ __launch_bounds__(256) void k_gemm_qkv(const float* __restrict__ W,
                                                  const __bf16* __restrict__ X,
                                                  const float* __restrict__ bias,
                                                  const float* __restrict__ uk,
                                                  float* __restrict__ dq,
                                                  __bf16* __restrict__ Qt,
                                                  __bf16* __restrict__ Kt,
                                                  __bf16* __restrict__ Vt) {
  const int tx = blockIdx.x;
  const int b = blockIdx.y;
  int role, hd, nt;
  if (tx < 64) { role = 0; hd = tx >> 4; nt = tx & 15; }
  else if (tx < 100) { role = 1; const int i = tx - 64; hd = i / 9; nt = i - hd * 9; }
  else { role = 2; const int i = tx - 100; hd = i / 9; nt = i - hd * 9; }
  const int n0 = nt * 128;
  const int bo = hd * 192 + role * 64;
  const __bf16* Xb = X + (size_t)b * 524288;

  __shared__ __align__(16) char smem[30720];
  __bf16 (*Ot)[72] = (__bf16(*)[72])smem;
  __bf16 (*Ot2)[136] = (__bf16(*)[136])smem;

  const int tid = threadIdx.x, lane = tid & 63, wv = tid >> 6;
  const int quad = lane >> 4, q16 = lane & 15, wn = wv * 32;

  const int rowA = tid >> 2, chA = (tid & 3) * 8;
  const int browB0 = tid >> 2, bchB = (tid & 3) * 8;
  const float* wA = W + (size_t)(bo + rowA) * 256 + chA;

  const int s0r = n0 + browB0, s1r = n0 + browB0 + 64;
  const int pn0 = (role == 0) ? s0r : slot2n(s0r);
  const int pn1 = (role == 0) ? s1r : slot2n(s1r);

  float4 aP0 = *(const float4*)(wA);
  float4 aP1 = *(const float4*)(wA + 4);
  uint4 bP0 = *(const uint4*)(Xb + (size_t)pn0 * 256 + bchB);
  uint4 bP1 = *(const uint4*)(Xb + (size_t)pn1 * 256 + bchB);

  f32x4 acc[4][2] = {};
  int bsel = 0;
  for (int k0 = 0; k0 < 256; k0 += 32) {
    char* const Ab = smem + bsel;
    char* const Bb = smem + bsel + 5120;
    {
      union { uint4 u; __bf16 h[8]; } pa;
      pa.h[0] = (__bf16)aP0.x; pa.h[1] = (__bf16)aP0.y;
      pa.h[2] = (__bf16)aP0.z; pa.h[3] = (__bf16)aP0.w;
      pa.h[4] = (__bf16)aP1.x; pa.h[5] = (__bf16)aP1.y;
      pa.h[6] = (__bf16)aP1.z; pa.h[7] = (__bf16)aP1.w;
      *(uint4*)(Ab + rowA * 80 + chA * 2) = pa.u;
      *(uint4*)(Bb + browB0 * 80 + bchB * 2) = bP0;
      *(uint4*)(Bb + (browB0 + 64) * 80 + bchB * 2) = bP1;
    }
    __syncthreads();
    if (k0 + 32 < 256) {
      const int kn = k0 + 32;
      aP0 = *(const float4*)(wA + kn);
      aP1 = *(const float4*)(wA + kn + 4);
      bP0 = *(const uint4*)(Xb + (size_t)pn0 * 256 + kn + bchB);
      bP1 = *(const uint4*)(Xb + (size_t)pn1 * 256 + kn + bchB);
    }
    bf16x8 af[4], bfr[2];
#pragma unroll
    for (int mt = 0; mt < 4; ++mt)
      af[mt] = *(const bf16x8*)(Ab + (mt * 16 + q16) * 80 + quad * 16);
#pragma unroll
    for (int jn = 0; jn < 2; ++jn)
      bfr[jn] = *(const bf16x8*)(Bb + (wn + jn * 16 + q16) * 80 + quad * 16);
#pragma unroll
    for (int mt = 0; mt < 4; ++mt)
#pragma unroll
      for (int jn = 0; jn < 2; ++jn)
        acc[mt][jn] = __builtin_amdgcn_mfma_f32_16x16x32_bf16(af[mt], bfr[jn], acc[mt][jn], 0, 0, 0);
    bsel ^= 15360;
  }
  __syncthreads();

  const int bh = b * 4 + hd;
  if (role == 2) {
#pragma unroll
    for (int mt = 0; mt < 4; ++mt)
#pragma unroll
      for (int r = 0; r < 4; ++r) {
        const int c = mt * 16 + quad * 4 + r;
        const float bv = bias[bo + c];
#pragma unroll
        for (int jn = 0; jn < 2; ++jn)
          Ot2[c][wn + jn * 16 + q16] = (__bf16)(acc[mt][jn][r] + bv);
      }
    __syncthreads();
    __bf16* dst = Vt + (size_t)bh * 73728;  // [c][1152]
    for (int i = tid; i < 1024; i += 256) {
      const int c = i >> 4, sg = (i & 15) * 8;
      *(uint4*)(dst + (size_t)c * 1152 + n0 + sg) = *(const uint4*)&Ot2[c][sg];
    }
  } else {
    __bf16* dst = (role == 0 ? Qt + (size_t)bh * 131072
                             : Kt + (size_t)bh * 73728);  // [n][64]
#pragma unroll
    for (int mt = 0; mt < 4; ++mt)
#pragma unroll
      for (int r = 0; r < 4; ++r) {
        const int c = mt * 16 + quad * 4 + r;
        const float bv = bias[bo + c];
#pragma unroll
        for (int jn = 0; jn < 2; ++jn)
          Ot[wn + jn * 16 + q16][c] = (__bf16)(acc[mt][jn][r] + bv);
      }
    __syncthreads();
    for (int i = tid; i < 1024; i += 256) {
      const int nl = i >> 3, cch = (i & 7) * 8;
      *(uint4*)(dst + (size_t)(n0 + nl) * 64 + cch) = *(const uint4*)&Ot[nl][cch];
    }
    if (role == 0 && tid < 128) {
      const float* ukp = uk + (size_t)bh * 64;
      float dv = 0.f;
#pragma unroll
      for (int g8 = 0; g8 < 8; ++g8) {
        const bf16x8 qv = *(const bf16x8*)&Ot[tid][g8 * 8];
#pragma unroll
        for (int k = 0; k < 8; ++k) dv += (float)qv[k] * ukp[g8 * 8 + k];
      }
      dq[(size_t)bh * 2048 + n0 + tid] = dv * (2.0f * C1_EXP);
    }
  }
}

// ---------------------------------------------------------------------------
// Kernel 5: MFMA flash attention. r25: KVBLK=128 — stage 4x4KB K-halves +
// 4x4KB V-halves per barrier pair (OFF in {0,4096,8192,12288} folded into
// ds offsets), run the proven 32-slot body 4x between barriers. Barriers
// 36 -> 18. launch_bounds(256,2): grid is 512 blocks = 2 blocks/CU
// (grid-limited), so the relaxed VGPR cap (256) costs no occupancy and
// removes spill pressure from the 8 in-flight prefetch uint4s.
// LDS: K 16K @0 + V 16K @16384 + P 8K @32768 = 40960 B.
// ---------------------------------------------------------------------------
template <bool EDGE, int OFF>
__device__ __forceinline__ void attn_half(
    const int s0, const int quad,
    const char* const (&krp)[2][2], const char* const (&vrp)[4],
    char* const (&pwp)[2][2], const char* const (&prp)[2],
    const bf16x8 (&bq)[2][2], const float (&Dm)[2],
    f32x4 (&oacc)[2][4], float (&lsum)[2], float (&spsum)[2]) {
  f32x4 sacc[2][2] = {};
#pragma unroll
  for (int j = 0; j < 2; ++j)
#pragma unroll
    for (int kk = 0; kk < 2; ++kk) {
      const bf16x8 ak = *(const bf16x8*)(krp[j][kk] + OFF);
      sacc[0][j] = __builtin_amdgcn_mfma_f32_16x16x32_bf16(ak, bq[0][kk], sacc[0][j], 0, 0, 0);
      sacc[1][j] = __builtin_amdgcn_mfma_f32_16x16x32_bf16(ak, bq[1][kk], sacc[1][j], 0, 0, 0);
    }

#pragma unroll
  for (int b = 0; b < 2; ++b) {
    float lacc = 0.f, spacc = 0.f;
#pragma unroll
    for (int j = 0; j < 2; ++j) {
      float B0, B2, Bv1, Bv3, Bm1, Bm3;
      if (EDGE) {
        const int sg = s0 + j * 16 + quad * 4;
        B0 = (sg < 1020) ? (1.0f - C2_EXP) : ((sg < 1028) ? -C2_EXP : -1e30f);
        B2 = (sg + 2 < 1020) ? (1.0f - C2_EXP)
                             : ((sg + 2 < 1028) ? -C2_EXP : -1e30f);
        Bv1 = (sg + 1 < 1028) ? -C2_EXP : -1e30f;
        Bv3 = (sg + 3 < 1028) ? -C2_EXP : -1e30f;
        Bm1 = (sg + 1 < 1020) ? Dm[b] : -1e30f;
        Bm3 = (sg + 3 < 1020) ? Dm[b] : -1e30f;
      } else {
        B0 = 1.0f - C2_EXP;
        B2 = 1.0f - C2_EXP;
        Bv1 = -C2_EXP;
        Bv3 = -C2_EXP;
        Bm1 = Dm[b];
        Bm3 = Dm[b];
      }
      const float P0  = __builtin_amdgcn_exp2f(fmaf(sacc[b][j][0],  C1_EXP, B0));
      const float Pv1 = __builtin_amdgcn_exp2f(fmaf(sacc[b][j][1],  C1_EXP, Bv1));
      const float P2  = __builtin_amdgcn_exp2f(fmaf(sacc[b][j][2],  C1_EXP, B2));
      const float Pv3 = __builtin_amdgcn_exp2f(fmaf(sacc[b][j][3],  C1_EXP, Bv3));
      const float pm1 = __builtin_amdgcn_exp2f(fmaf(sacc[b][j][1], -C1_EXP, Bm1));
      const float pm3 = __builtin_amdgcn_exp2f(fmaf(sacc[b][j][3], -C1_EXP, Bm3));
      const float mm = pm1 + pm3;
      lacc += (P0 + P2) + (Pv1 + Pv3) + mm;
      spacc += mm;
      union { uint2 u; __bf16 h[4]; } pk;
      pk.h[0] = (__bf16)P0;
      pk.h[1] = (__bf16)(Pv1 - pm1);
      pk.h[2] = (__bf16)P2;
      pk.h[3] = (__bf16)(Pv3 - pm3);
      *(uint2*)pwp[b][j] = pk.u;
    }
    lsum[b] += lacc;
    spsum[b] += spacc;
  }
  asm volatile("" ::: "memory");

  bf16x8 bp[2];
  bp[0] = *(const bf16x8*)prp[0];
  bp[1] = *(const bf16x8*)prp[1];
#pragma unroll
  for (int jc = 0; jc < 4; ++jc) {
    const bf16x8 av = *(const bf16x8*)(vrp[jc] + OFF);
    oacc[0][jc] = __builtin_amdgcn_mfma_f32_16x16x32_bf16(av, bp[0], oacc[0][jc], 0, 0, 0);
    oacc[1][jc] = __builtin_amdgcn_mfma_f32_16x16x32_bf16(av, bp[1], oacc[1][jc], 0, 0, 0);
  }
}

__global__ __launch_bounds__(256, 2) void k_attn_mfma(const __bf16* __restrict__ Qt,
                                                      const __bf16* __restrict__ Kt,
                                                      const __bf16* __restrict__ Vt,
                                                      const float* __restrict__ dq,
                                                      const float* __restrict__ uv,
                                                      __bf16* __restrict__ opart) {
  const int t0 = blockIdx.x * 128;
  const int bh = blockIdx.y;
  const __bf16* kt = Kt + (size_t)bh * 73728;
  const __bf16* vt = Vt + (size_t)bh * 73728;

  __shared__ __align__(16) char smem[40960];

  const int tid = threadIdx.x, lane = tid & 63, wv = tid >> 6;
  const int quad = lane >> 4, q16 = lane & 15;
  const int wband = wv * 32;

  const int rK = tid >> 3, gK = tid & 7;
  char* const kw = smem + rK * 128 + ((gK ^ (rK & 7)) * 16);
  const int cV = tid >> 2, gV = tid & 3;
  char* const vw = smem + 16384 + (cV >> 1) * 128 +
                   ((((cV & 1) * 4 + gV) ^ ((cV >> 1) & 7)) * 16);
  const __bf16* const kg = kt + (size_t)rK * 64 + gK * 8;
  const __bf16* const vg = vt + (size_t)cV * 1152 + gV * 8;

  const char* krp[2][2];
#pragma unroll
  for (int j = 0; j < 2; ++j)
#pragma unroll
    for (int kk = 0; kk < 2; ++kk)
      krp[j][kk] = smem + (j * 16 + q16) * 128 + (((kk * 4 + quad) ^ (q16 & 7)) * 16);
  const int a7 = (q16 >> 1) & 7, p1 = q16 & 1;
  const char* vrp[4];
#pragma unroll
  for (int jc = 0; jc < 4; ++jc)
    vrp[jc] = smem + 16384 + (jc * 8 + (q16 >> 1)) * 128 +
              (((p1 * 4 + quad) ^ a7) * 16);
  char* pwp[2][2];
  const char* prp[2];
#pragma unroll
  for (int b = 0; b < 2; ++b) {
    const int mrow = ((wband + b * 16) >> 1) + (q16 >> 1);
    prp[b] = smem + 32768 + mrow * 128 + (((p1 * 4 + quad) ^ a7) * 16);
#pragma unroll
    for (int j = 0; j < 2; ++j)
      pwp[b][j] = smem + 32768 + mrow * 128 +
                  (((p1 * 4 + j * 2 + (quad >> 1)) ^ a7) * 16) + (quad & 1) * 8;
  }

  const __bf16* qbase = Qt + (size_t)bh * 131072;
  bf16x8 bq[2][2];
  float Dm[2];
#pragma unroll
  for (int b = 0; b < 2; ++b) {
    const int t = t0 + wband + b * 16 + q16;
    const __bf16* qp = qbase + (size_t)t * 64 + quad * 8;
    bq[b][0] = *(const bf16x8*)qp;
    bq[b][1] = *(const bf16x8*)(qp + 32);
    Dm[b] = dq[(size_t)bh * 2048 + t] - C2_EXP;
  }

  f32x4 oacc[2][4] = {};
  float lsum[2] = {0.f, 0.f};
  float spsum[2] = {0.f, 0.f};

  // 1056 slots = 7 x quad(128) [0..895] + quad(128) with edge last half
  // [896..1023] + single(32) edge [1024..1055].
  uint4 kA0 = *(const uint4*)(kg);
  uint4 kA1 = *(const uint4*)(kg + (size_t)32 * 64);
  uint4 kA2 = *(const uint4*)(kg + (size_t)64 * 64);
  uint4 kA3 = *(const uint4*)(kg + (size_t)96 * 64);
  uint4 vA0 = *(const uint4*)(vg);
  uint4 vA1 = *(const uint4*)(vg + 32);
  uint4 vA2 = *(const uint4*)(vg + 64);
  uint4 vA3 = *(const uint4*)(vg + 96);

  int s0 = 0;
#pragma unroll 1
  for (int it = 0; it < 7; ++it) {
    *(uint4*)kw = kA0;
    *(uint4*)(kw + 4096) = kA1;
    *(uint4*)(kw + 8192) = kA2;
    *(uint4*)(kw + 12288) = kA3;
    *(uint4*)vw = vA0;
    *(uint4*)(vw + 4096) = vA1;
    *(uint4*)(vw + 8192) = vA2;
    *(uint4*)(vw + 12288) = vA3;
    BAR_LDS();
    kA0 = *(const uint4*)(kg + (size_t)(s0 + 128) * 64);
    kA1 = *(const uint4*)(kg + (size_t)(s0 + 160) * 64);
    kA2 = *(const uint4*)(kg + (size_t)(s0 + 192) * 64);
    kA3 = *(const uint4*)(kg + (size_t)(s0 + 224) * 64);
    vA0 = *(const uint4*)(vg + s0 + 128);
    vA1 = *(const uint4*)(vg + s0 + 160);
    vA2 = *(const uint4*)(vg + s0 + 192);
    vA3 = *(const uint4*)(vg + s0 + 224);
    attn_half<false, 0>(s0, quad, krp, vrp, pwp, prp, bq, Dm,
                        oacc, lsum, spsum);
    attn_half<false, 4096>(s0 + 32, quad, krp, vrp, pwp, prp, bq, Dm,
                           oacc, lsum, spsum);
    attn_half<false, 8192>(s0 + 64, quad, krp, vrp, pwp, prp, bq, Dm,
                           oacc, lsum, spsum);
    attn_half<false, 12288>(s0 + 96, quad, krp, vrp, pwp, prp, bq, Dm,
                            oacc, lsum, spsum);
    BAR_LDS();
    s0 += 128;
  }
  // s0 == 896; regs hold tiles 896,928,960,992.
  *(uint4*)kw = kA0;
  *(uint4*)(kw + 4096) = kA1;
  *(uint4*)(kw + 8192) = kA2;
  *(uint4*)(kw + 12288) = kA3;
  *(uint4*)vw = vA0;
  *(uint4*)(vw + 4096) = vA1;
  *(uint4*)(vw + 8192) = vA2;
  *(uint4*)(vw + 12288) = vA3;
  BAR_LDS();
  kA0 = *(const uint4*)(kg + (size_t)1024 * 64);
  vA0 = *(const uint4*)(vg + 1024);
  attn_half<false, 0>(896, quad, krp, vrp, pwp, prp, bq, Dm,
                      oacc, lsum, spsum);
  attn_half<false, 4096>(928, quad, krp, vrp, pwp, prp, bq, Dm,
                         oacc, lsum, spsum);
  attn_half<false, 8192>(960, quad, krp, vrp, pwp, prp, bq, Dm,
                         oacc, lsum, spsum);   // 960+31=991 < 1020: interior
  attn_half<true, 12288>(992, quad, krp, vrp, pwp, prp, bq, Dm,
                         oacc, lsum, spsum);
  BAR_LDS();
  // final single 32-slot tile at base offsets
  *(uint4*)kw = kA0;
  *(uint4*)vw = vA0;
  BAR_LDS();
  attn_half<true, 0>(1024, quad, krp, vrp, pwp, prp, bq, Dm,
                     oacc, lsum, spsum);

  // epilogue-only uv load (kept out of the loop-live register set)
  float4 uv4[4];
  {
    const float* uvp = uv + (size_t)bh * 64;
#pragma unroll
    for (int jc = 0; jc < 4; ++jc)
      uv4[jc] = *(const float4*)(uvp + jc * 16 + quad * 4);
  }

#pragma unroll
  for (int b = 0; b < 2; ++b) {
    float l = lsum[b], sp = spsum[b];
    l += __shfl_xor(l, 16);
    l += __shfl_xor(l, 32);
    sp += __shfl_xor(sp, 16);
    sp += __shfl_xor(sp, 32);
    const float inv = 1.0f / l;         // l complete: self-normalize
    const float su = 2.0f * sp * inv;
    const int t = t0 + wband + b * 16 + q16;
    __bf16* opp = opart + ((size_t)bh * 2048 + t) * 64;
#pragma unroll
    for (int jc = 0; jc < 4; ++jc) {
      union { uint2 u; __bf16 h[4]; } pk;
      pk.h[0] = (__bf16)(oacc[b][jc][0] * inv + su * uv4[jc].x);
      pk.h[1] = (__bf16)(oacc[b][jc][1] * inv + su * uv4[jc].y);
      pk.h[2] = (__bf16)(oacc[b][jc][2] * inv + su * uv4[jc].z);
      pk.h[3] = (__bf16)(oacc[b][jc][3] * inv + su * uv4[jc].w);
      *(uint2*)(opp + jc * 16 + quad * 4) = pk.u;
    }
  }
}

// ---------------------------------------------------------------------------
// Kernel 6: proj GEMM (bf16 MFMA), double-buffered, plain GEMM; unchanged.
// ---------------------------------------------------------------------------
__global__ __launch_bounds__(256) void k_gemm_proj(const float* __restrict__ W,
                                                   const __bf16* __restrict__ opart,
                                                   const float* __restrict__ bias,
                                                   float* __restrict__ C) {
  const int n0 = blockIdx.x * 128;
  const int bo = blockIdx.y * 64;
  const int b = blockIdx.z;
  float* Cb = C + (size_t)b * 524288;

  __shared__ __align__(16) char smem[30720];

  const int tid = threadIdx.x, lane = tid & 63, wv = tid >> 6;
  const int quad = lane >> 4, q16 = lane & 15, wn = wv * 32;

  const int rowA = tid >> 2, chA = (tid & 3) * 8;
  const int browB0 = tid >> 2, bchB = (tid & 3) * 8;
  const float* wA = W + (size_t)(bo + rowA) * 256 + chA;

  float4 aP0 = *(const float4*)(wA);
  float4 aP1 = *(const float4*)(wA + 4);
  uint4 oPd[2];
#pragma unroll
  for (int g = 0; g < 2; ++g) {
    const int t = n0 + browB0 + g * 64;
    const size_t rr = (size_t)(b * 4) * 2048 + t;
    oPd[g] = *(const uint4*)(opart + rr * 64 + bchB);
  }

  f32x4 acc[4][2] = {};
  int bsel = 0;
  for (int k0 = 0; k0 < 256; k0 += 32) {
    char* const Ab = smem + bsel;
    char* const Bb = smem + bsel + 5120;
    {
      union { uint4 u; __bf16 h[8]; } pa;
      pa.h[0] = (__bf16)aP0.x; pa.h[1] = (__bf16)aP0.y;
      pa.h[2] = (__bf16)aP0.z; pa.h[3] = (__bf16)aP0.w;
      pa.h[4] = (__bf16)aP1.x; pa.h[5] = (__bf16)aP1.y;
      pa.h[6] = (__bf16)aP1.z; pa.h[7] = (__bf16)aP1.w;
      *(uint4*)(Ab + rowA * 80 + chA * 2) = pa.u;
      *(uint4*)(Bb + browB0 * 80 + bchB * 2) = oPd[0];
      *(uint4*)(Bb + (browB0 + 64) * 80 + bchB * 2) = oPd[1];
    }
    __syncthreads();
    if (k0 + 32 < 256) {
      const int kn = k0 + 32;
      aP0 = *(const float4*)(wA + kn);
      aP1 = *(const float4*)(wA + kn + 4);
      const int c = kn + bchB;
      const int hd = c >> 6, cu = c & 63;
#pragma unroll
      for (int g = 0; g < 2; ++g) {
        const int t = n0 + browB0 + g * 64;
        const size_t rr = (size_t)(b * 4 + hd) * 2048 + t;
        oPd[g] = *(const uint4*)(opart + rr * 64 + cu);
      }
    }
    bf16x8 af[4], bfr[2];
#pragma unroll
    for (int mt = 0; mt < 4; ++mt)
      af[mt] = *(const bf16x8*)(Ab + (mt * 16 + q16) * 80 + quad * 16);
#pragma unroll
    for (int jn = 0; jn < 2; ++jn)
      bfr[jn] = *(const bf16x8*)(Bb + (wn + jn * 16 + q16) * 80 + quad * 16);
#pragma unroll
    for (int mt = 0; mt < 4; ++mt)
#pragma unroll
      for (int jn = 0; jn < 2; ++jn)
        acc[mt][jn] = __builtin_amdgcn_mfma_f32_16x16x32_bf16(af[mt], bfr[jn], acc[mt][jn], 0, 0, 0);
    bsel ^= 15360;
  }

#pragma unroll
  for (int mt = 0; mt < 4; ++mt)
#pragma unroll
    for (int r = 0; r < 4; ++r) {
      const int o = bo + mt * 16 + quad * 4 + r;
      const float bv = bias[o];
#pragma unroll
      for (int jn = 0; jn < 2; ++jn)
        Cb[(size_t)o * 2048 + n0 + wn + jn * 16 + q16] = acc[mt][jn][r] + bv;
    }
}

// ---------------------------------------------------------------------------
// Kernel 7: inverse FFT2 via split-bf16 MFMA. One slice per wave; r22 form.
// ---------------------------------------------------------------------------
__global__ __launch_bounds__(256) void k_ifft2(const float* __restrict__ spec,
                                               float* __restrict__ out) {
  __shared__ __align__(16) char smem[51200];
  const int tid = threadIdx.x, lane = tid & 63, wv = tid >> 6;
  const int quad = lane >> 4, q16 = lane & 15;
  const int slice = blockIdx.x * 4 + wv;
  char* const wr_ = smem + 10240 + wv * 10240;

  // early spec global loads
  const float* sp = spec + (size_t)slice * 2048;
  float4 sv8[8];
#pragma unroll
  for (int u = 0; u < 8; ++u) sv8[u] = ((const float4*)sp)[u * 64 + lane];

  build_twiddle_lds(smem, tid);

#pragma unroll
  for (int u = 0; u < 8; ++u) {
    const int f = u * 64 + lane;  // 0..511 float4 (2 complex each)
    const float4 v = sv8[u];
    const int k1 = f >> 4, k2 = (f & 15) * 2;
    char* base = wr_ + k1 * 80 + k2 * 2;
    union { unsigned int w; __bf16 b[2]; } p;
    const __bf16 rh0 = (__bf16)v.x, rh1 = (__bf16)v.z;
    const __bf16 ih0 = (__bf16)v.y, ih1 = (__bf16)v.w;
    p.b[0] = rh0; p.b[1] = rh1; *(unsigned int*)(base) = p.w;
    p.b[0] = (__bf16)(v.x - (float)rh0);
    p.b[1] = (__bf16)(v.z - (float)rh1); *(unsigned int*)(base + 2560) = p.w;
    p.b[0] = ih0; p.b[1] = ih1; *(unsigned int*)(base + 5120) = p.w;
    p.b[0] = (__bf16)(v.y - (float)ih0);
    p.b[1] = (__bf16)(v.w - (float)ih1); *(unsigned int*)(base + 7680) = p.w;
  }
  __syncthreads();  // tables visible; X same-wave ordered

  bf16x8 cch[2], ccl[2], ssh[2], ssl[2], ssnh[2], ssnl[2];
  bf16x8 xreh[2], xrel[2], ximh[2], ximl[2];
#pragma unroll
  for (int t2 = 0; t2 < 2; ++t2) {
    const int row = t2 * 16 + q16;
    cch[t2] = *(const bf16x8*)(smem + row * 80 + quad * 16);
    ccl[t2] = *(const bf16x8*)(smem + 2560 + row * 80 + quad * 16);
    ssh[t2] = *(const bf16x8*)(smem + 5120 + row * 80 + quad * 16);
    ssl[t2] = *(const bf16x8*)(smem + 7680 + row * 80 + quad * 16);
    xreh[t2] = *(const bf16x8*)(wr_ + row * 80 + quad * 16);
    xrel[t2] = *(const bf16x8*)(wr_ + 2560 + row * 80 + quad * 16);
    ximh[t2] = *(const bf16x8*)(wr_ + 5120 + row * 80 + quad * 16);
    ximl[t2] = *(const bf16x8*)(wr_ + 7680 + row * 80 + quad * 16);
  }
  ssnh[0] = neg8(ssh[0]); ssnh[1] = neg8(ssh[1]);
  ssnl[0] = neg8(ssl[0]); ssnl[1] = neg8(ssl[1]);

  // pass 1
  f32x4 yre[2][2] = {}, yim[2][2] = {};
#pragma unroll
  for (int mt = 0; mt < 2; ++mt)
#pragma unroll
    for (int nt = 0; nt < 2; ++nt) {
      MFMA3(yre[mt][nt], xreh[mt], xrel[mt], cch[nt], ccl[nt]);
      MFMA3(yre[mt][nt], ximh[mt], ximl[mt], ssnh[nt], ssnl[nt]);
      MFMA3(yim[mt][nt], xreh[mt], xrel[mt], ssh[nt], ssl[nt]);
      MFMA3(yim[mt][nt], ximh[mt], ximl[mt], cch[nt], ccl[nt]);
    }

  // write Yt transposed + split over the X regions (wave-private)
#pragma unroll
  for (int mt = 0; mt < 2; ++mt)
#pragma unroll
    for (int nt = 0; nt < 2; ++nt) {
      char* base = wr_ + (nt * 16 + q16) * 80 + (mt * 16 + quad * 4) * 2;
      union { unsigned long long q; __bf16 b[4]; } h, l;
#pragma unroll
      for (int r = 0; r < 4; ++r) {
        const float v = yre[mt][nt][r];
        h.b[r] = (__bf16)v; l.b[r] = (__bf16)(v - (float)h.b[r]);
      }
      *(unsigned long long*)(base) = h.q;
      *(unsigned long long*)(base + 2560) = l.q;
#pragma unroll
      for (int r = 0; r < 4; ++r) {
        const float v = yim[mt][nt][r];
        h.b[r] = (__bf16)v; l.b[r] = (__bf16)(v - (float)h.b[r]);
      }
      *(unsigned long long*)(base + 5120) = h.q;
      *(unsigned long long*)(base + 7680) = l.q;
    }
  asm volatile("" ::: "memory");

  bf16x8 yreh[2], yrel[2], yimh[2], yiml[2];
#pragma unroll
  for (int nt = 0; nt < 2; ++nt) {
    const int row = nt * 16 + q16;
    yreh[nt] = *(const bf16x8*)(wr_ + row * 80 + quad * 16);
    yrel[nt] = *(const bf16x8*)(wr_ + 2560 + row * 80 + quad * 16);
    yimh[nt] = *(const bf16x8*)(wr_ + 5120 + row * 80 + quad * 16);
    yiml[nt] = *(const bf16x8*)(wr_ + 7680 + row * 80 + quad * 16);
  }

  // pass 2
  f32x4 zre[2][2] = {}, zim[2][2] = {};
#pragma unroll
  for (int mt = 0; mt < 2; ++mt)
#pragma unroll
    for (int nt = 0; nt < 2; ++nt) {
      MFMA3(zre[mt][nt], cch[mt], ccl[mt], yreh[nt], yrel[nt]);
      MFMA3(zre[mt][nt], ssnh[mt], ssnl[mt], yimh[nt], yiml[nt]);
      MFMA3(zim[mt][nt], cch[mt], ccl[mt], yimh[nt], yiml[nt]);
      MFMA3(zim[mt][nt], ssh[mt], ssl[mt], yreh[nt], yrel[nt]);
    }

  float* op = out + (size_t)slice * 2048;
#pragma unroll
  for (int mt = 0; mt < 2; ++mt)
#pragma unroll
    for (int nt = 0; nt < 2; ++nt)
#pragma unroll
      for (int r = 0; r < 4; ++r) {
        const int n1 = mt * 16 + quad * 4 + r;
        const int n2 = nt * 16 + q16;
        float2 st;
        st.x = zre[mt][nt][r] * (1.0f / 1024.0f);
        st.y = zim[mt][nt][r] * (1.0f / 1024.0f);
        *(float2*)(op + 2 * (n1 * 32 + n2)) = st;
      }
}

// ---------------------------------------------------------------------------
extern "C" void kernel_launch(void* const* d_in, const int* in_sizes, int n_in,
                              void* d_out, int out_size, void* d_ws, size_t ws_size,
                              hipStream_t stream) {
  (void)in_sizes; (void)n_in; (void)out_size; (void)ws_size;
  const float* x      = (const float*)d_in[0];
  const float* gn_w   = (const float*)d_in[1];
  const float* gn_b   = (const float*)d_in[2];
  const float* qkv_w  = (const float*)d_in[3];
  const float* qkv_b  = (const float*)d_in[4];
  const float* proj_w = (const float*)d_in[5];
  const float* proj_b = (const float*)d_in[6];
  float* out = (float*)d_out;

  float* spec  = (float*)d_ws;
  __bf16* Qt   = (__bf16*)(spec + 4194304);   // 4194304 elems
  __bf16* Kt   = Qt + 4194304;                // 2359296 elems (32*1152*64)
  __bf16* Vt   = Kt + 2359296;                // 2359296 elems
  float* xr    = (float*)(Vt + 2359296) + 512; // 512-float hole (old stats slot)
  __bf16* xt   = (__bf16*)(xr + 4194304);     // 4194304 bf16
  __bf16* opart = (__bf16*)xr;                // 4194304 bf16 (clobbers xr; single-part)
  float*  dq    = (float*)(opart + 12582912); // 65536 (offset kept from 3-part era)
  float*  uk    = dq + 65536;                 // 2048
  float*  uv    = uk + 2048;                  // 2048
  float*  stats_part = uv + 2048;             // 4096 floats (256 bg x 8 sub x 2)

  k_fft2<<<512, 256, 0, stream>>>(x, xr, stats_part);
  k_gnuv<<<1088, 256, 0, stream>>>(xr, stats_part, gn_w, gn_b, qkv_w, qkv_b,
                                   xt, uk, uv);
  k_gemm_qkv<<<dim3(136, 8), 256, 0, stream>>>(qkv_w, xt, qkv_b, uk, dq,
                                               Qt, Kt, Vt);
  k_attn_mfma<<<dim3(16, 32), 256, 0, stream>>>(Qt, Kt, Vt, dq, uv, opart);
  k_gemm_proj<<<dim3(16, 4, 8), 256, 0, stream>>>(proj_w, opart, proj_b, spec);
  k_ifft2<<<512, 256, 0, stream>>>(spec, out);
}

// Round 11
// 152.736 us; speedup vs baseline: 1.2511x; 1.0047x over previous
//
#include <hip/hip_runtime.h>
#include <hip/hip_bf16.h>
#include <stdint.h>

#define PI_F 3.14159265358979323846f
#define C1_EXP 0.18033688f   // log2(e)/8
#define C2_EXP 23.083120f    // 16*log2(e)

typedef __bf16 bf16x8 __attribute__((ext_vector_type(8)));
typedef float f32x4 __attribute__((ext_vector_type(4)));
typedef unsigned int uint32x4 __attribute__((ext_vector_type(4)));

// LDS-only barrier: s_barrier with lgkmcnt drain but NO vmcnt drain, so
// in-flight global prefetch loads survive across the barrier (T4-minimal).
// Proven +3us on attn in r20.
#define BAR_LDS() asm volatile("s_waitcnt lgkmcnt(0)\n\ts_barrier" ::: "memory")

__device__ __forceinline__ bf16x8 neg8(bf16x8 v) {
  union { bf16x8 b; uint32x4 u; } x;
  x.b = v;
  x.u ^= (uint32x4){0x80008000u, 0x80008000u, 0x80008000u, 0x80008000u};
  return x.b;
}

// 3-term split-accumulate: P*Q with P=Ph+Pl, Q=Qh+Ql (drop Pl*Ql ~2^-18)
#define MFMA3(acc, Ph, Pl, Qh, Ql)                                        \
  acc = __builtin_amdgcn_mfma_f32_16x16x32_bf16(Ph, Qh, acc, 0, 0, 0);    \
  acc = __builtin_amdgcn_mfma_f32_16x16x32_bf16(Ph, Ql, acc, 0, 0, 0);    \
  acc = __builtin_amdgcn_mfma_f32_16x16x32_bf16(Pl, Qh, acc, 0, 0, 0);

// Closed-form base-slot -> original column mapping.
__device__ __forceinline__ int slot2n(int slot) {
  const int pi = slot >> 1, im = slot & 1;
  int k1, k2;
  if (pi < 480)      { k1 = 1 + (pi >> 5); k2 = pi & 31; }
  else if (pi < 495) { k1 = 0;  k2 = pi - 479; }
  else if (pi < 510) { k1 = 16; k2 = pi - 494; }
  else if (pi < 514) { k1 = ((pi - 510) >> 1) * 16; k2 = ((pi - 510) & 1) * 16; }
  else               { k1 = 0; k2 = 0; }
  return 2 * (k1 * 32 + k2) + im;
}

// Inline twiddle-table build (r22: replaces k_twid kernel + global staging).
__device__ __forceinline__ void build_twiddle_lds(char* smem, int tid) {
  for (int e = tid; e < 1024; e += 256) {
    const int j = e >> 5, k = e & 31;
    const int t = (j * k) & 31;
    float sv, cv;
    sincosf(2.0f * PI_F * (float)t / 32.0f, &sv, &cv);
    const __bf16 ch = (__bf16)cv, sh = (__bf16)sv;
    *(__bf16*)(smem + j * 80 + k * 2) = ch;
    *(__bf16*)(smem + 2560 + j * 80 + k * 2) = (__bf16)(cv - (float)ch);
    *(__bf16*)(smem + 5120 + j * 80 + k * 2) = sh;
    *(__bf16*)(smem + 7680 + j * 80 + k * 2) = (__bf16)(sv - (float)sh);
  }
}

// ---------------------------------------------------------------------------
// Kernel 1: forward FFT2 via split-bf16 MFMA. One slice per wave; r22 form.
// ---------------------------------------------------------------------------
__global__ __launch_bounds__(256) void k_fft2(const float* __restrict__ x,
                                              float* __restrict__ xr,
                                              float* __restrict__ stats_part) {
  __shared__ __align__(16) char smem[51200];
  const int tid = threadIdx.x, lane = tid & 63, wv = tid >> 6;
  const int quad = lane >> 4, q16 = lane & 15;
  const int slice = blockIdx.x * 4 + wv;
  char* const wr_ = smem + 10240 + wv * 10240;

  // early X global loads (wave-private region; overlap with table build)
  const float* xs = x + (size_t)slice * 1024;
  float4 xv[4];
#pragma unroll
  for (int u = 0; u < 4; ++u) xv[u] = ((const float4*)xs)[u * 64 + lane];

  build_twiddle_lds(smem, tid);

  // X split + stage (same-wave ds ordering)
#pragma unroll
  for (int u = 0; u < 4; ++u) {
    const int f = u * 64 + lane;
    const float4 v = xv[u];
    const int row = f >> 3, c4 = (f & 7) * 4;
    union { unsigned long long q; __bf16 b[4]; } ph, pl;
    ph.b[0] = (__bf16)v.x; ph.b[1] = (__bf16)v.y;
    ph.b[2] = (__bf16)v.z; ph.b[3] = (__bf16)v.w;
    pl.b[0] = (__bf16)(v.x - (float)ph.b[0]);
    pl.b[1] = (__bf16)(v.y - (float)ph.b[1]);
    pl.b[2] = (__bf16)(v.z - (float)ph.b[2]);
    pl.b[3] = (__bf16)(v.w - (float)ph.b[3]);
    *(unsigned long long*)(wr_ + row * 80 + c4 * 2) = ph.q;
    *(unsigned long long*)(wr_ + 2560 + row * 80 + c4 * 2) = pl.q;
  }
  __syncthreads();  // tables visible to all waves; X same-wave ordered

  bf16x8 cch[2], ccl[2], ssh[2], ssl[2], xh[2], xl[2];
#pragma unroll
  for (int t2 = 0; t2 < 2; ++t2) {
    const int row = t2 * 16 + q16;
    cch[t2] = *(const bf16x8*)(smem + row * 80 + quad * 16);
    ccl[t2] = *(const bf16x8*)(smem + 2560 + row * 80 + quad * 16);
    ssh[t2] = *(const bf16x8*)(smem + 5120 + row * 80 + quad * 16);
    ssl[t2] = *(const bf16x8*)(smem + 7680 + row * 80 + quad * 16);
    xh[t2] = *(const bf16x8*)(wr_ + row * 80 + quad * 16);
    xl[t2] = *(const bf16x8*)(wr_ + 2560 + row * 80 + quad * 16);
  }

  // pass 1: Yre = X@Cc, Yim = -(X@Ss)
  f32x4 yre[2][2] = {}, yim[2][2] = {};
#pragma unroll
  for (int mt = 0; mt < 2; ++mt)
#pragma unroll
    for (int nt = 0; nt < 2; ++nt) {
      MFMA3(yre[mt][nt], xh[mt], xl[mt], cch[nt], ccl[nt]);
      MFMA3(yim[mt][nt], xh[mt], xl[mt], ssh[nt], ssl[nt]);
    }

  // write Yt transposed + split (wave-private; same-wave ordering)
#pragma unroll
  for (int mt = 0; mt < 2; ++mt)
#pragma unroll
    for (int nt = 0; nt < 2; ++nt) {
      char* base = wr_ + (nt * 16 + q16) * 80 + (mt * 16 + quad * 4) * 2;
      union { unsigned long long q; __bf16 b[4]; } h, l;
#pragma unroll
      for (int r = 0; r < 4; ++r) {
        const float v = yre[mt][nt][r];
        h.b[r] = (__bf16)v; l.b[r] = (__bf16)(v - (float)h.b[r]);
      }
      *(unsigned long long*)(base) = h.q;
      *(unsigned long long*)(base + 2560) = l.q;
#pragma unroll
      for (int r = 0; r < 4; ++r) {
        const float v = -yim[mt][nt][r];
        h.b[r] = (__bf16)v; l.b[r] = (__bf16)(v - (float)h.b[r]);
      }
      *(unsigned long long*)(base + 5120) = h.q;
      *(unsigned long long*)(base + 7680) = l.q;
    }
  asm volatile("" ::: "memory");

  bf16x8 yreh[2], yrel[2], yimh[2], yiml[2];
#pragma unroll
  for (int nt = 0; nt < 2; ++nt) {
    const int row = nt * 16 + q16;
    yreh[nt] = *(const bf16x8*)(wr_ + row * 80 + quad * 16);
    yrel[nt] = *(const bf16x8*)(wr_ + 2560 + row * 80 + quad * 16);
    yimh[nt] = *(const bf16x8*)(wr_ + 5120 + row * 80 + quad * 16);
    yiml[nt] = *(const bf16x8*)(wr_ + 7680 + row * 80 + quad * 16);
  }

  // pass 2: Zre = Cc@Yre + Ss@Yim ; Zim = Cc@Yim - Ss@Yre
  f32x4 zre[2][2] = {}, zim[2][2] = {};
  bf16x8 ssnh[2], ssnl[2];
  ssnh[0] = neg8(ssh[0]); ssnh[1] = neg8(ssh[1]);
  ssnl[0] = neg8(ssl[0]); ssnl[1] = neg8(ssl[1]);
#pragma unroll
  for (int mt = 0; mt < 2; ++mt)
#pragma unroll
    for (int nt = 0; nt < 2; ++nt) {
      MFMA3(zre[mt][nt], cch[mt], ccl[mt], yreh[nt], yrel[nt]);
      MFMA3(zre[mt][nt], ssh[mt], ssl[mt], yimh[nt], yiml[nt]);
      MFMA3(zim[mt][nt], cch[mt], ccl[mt], yimh[nt], yiml[nt]);
      MFMA3(zim[mt][nt], ssnh[mt], ssnl[mt], yreh[nt], yrel[nt]);
    }

  // stats + store
  float* op = xr + (size_t)slice * 2048;
  float s1 = 0.f, s2 = 0.f;
#pragma unroll
  for (int mt = 0; mt < 2; ++mt)
#pragma unroll
    for (int nt = 0; nt < 2; ++nt)
#pragma unroll
      for (int r = 0; r < 4; ++r) {
        const int k1 = mt * 16 + quad * 4 + r;
        const int k2 = nt * 16 + q16;
        const float a = zre[mt][nt][r], bimg = zim[mt][nt][r];
        s1 += a + bimg;
        s2 += a * a + bimg * bimg;
        float2 st; st.x = a; st.y = bimg;
        *(float2*)(op + 2 * (k1 * 32 + k2)) = st;
      }
#pragma unroll
  for (int off = 1; off <= 32; off <<= 1) {
    s1 += __shfl_xor(s1, off);
    s2 += __shfl_xor(s2, off);
  }
  if (lane == 0) {
    const int bg = (slice >> 8) * 32 + ((slice & 255) >> 3);
    const int sub = slice & 7;
    float2 st; st.x = s1; st.y = s2;
    *(float2*)(stats_part + (size_t)(bg * 8 + sub) * 2) = st;
  }
}

// ---------------------------------------------------------------------------
// Kernel 2+3 merged (r24): GroupNorm-apply/transpose AND mirror-correction
// vectors in ONE launch. Blocks 0..1023 = gntrans tiles; 1024..1087 = uvec.
// ---------------------------------------------------------------------------
__global__ __launch_bounds__(256) void k_gnuv(const float* __restrict__ xr,
                                              const float* __restrict__ stats_part,
                                              const float* __restrict__ gn_w,
                                              const float* __restrict__ gn_b,
                                              const float* __restrict__ qkv_w,
                                              const float* __restrict__ qkv_b,
                                              __bf16* __restrict__ xt,
                                              float* __restrict__ uk,
                                              float* __restrict__ uv) {
  const int bid = blockIdx.x;
  const int tid = threadIdx.x;
  if (bid >= 1024) {
    // ---- uvec body (identical arithmetic to old k_uvec) ----
    const int blk = bid - 1024;
    const int b = blk >> 3, h = (blk >> 1) & 3, role = blk & 1;
    __shared__ float Bsh[256];
    {
      const int g = tid >> 3;
      float S = 0.f, S2 = 0.f;
#pragma unroll
      for (int s = 0; s < 8; ++s) {
        S  += stats_part[((b * 32 + g) * 8 + s) * 2];
        S2 += stats_part[((b * 32 + g) * 8 + s) * 2 + 1];
      }
      const float mean = S * (1.0f / 16384.0f);
      const float var = S2 * (1.0f / 16384.0f) - mean * mean;
      const float rstd = rsqrtf(var + 1e-5f);
      Bsh[tid] = gn_b[tid] - mean * rstd * gn_w[tid];
    }
    __syncthreads();
    const int cp = tid >> 2, seg = tid & 3;
    const int row = h * 192 + 64 + role * 64 + cp;
    const float* wr_ = qkv_w + (size_t)row * 256 + seg * 64;
    const float* bs = Bsh + seg * 64;
    float s = 0.f;
#pragma unroll
    for (int i = 0; i < 16; ++i) {
      const float4 w4 = *(const float4*)(wr_ + i * 4);
      const float4 b4 = *(const float4*)(bs + i * 4);
      s += w4.x * b4.x + w4.y * b4.y + w4.z * b4.z + w4.w * b4.w;
    }
    s += __shfl_xor(s, 1);
    s += __shfl_xor(s, 2);
    if (seg == 0) {
      float* dst = (role == 0) ? uk : uv;
      dst[(size_t)(b * 4 + h) * 64 + cp] = s + qkv_b[row];
    }
    return;
  }
  // ---- gntrans body (identical arithmetic to old k_gntrans) ----
  const int n0 = (bid & 31) * 64;
  const int c0 = ((bid >> 5) & 3) * 64;
  const int b = bid >> 7;
  __shared__ __bf16 Lt[64][72];
  __shared__ float gsum[8][2];
  if (tid < 8) {
    const int g = (c0 >> 3) + tid;
    float S = 0.f, S2 = 0.f;
#pragma unroll
    for (int s = 0; s < 8; ++s) {
      S  += stats_part[((b * 32 + g) * 8 + s) * 2];
      S2 += stats_part[((b * 32 + g) * 8 + s) * 2 + 1];
    }
    gsum[tid][0] = S;
    gsum[tid][1] = S2;
  }
  __syncthreads();
  for (int i = tid; i < 1024; i += 256) {
    const int cl = i >> 4, c = c0 + cl, nl = (i & 15) * 4;
    const float S = gsum[cl >> 3][0];
    const float S2 = gsum[cl >> 3][1];
    const float mean = S * (1.0f / 16384.0f);
    const float var = S2 * (1.0f / 16384.0f) - mean * mean;
    const float rstd = rsqrtf(var + 1e-5f);
    const float sc = rstd * gn_w[c];
    const float sh = gn_b[c] - mean * sc;
    const float4 v = *(const float4*)(xr + ((size_t)b * 256 + c) * 2048 + n0 + nl);
    Lt[nl][cl] = (__bf16)(v.x * sc + sh);
    Lt[nl + 1][cl] = (__bf16)(v.y * sc + sh);
    Lt[nl + 2][cl] = (__bf16)(v.z * sc + sh);
    Lt[nl + 3][cl] = (__bf16)(v.w * sc + sh);
  }
  __syncthreads();
  __bf16* dst = xt + (size_t)b * 524288 + (size_t)n0 * 256 + c0;
  for (int i = tid; i < 512; i += 256) {
    const int nl = i >> 3, cch = (i & 7) * 8;
    *(uint4*)(dst + (size_t)nl * 256 + cch) = *(const uint4*)&Lt[nl][cch];
  }
}

// ---------------------------------------------------------------------------
// Kernel 4: QKV GEMM (bf16 MFMA), double-buffered LDS; unchanged.
// ---------------------------------------------------------------------------
__global__ __launch_bounds__(256) void k_gemm_qkv(const float* __restrict__ W,
                                                  const __bf16* __restrict__ X,
                                                  const float* __restrict__ bias,
                                                  const float* __restrict__ uk,
                                                  float* __restrict__ dq,
                                                  __bf16* __restrict__ Qt,
                                                  __bf16* __restrict__ Kt,
                                                  __bf16* __restrict__ Vt) {
  const int tx = blockIdx.x;
  const int b = blockIdx.y;
  int role, hd, nt;
  if (tx < 64) { role = 0; hd = tx >> 4; nt = tx & 15; }
  else if (tx < 100) { role = 1; const int i = tx - 64; hd = i / 9; nt = i - hd * 9; }
  else { role = 2; const int i = tx - 100; hd = i / 9; nt = i - hd * 9; }
  const int n0 = nt * 128;
  const int bo = hd * 192 + role * 64;
  const __bf16* Xb = X + (size_t)b * 524288;

  __shared__ __align__(16) char smem[30720];
  __bf16 (*Ot)[72] = (__bf16(*)[72])smem;
  __bf16 (*Ot2)[136] = (__bf16(*)[136])smem;

  const int tid = threadIdx.x, lane = tid & 63, wv = tid >> 6;
  const int quad = lane >> 4, q16 = lane & 15, wn = wv * 32;

  const int rowA = tid >> 2, chA = (tid & 3) * 8;
  const int browB0 = tid >> 2, bchB = (tid & 3) * 8;
  const float* wA = W + (size_t)(bo + rowA) * 256 + chA;

  const int s0r = n0 + browB0, s1r = n0 + browB0 + 64;
  const int pn0 = (role == 0) ? s0r : slot2n(s0r);
  const int pn1 = (role == 0) ? s1r : slot2n(s1r);

  float4 aP0 = *(const float4*)(wA);
  float4 aP1 = *(const float4*)(wA + 4);
  uint4 bP0 = *(const uint4*)(Xb + (size_t)pn0 * 256 + bchB);
  uint4 bP1 = *(const uint4*)(Xb + (size_t)pn1 * 256 + bchB);

  f32x4 acc[4][2] = {};
  int bsel = 0;
  for (int k0 = 0; k0 < 256; k0 += 32) {
    char* const Ab = smem + bsel;
    char* const Bb = smem + bsel + 5120;
    {
      union { uint4 u; __bf16 h[8]; } pa;
      pa.h[0] = (__bf16)aP0.x; pa.h[1] = (__bf16)aP0.y;
      pa.h[2] = (__bf16)aP0.z; pa.h[3] = (__bf16)aP0.w;
      pa.h[4] = (__bf16)aP1.x; pa.h[5] = (__bf16)aP1.y;
      pa.h[6] = (__bf16)aP1.z; pa.h[7] = (__bf16)aP1.w;
      *(uint4*)(Ab + rowA * 80 + chA * 2) = pa.u;
      *(uint4*)(Bb + browB0 * 80 + bchB * 2) = bP0;
      *(uint4*)(Bb + (browB0 + 64) * 80 + bchB * 2) = bP1;
    }
    __syncthreads();
    if (k0 + 32 < 256) {
      const int kn = k0 + 32;
      aP0 = *(const float4*)(wA + kn);
      aP1 = *(const float4*)(wA + kn + 4);
      bP0 = *(const uint4*)(Xb + (size_t)pn0 * 256 + kn + bchB);
      bP1 = *(const uint4*)(Xb + (size_t)pn1 * 256 + kn + bchB);
    }
    bf16x8 af[4], bfr[2];
#pragma unroll
    for (int mt = 0; mt < 4; ++mt)
      af[mt] = *(const bf16x8*)(Ab + (mt * 16 + q16) * 80 + quad * 16);
#pragma unroll
    for (int jn = 0; jn < 2; ++jn)
      bfr[jn] = *(const bf16x8*)(Bb + (wn + jn * 16 + q16) * 80 + quad * 16);
#pragma unroll
    for (int mt = 0; mt < 4; ++mt)
#pragma unroll
      for (int jn = 0; jn < 2; ++jn)
        acc[mt][jn] = __builtin_amdgcn_mfma_f32_16x16x32_bf16(af[mt], bfr[jn], acc[mt][jn], 0, 0, 0);
    bsel ^= 15360;
  }
  __syncthreads();

  const int bh = b * 4 + hd;
  if (role == 2) {
#pragma unroll
    for (int mt = 0; mt < 4; ++mt)
#pragma unroll
      for (int r = 0; r < 4; ++r) {
        const int c = mt * 16 + quad * 4 + r;
        const float bv = bias[bo + c];
#pragma unroll
        for (int jn = 0; jn < 2; ++jn)
          Ot2[c][wn + jn * 16 + q16] = (__bf16)(acc[mt][jn][r] + bv);
      }
    __syncthreads();
    __bf16* dst = Vt + (size_t)bh * 73728;  // [c][1152]
    for (int i = tid; i < 1024; i += 256) {
      const int c = i >> 4, sg = (i & 15) * 8;
      *(uint4*)(dst + (size_t)c * 1152 + n0 + sg) = *(const uint4*)&Ot2[c][sg];
    }
  } else {
    __bf16* dst = (role == 0 ? Qt + (size_t)bh * 131072
                             : Kt + (size_t)bh * 73728);  // [n][64]
#pragma unroll
    for (int mt = 0; mt < 4; ++mt)
#pragma unroll
      for (int r = 0; r < 4; ++r) {
        const int c = mt * 16 + quad * 4 + r;
        const float bv = bias[bo + c];
#pragma unroll
        for (int jn = 0; jn < 2; ++jn)
          Ot[wn + jn * 16 + q16][c] = (__bf16)(acc[mt][jn][r] + bv);
      }
    __syncthreads();
    for (int i = tid; i < 1024; i += 256) {
      const int nl = i >> 3, cch = (i & 7) * 8;
      *(uint4*)(dst + (size_t)(n0 + nl) * 64 + cch) = *(const uint4*)&Ot[nl][cch];
    }
    if (role == 0 && tid < 128) {
      const float* ukp = uk + (size_t)bh * 64;
      float dv = 0.f;
#pragma unroll
      for (int g8 = 0; g8 < 8; ++g8) {
        const bf16x8 qv = *(const bf16x8*)&Ot[tid][g8 * 8];
#pragma unroll
        for (int k = 0; k < 8; ++k) dv += (float)qv[k] * ukp[g8 * 8 + k];
      }
      dq[(size_t)bh * 2048 + n0 + tid] = dv * (2.0f * C1_EXP);
    }
  }
}

// ---------------------------------------------------------------------------
// Kernel 5: MFMA flash attention. r26 = r25 (KVBLK=128, 18 barriers) +
// s_setprio(1)/(0) around both MFMA clusters (T5 — never cleanly tested on
// this kernel; r18's bundled attempt was masked by spill). Zero layout or
// regalloc change otherwise.
// ---------------------------------------------------------------------------
template <bool EDGE, int OFF>
__device__ __forceinline__ void attn_half(
    const int s0, const int quad,
    const char* const (&krp)[2][2], const char* const (&vrp)[4],
    char* const (&pwp)[2][2], const char* const (&prp)[2],
    const bf16x8 (&bq)[2][2], const float (&Dm)[2],
    f32x4 (&oacc)[2][4], float (&lsum)[2], float (&spsum)[2]) {
  f32x4 sacc[2][2] = {};
  __builtin_amdgcn_s_setprio(1);
#pragma unroll
  for (int j = 0; j < 2; ++j)
#pragma unroll
    for (int kk = 0; kk < 2; ++kk) {
      const bf16x8 ak = *(const bf16x8*)(krp[j][kk] + OFF);
      sacc[0][j] = __builtin_amdgcn_mfma_f32_16x16x32_bf16(ak, bq[0][kk], sacc[0][j], 0, 0, 0);
      sacc[1][j] = __builtin_amdgcn_mfma_f32_16x16x32_bf16(ak, bq[1][kk], sacc[1][j], 0, 0, 0);
    }
  __builtin_amdgcn_s_setprio(0);

#pragma unroll
  for (int b = 0; b < 2; ++b) {
    float lacc = 0.f, spacc = 0.f;
#pragma unroll
    for (int j = 0; j < 2; ++j) {
      float B0, B2, Bv1, Bv3, Bm1, Bm3;
      if (EDGE) {
        const int sg = s0 + j * 16 + quad * 4;
        B0 = (sg < 1020) ? (1.0f - C2_EXP) : ((sg < 1028) ? -C2_EXP : -1e30f);
        B2 = (sg + 2 < 1020) ? (1.0f - C2_EXP)
                             : ((sg + 2 < 1028) ? -C2_EXP : -1e30f);
        Bv1 = (sg + 1 < 1028) ? -C2_EXP : -1e30f;
        Bv3 = (sg + 3 < 1028) ? -C2_EXP : -1e30f;
        Bm1 = (sg + 1 < 1020) ? Dm[b] : -1e30f;
        Bm3 = (sg + 3 < 1020) ? Dm[b] : -1e30f;
      } else {
        B0 = 1.0f - C2_EXP;
        B2 = 1.0f - C2_EXP;
        Bv1 = -C2_EXP;
        Bv3 = -C2_EXP;
        Bm1 = Dm[b];
        Bm3 = Dm[b];
      }
      const float P0  = __builtin_amdgcn_exp2f(fmaf(sacc[b][j][0],  C1_EXP, B0));
      const float Pv1 = __builtin_amdgcn_exp2f(fmaf(sacc[b][j][1],  C1_EXP, Bv1));
      const float P2  = __builtin_amdgcn_exp2f(fmaf(sacc[b][j][2],  C1_EXP, B2));
      const float Pv3 = __builtin_amdgcn_exp2f(fmaf(sacc[b][j][3],  C1_EXP, Bv3));
      const float pm1 = __builtin_amdgcn_exp2f(fmaf(sacc[b][j][1], -C1_EXP, Bm1));
      const float pm3 = __builtin_amdgcn_exp2f(fmaf(sacc[b][j][3], -C1_EXP, Bm3));
      const float mm = pm1 + pm3;
      lacc += (P0 + P2) + (Pv1 + Pv3) + mm;
      spacc += mm;
      union { uint2 u; __bf16 h[4]; } pk;
      pk.h[0] = (__bf16)P0;
      pk.h[1] = (__bf16)(Pv1 - pm1);
      pk.h[2] = (__bf16)P2;
      pk.h[3] = (__bf16)(Pv3 - pm3);
      *(uint2*)pwp[b][j] = pk.u;
    }
    lsum[b] += lacc;
    spsum[b] += spacc;
  }
  asm volatile("" ::: "memory");

  bf16x8 bp[2];
  bp[0] = *(const bf16x8*)prp[0];
  bp[1] = *(const bf16x8*)prp[1];
  __builtin_amdgcn_s_setprio(1);
#pragma unroll
  for (int jc = 0; jc < 4; ++jc) {
    const bf16x8 av = *(const bf16x8*)(vrp[jc] + OFF);
    oacc[0][jc] = __builtin_amdgcn_mfma_f32_16x16x32_bf16(av, bp[0], oacc[0][jc], 0, 0, 0);
    oacc[1][jc] = __builtin_amdgcn_mfma_f32_16x16x32_bf16(av, bp[1], oacc[1][jc], 0, 0, 0);
  }
  __builtin_amdgcn_s_setprio(0);
}

__global__ __launch_bounds__(256, 2) void k_attn_mfma(const __bf16* __restrict__ Qt,
                                                      const __bf16* __restrict__ Kt,
                                                      const __bf16* __restrict__ Vt,
                                                      const float* __restrict__ dq,
                                                      const float* __restrict__ uv,
                                                      __bf16* __restrict__ opart) {
  const int t0 = blockIdx.x * 128;
  const int bh = blockIdx.y;
  const __bf16* kt = Kt + (size_t)bh * 73728;
  const __bf16* vt = Vt + (size_t)bh * 73728;

  __shared__ __align__(16) char smem[40960];

  const int tid = threadIdx.x, lane = tid & 63, wv = tid >> 6;
  const int quad = lane >> 4, q16 = lane & 15;
  const int wband = wv * 32;

  const int rK = tid >> 3, gK = tid & 7;
  char* const kw = smem + rK * 128 + ((gK ^ (rK & 7)) * 16);
  const int cV = tid >> 2, gV = tid & 3;
  char* const vw = smem + 16384 + (cV >> 1) * 128 +
                   ((((cV & 1) * 4 + gV) ^ ((cV >> 1) & 7)) * 16);
  const __bf16* const kg = kt + (size_t)rK * 64 + gK * 8;
  const __bf16* const vg = vt + (size_t)cV * 1152 + gV * 8;

  const char* krp[2][2];
#pragma unroll
  for (int j = 0; j < 2; ++j)
#pragma unroll
    for (int kk = 0; kk < 2; ++kk)
      krp[j][kk] = smem + (j * 16 + q16) * 128 + (((kk * 4 + quad) ^ (q16 & 7)) * 16);
  const int a7 = (q16 >> 1) & 7, p1 = q16 & 1;
  const char* vrp[4];
#pragma unroll
  for (int jc = 0; jc < 4; ++jc)
    vrp[jc] = smem + 16384 + (jc * 8 + (q16 >> 1)) * 128 +
              (((p1 * 4 + quad) ^ a7) * 16);
  char* pwp[2][2];
  const char* prp[2];
#pragma unroll
  for (int b = 0; b < 2; ++b) {
    const int mrow = ((wband + b * 16) >> 1) + (q16 >> 1);
    prp[b] = smem + 32768 + mrow * 128 + (((p1 * 4 + quad) ^ a7) * 16);
#pragma unroll
    for (int j = 0; j < 2; ++j)
      pwp[b][j] = smem + 32768 + mrow * 128 +
                  (((p1 * 4 + j * 2 + (quad >> 1)) ^ a7) * 16) + (quad & 1) * 8;
  }

  const __bf16* qbase = Qt + (size_t)bh * 131072;
  bf16x8 bq[2][2];
  float Dm[2];
#pragma unroll
  for (int b = 0; b < 2; ++b) {
    const int t = t0 + wband + b * 16 + q16;
    const __bf16* qp = qbase + (size_t)t * 64 + quad * 8;
    bq[b][0] = *(const bf16x8*)qp;
    bq[b][1] = *(const bf16x8*)(qp + 32);
    Dm[b] = dq[(size_t)bh * 2048 + t] - C2_EXP;
  }

  f32x4 oacc[2][4] = {};
  float lsum[2] = {0.f, 0.f};
  float spsum[2] = {0.f, 0.f};

  // 1056 slots = 7 x quad(128) [0..895] + quad(128) with edge last half
  // [896..1023] + single(32) edge [1024..1055].
  uint4 kA0 = *(const uint4*)(kg);
  uint4 kA1 = *(const uint4*)(kg + (size_t)32 * 64);
  uint4 kA2 = *(const uint4*)(kg + (size_t)64 * 64);
  uint4 kA3 = *(const uint4*)(kg + (size_t)96 * 64);
  uint4 vA0 = *(const uint4*)(vg);
  uint4 vA1 = *(const uint4*)(vg + 32);
  uint4 vA2 = *(const uint4*)(vg + 64);
  uint4 vA3 = *(const uint4*)(vg + 96);

  int s0 = 0;
#pragma unroll 1
  for (int it = 0; it < 7; ++it) {
    *(uint4*)kw = kA0;
    *(uint4*)(kw + 4096) = kA1;
    *(uint4*)(kw + 8192) = kA2;
    *(uint4*)(kw + 12288) = kA3;
    *(uint4*)vw = vA0;
    *(uint4*)(vw + 4096) = vA1;
    *(uint4*)(vw + 8192) = vA2;
    *(uint4*)(vw + 12288) = vA3;
    BAR_LDS();
    kA0 = *(const uint4*)(kg + (size_t)(s0 + 128) * 64);
    kA1 = *(const uint4*)(kg + (size_t)(s0 + 160) * 64);
    kA2 = *(const uint4*)(kg + (size_t)(s0 + 192) * 64);
    kA3 = *(const uint4*)(kg + (size_t)(s0 + 224) * 64);
    vA0 = *(const uint4*)(vg + s0 + 128);
    vA1 = *(const uint4*)(vg + s0 + 160);
    vA2 = *(const uint4*)(vg + s0 + 192);
    vA3 = *(const uint4*)(vg + s0 + 224);
    attn_half<false, 0>(s0, quad, krp, vrp, pwp, prp, bq, Dm,
                        oacc, lsum, spsum);
    attn_half<false, 4096>(s0 + 32, quad, krp, vrp, pwp, prp, bq, Dm,
                           oacc, lsum, spsum);
    attn_half<false, 8192>(s0 + 64, quad, krp, vrp, pwp, prp, bq, Dm,
                           oacc, lsum, spsum);
    attn_half<false, 12288>(s0 + 96, quad, krp, vrp, pwp, prp, bq, Dm,
                            oacc, lsum, spsum);
    BAR_LDS();
    s0 += 128;
  }
  // s0 == 896; regs hold tiles 896,928,960,992.
  *(uint4*)kw = kA0;
  *(uint4*)(kw + 4096) = kA1;
  *(uint4*)(kw + 8192) = kA2;
  *(uint4*)(kw + 12288) = kA3;
  *(uint4*)vw = vA0;
  *(uint4*)(vw + 4096) = vA1;
  *(uint4*)(vw + 8192) = vA2;
  *(uint4*)(vw + 12288) = vA3;
  BAR_LDS();
  kA0 = *(const uint4*)(kg + (size_t)1024 * 64);
  vA0 = *(const uint4*)(vg + 1024);
  attn_half<false, 0>(896, quad, krp, vrp, pwp, prp, bq, Dm,
                      oacc, lsum, spsum);
  attn_half<false, 4096>(928, quad, krp, vrp, pwp, prp, bq, Dm,
                         oacc, lsum, spsum);
  attn_half<false, 8192>(960, quad, krp, vrp, pwp, prp, bq, Dm,
                         oacc, lsum, spsum);   // 960+31=991 < 1020: interior
  attn_half<true, 12288>(992, quad, krp, vrp, pwp, prp, bq, Dm,
                         oacc, lsum, spsum);
  BAR_LDS();
  // final single 32-slot tile at base offsets
  *(uint4*)kw = kA0;
  *(uint4*)vw = vA0;
  BAR_LDS();
  attn_half<true, 0>(1024, quad, krp, vrp, pwp, prp, bq, Dm,
                     oacc, lsum, spsum);

  // epilogue-only uv load (kept out of the loop-live register set)
  float4 uv4[4];
  {
    const float* uvp = uv + (size_t)bh * 64;
#pragma unroll
    for (int jc = 0; jc < 4; ++jc)
      uv4[jc] = *(const float4*)(uvp + jc * 16 + quad * 4);
  }

#pragma unroll
  for (int b = 0; b < 2; ++b) {
    float l = lsum[b], sp = spsum[b];
    l += __shfl_xor(l, 16);
    l += __shfl_xor(l, 32);
    sp += __shfl_xor(sp, 16);
    sp += __shfl_xor(sp, 32);
    const float inv = 1.0f / l;         // l complete: self-normalize
    const float su = 2.0f * sp * inv;
    const int t = t0 + wband + b * 16 + q16;
    __bf16* opp = opart + ((size_t)bh * 2048 + t) * 64;
#pragma unroll
    for (int jc = 0; jc < 4; ++jc) {
      union { uint2 u; __bf16 h[4]; } pk;
      pk.h[0] = (__bf16)(oacc[b][jc][0] * inv + su * uv4[jc].x);
      pk.h[1] = (__bf16)(oacc[b][jc][1] * inv + su * uv4[jc].y);
      pk.h[2] = (__bf16)(oacc[b][jc][2] * inv + su * uv4[jc].z);
      pk.h[3] = (__bf16)(oacc[b][jc][3] * inv + su * uv4[jc].w);
      *(uint2*)(opp + jc * 16 + quad * 4) = pk.u;
    }
  }
}

// ---------------------------------------------------------------------------
// Kernel 6: proj GEMM (bf16 MFMA), double-buffered, plain GEMM; unchanged.
// ---------------------------------------------------------------------------
__global__ __launch_bounds__(256) void k_gemm_proj(const float* __restrict__ W,
                                                   const __bf16* __restrict__ opart,
                                                   const float* __restrict__ bias,
                                                   float* __restrict__ C) {
  const int n0 = blockIdx.x * 128;
  const int bo = blockIdx.y * 64;
  const int b = blockIdx.z;
  float* Cb = C + (size_t)b * 524288;

  __shared__ __align__(16) char smem[30720];

  const int tid = threadIdx.x, lane = tid & 63, wv = tid >> 6;
  const int quad = lane >> 4, q16 = lane & 15, wn = wv * 32;

  const int rowA = tid >> 2, chA = (tid & 3) * 8;
  const int browB0 = tid >> 2, bchB = (tid & 3) * 8;
  const float* wA = W + (size_t)(bo + rowA) * 256 + chA;

  float4 aP0 = *(const float4*)(wA);
  float4 aP1 = *(const float4*)(wA + 4);
  uint4 oPd[2];
#pragma unroll
  for (int g = 0; g < 2; ++g) {
    const int t = n0 + browB0 + g * 64;
    const size_t rr = (size_t)(b * 4) * 2048 + t;
    oPd[g] = *(const uint4*)(opart + rr * 64 + bchB);
  }

  f32x4 acc[4][2] = {};
  int bsel = 0;
  for (int k0 = 0; k0 < 256; k0 += 32) {
    char* const Ab = smem + bsel;
    char* const Bb = smem + bsel + 5120;
    {
      union { uint4 u; __bf16 h[8]; } pa;
      pa.h[0] = (__bf16)aP0.x; pa.h[1] = (__bf16)aP0.y;
      pa.h[2] = (__bf16)aP0.z; pa.h[3] = (__bf16)aP0.w;
      pa.h[4] = (__bf16)aP1.x; pa.h[5] = (__bf16)aP1.y;
      pa.h[6] = (__bf16)aP1.z; pa.h[7] = (__bf16)aP1.w;
      *(uint4*)(Ab + rowA * 80 + chA * 2) = pa.u;
      *(uint4*)(Bb + browB0 * 80 + bchB * 2) = oPd[0];
      *(uint4*)(Bb + (browB0 + 64) * 80 + bchB * 2) = oPd[1];
    }
    __syncthreads();
    if (k0 + 32 < 256) {
      const int kn = k0 + 32;
      aP0 = *(const float4*)(wA + kn);
      aP1 = *(const float4*)(wA + kn + 4);
      const int c = kn + bchB;
      const int hd = c >> 6, cu = c & 63;
#pragma unroll
      for (int g = 0; g < 2; ++g) {
        const int t = n0 + browB0 + g * 64;
        const size_t rr = (size_t)(b * 4 + hd) * 2048 + t;
        oPd[g] = *(const uint4*)(opart + rr * 64 + cu);
      }
    }
    bf16x8 af[4], bfr[2];
#pragma unroll
    for (int mt = 0; mt < 4; ++mt)
      af[mt] = *(const bf16x8*)(Ab + (mt * 16 + q16) * 80 + quad * 16);
#pragma unroll
    for (int jn = 0; jn < 2; ++jn)
      bfr[jn] = *(const bf16x8*)(Bb + (wn + jn * 16 + q16) * 80 + quad * 16);
#pragma unroll
    for (int mt = 0; mt < 4; ++mt)
#pragma unroll
      for (int jn = 0; jn < 2; ++jn)
        acc[mt][jn] = __builtin_amdgcn_mfma_f32_16x16x32_bf16(af[mt], bfr[jn], acc[mt][jn], 0, 0, 0);
    bsel ^= 15360;
  }

#pragma unroll
  for (int mt = 0; mt < 4; ++mt)
#pragma unroll
    for (int r = 0; r < 4; ++r) {
      const int o = bo + mt * 16 + quad * 4 + r;
      const float bv = bias[o];
#pragma unroll
      for (int jn = 0; jn < 2; ++jn)
        Cb[(size_t)o * 2048 + n0 + wn + jn * 16 + q16] = acc[mt][jn][r] + bv;
    }
}

// ---------------------------------------------------------------------------
// Kernel 7: inverse FFT2 via split-bf16 MFMA. One slice per wave; r22 form.
// ---------------------------------------------------------------------------
__global__ __launch_bounds__(256) void k_ifft2(const float* __restrict__ spec,
                                               float* __restrict__ out) {
  __shared__ __align__(16) char smem[51200];
  const int tid = threadIdx.x, lane = tid & 63, wv = tid >> 6;
  const int quad = lane >> 4, q16 = lane & 15;
  const int slice = blockIdx.x * 4 + wv;
  char* const wr_ = smem + 10240 + wv * 10240;

  // early spec global loads
  const float* sp = spec + (size_t)slice * 2048;
  float4 sv8[8];
#pragma unroll
  for (int u = 0; u < 8; ++u) sv8[u] = ((const float4*)sp)[u * 64 + lane];

  build_twiddle_lds(smem, tid);

#pragma unroll
  for (int u = 0; u < 8; ++u) {
    const int f = u * 64 + lane;  // 0..511 float4 (2 complex each)
    const float4 v = sv8[u];
    const int k1 = f >> 4, k2 = (f & 15) * 2;
    char* base = wr_ + k1 * 80 + k2 * 2;
    union { unsigned int w; __bf16 b[2]; } p;
    const __bf16 rh0 = (__bf16)v.x, rh1 = (__bf16)v.z;
    const __bf16 ih0 = (__bf16)v.y, ih1 = (__bf16)v.w;
    p.b[0] = rh0; p.b[1] = rh1; *(unsigned int*)(base) = p.w;
    p.b[0] = (__bf16)(v.x - (float)rh0);
    p.b[1] = (__bf16)(v.z - (float)rh1); *(unsigned int*)(base + 2560) = p.w;
    p.b[0] = ih0; p.b[1] = ih1; *(unsigned int*)(base + 5120) = p.w;
    p.b[0] = (__bf16)(v.y - (float)ih0);
    p.b[1] = (__bf16)(v.w - (float)ih1); *(unsigned int*)(base + 7680) = p.w;
  }
  __syncthreads();  // tables visible; X same-wave ordered

  bf16x8 cch[2], ccl[2], ssh[2], ssl[2], ssnh[2], ssnl[2];
  bf16x8 xreh[2], xrel[2], ximh[2], ximl[2];
#pragma unroll
  for (int t2 = 0; t2 < 2; ++t2) {
    const int row = t2 * 16 + q16;
    cch[t2] = *(const bf16x8*)(smem + row * 80 + quad * 16);
    ccl[t2] = *(const bf16x8*)(smem + 2560 + row * 80 + quad * 16);
    ssh[t2] = *(const bf16x8*)(smem + 5120 + row * 80 + quad * 16);
    ssl[t2] = *(const bf16x8*)(smem + 7680 + row * 80 + quad * 16);
    xreh[t2] = *(const bf16x8*)(wr_ + row * 80 + quad * 16);
    xrel[t2] = *(const bf16x8*)(wr_ + 2560 + row * 80 + quad * 16);
    ximh[t2] = *(const bf16x8*)(wr_ + 5120 + row * 80 + quad * 16);
    ximl[t2] = *(const bf16x8*)(wr_ + 7680 + row * 80 + quad * 16);
  }
  ssnh[0] = neg8(ssh[0]); ssnh[1] = neg8(ssh[1]);
  ssnl[0] = neg8(ssl[0]); ssnl[1] = neg8(ssl[1]);

  // pass 1
  f32x4 yre[2][2] = {}, yim[2][2] = {};
#pragma unroll
  for (int mt = 0; mt < 2; ++mt)
#pragma unroll
    for (int nt = 0; nt < 2; ++nt) {
      MFMA3(yre[mt][nt], xreh[mt], xrel[mt], cch[nt], ccl[nt]);
      MFMA3(yre[mt][nt], ximh[mt], ximl[mt], ssnh[nt], ssnl[nt]);
      MFMA3(yim[mt][nt], xreh[mt], xrel[mt], ssh[nt], ssl[nt]);
      MFMA3(yim[mt][nt], ximh[mt], ximl[mt], cch[nt], ccl[nt]);
    }

  // write Yt transposed + split over the X regions (wave-private)
#pragma unroll
  for (int mt = 0; mt < 2; ++mt)
#pragma unroll
    for (int nt = 0; nt < 2; ++nt) {
      char* base = wr_ + (nt * 16 + q16) * 80 + (mt * 16 + quad * 4) * 2;
      union { unsigned long long q; __bf16 b[4]; } h, l;
#pragma unroll
      for (int r = 0; r < 4; ++r) {
        const float v = yre[mt][nt][r];
        h.b[r] = (__bf16)v; l.b[r] = (__bf16)(v - (float)h.b[r]);
      }
      *(unsigned long long*)(base) = h.q;
      *(unsigned long long*)(base + 2560) = l.q;
#pragma unroll
      for (int r = 0; r < 4; ++r) {
        const float v = yim[mt][nt][r];
        h.b[r] = (__bf16)v; l.b[r] = (__bf16)(v - (float)h.b[r]);
      }
      *(unsigned long long*)(base + 5120) = h.q;
      *(unsigned long long*)(base + 7680) = l.q;
    }
  asm volatile("" ::: "memory");

  bf16x8 yreh[2], yrel[2], yimh[2], yiml[2];
#pragma unroll
  for (int nt = 0; nt < 2; ++nt) {
    const int row = nt * 16 + q16;
    yreh[nt] = *(const bf16x8*)(wr_ + row * 80 + quad * 16);
    yrel[nt] = *(const bf16x8*)(wr_ + 2560 + row * 80 + quad * 16);
    yimh[nt] = *(const bf16x8*)(wr_ + 5120 + row * 80 + quad * 16);
    yiml[nt] = *(const bf16x8*)(wr_ + 7680 + row * 80 + quad * 16);
  }

  // pass 2
  f32x4 zre[2][2] = {}, zim[2][2] = {};
#pragma unroll
  for (int mt = 0; mt < 2; ++mt)
#pragma unroll
    for (int nt = 0; nt < 2; ++nt) {
      MFMA3(zre[mt][nt], cch[mt], ccl[mt], yreh[nt], yrel[nt]);
      MFMA3(zre[mt][nt], ssnh[mt], ssnl[mt], yimh[nt], yiml[nt]);
      MFMA3(zim[mt][nt], cch[mt], ccl[mt], yimh[nt], yiml[nt]);
      MFMA3(zim[mt][nt], ssh[mt], ssl[mt], yreh[nt], yrel[nt]);
    }

  float* op = out + (size_t)slice * 2048;
#pragma unroll
  for (int mt = 0; mt < 2; ++mt)
#pragma unroll
    for (int nt = 0; nt < 2; ++nt)
#pragma unroll
      for (int r = 0; r < 4; ++r) {
        const int n1 = mt * 16 + quad * 4 + r;
        const int n2 = nt * 16 + q16;
        float2 st;
        st.x = zre[mt][nt][r] * (1.0f / 1024.0f);
        st.y = zim[mt][nt][r] * (1.0f / 1024.0f);
        *(float2*)(op + 2 * (n1 * 32 + n2)) = st;
      }
}

// ---------------------------------------------------------------------------
extern "C" void kernel_launch(void* const* d_in, const int* in_sizes, int n_in,
                              void* d_out, int out_size, void* d_ws, size_t ws_size,
                              hipStream_t stream) {
  (void)in_sizes; (void)n_in; (void)out_size; (void)ws_size;
  const float* x      = (const float*)d_in[0];
  const float* gn_w   = (const float*)d_in[1];
  const float* gn_b   = (const float*)d_in[2];
  const float* qkv_w  = (const float*)d_in[3];
  const float* qkv_b  = (const float*)d_in[4];
  const float* proj_w = (const float*)d_in[5];
  const float* proj_b = (const float*)d_in[6];
  float* out = (float*)d_out;

  float* spec  = (float*)d_ws;
  __bf16* Qt   = (__bf16*)(spec + 4194304);   // 4194304 elems
  __bf16* Kt   = Qt + 4194304;                // 2359296 elems (32*1152*64)
  __bf16* Vt   = Kt + 2359296;                // 2359296 elems
  float* xr    = (float*)(Vt + 2359296) + 512; // 512-float hole (old stats slot)
  __bf16* xt   = (__bf16*)(xr + 4194304);     // 4194304 bf16
  __bf16* opart = (__bf16*)xr;                // 4194304 bf16 (clobbers xr; single-part)
  float*  dq    = (float*)(opart + 12582912); // 65536 (offset kept from 3-part era)
  float*  uk    = dq + 65536;                 // 2048
  float*  uv    = uk + 2048;                  // 2048
  float*  stats_part = uv + 2048;             // 4096 floats (256 bg x 8 sub x 2)

  k_fft2<<<512, 256, 0, stream>>>(x, xr, stats_part);
  k_gnuv<<<1088, 256, 0, stream>>>(xr, stats_part, gn_w, gn_b, qkv_w, qkv_b,
                                   xt, uk, uv);
  k_gemm_qkv<<<dim3(136, 8), 256, 0, stream>>>(qkv_w, xt, qkv_b, uk, dq,
                                               Qt, Kt, Vt);
  k_attn_mfma<<<dim3(16, 32), 256, 0, stream>>>(Qt, Kt, Vt, dq, uv, opart);
  k_gemm_proj<<<dim3(16, 4, 8), 256, 0, stream>>>(proj_w, opart, proj_b, spec);
  k_ifft2<<<512, 256, 0, stream>>>(spec, out);
}